// Round 12
// baseline (435.933 us; speedup 1.0000x reference)
//
#include <hip/hip_runtime.h>

#define NA 15
#define NB 32
#define DD 256
#define LDA 260   // 257 rounded to mult of 4 (fp32 stage1)
#define PL 65536  // shorts per weight plane
#define ASTR 264  // act LDS row stride (shorts)
#define P32 (24 * PL)  // offset of 32x32-layout planes within `planes`

using bf16x8 = __attribute__((ext_vector_type(8))) short;
using f32x4  = __attribute__((ext_vector_type(4))) float;
using f32x16 = __attribute__((ext_vector_type(16))) float;

__device__ __forceinline__ unsigned short f2bf(float f){
  unsigned int u = __float_as_uint(f);
  u = u + 0x7fffu + ((u >> 16) & 1u);
  return (unsigned short)(u >> 16);
}
__device__ __forceinline__ float bf2f(unsigned short h){
  return __uint_as_float(((unsigned int)h) << 16);
}
__device__ __forceinline__ unsigned int cvtpk_bf16(float lo, float hi){
    unsigned int r;
    asm("v_cvt_pk_bf16_f32 %0, %1, %2" : "=v"(r) : "v"(lo), "v"(hi));
    return r;
}
__device__ __forceinline__ void split2_write(const float v[4], short* pH, short* pL){
    unsigned int h01 = cvtpk_bf16(v[0], v[1]);
    unsigned int h23 = cvtpk_bf16(v[2], v[3]);
    float r0 = v[0] - __uint_as_float(h01 << 16);
    float r1 = v[1] - __uint_as_float(h01 & 0xffff0000u);
    float r2 = v[2] - __uint_as_float(h23 << 16);
    float r3 = v[3] - __uint_as_float(h23 & 0xffff0000u);
    unsigned int l01 = cvtpk_bf16(r0, r1);
    unsigned int l23 = cvtpk_bf16(r2, r3);
    *(uint2*)pH = make_uint2(h01, h23);
    *(uint2*)pL = make_uint2(l01, l23);
}
__device__ __forceinline__ void split3_write(const float v[4], short* pH, short* pM, short* pL){
    unsigned int h01 = cvtpk_bf16(v[0], v[1]);
    unsigned int h23 = cvtpk_bf16(v[2], v[3]);
    float r0 = v[0] - __uint_as_float(h01 << 16);
    float r1 = v[1] - __uint_as_float(h01 & 0xffff0000u);
    float r2 = v[2] - __uint_as_float(h23 << 16);
    float r3 = v[3] - __uint_as_float(h23 & 0xffff0000u);
    unsigned int m01 = cvtpk_bf16(r0, r1);
    unsigned int m23 = cvtpk_bf16(r2, r3);
    float s0 = r0 - __uint_as_float(m01 << 16);
    float s1 = r1 - __uint_as_float(m01 & 0xffff0000u);
    float s2 = r2 - __uint_as_float(m23 << 16);
    float s3 = r3 - __uint_as_float(m23 & 0xffff0000u);
    unsigned int l01 = cvtpk_bf16(s0, s1);
    unsigned int l23 = cvtpk_bf16(s2, s3);
    *(uint2*)pH = make_uint2(h01, h23);
    *(uint2*)pM = make_uint2(m01, m23);
    *(uint2*)pL = make_uint2(l01, l23);
}

// ---------------------------------------------------------------------------
// fp32 VALU primitives (value_x / stage1 branches of front kernel)
// ---------------------------------------------------------------------------
template<int TM, bool RELU>
__device__ __forceinline__ void layer256(
    const float* __restrict__ W, const float* __restrict__ bias,
    const float* act, int K, int lda, float* out, int ldo)
{
    constexpr int RPG = TM / 4;
    const int tid = threadIdx.x;
    const int tr = tid >> 6;
    const int tc = tid & 63;
    float acc[RPG][4];
#pragma unroll
    for (int i = 0; i < RPG; ++i) { acc[i][0]=0.f; acc[i][1]=0.f; acc[i][2]=0.f; acc[i][3]=0.f; }
    const float* wp = W + 4 * tc;
    int k = 0;
    for (; k + 4 <= K; k += 4) {
        float4 w0 = *reinterpret_cast<const float4*>(wp + (k + 0) * DD);
        float4 w1 = *reinterpret_cast<const float4*>(wp + (k + 1) * DD);
        float4 w2 = *reinterpret_cast<const float4*>(wp + (k + 2) * DD);
        float4 w3 = *reinterpret_cast<const float4*>(wp + (k + 3) * DD);
#pragma unroll
        for (int i = 0; i < RPG; ++i) {
            float4 a = *reinterpret_cast<const float4*>(act + (RPG * tr + i) * lda + k);
            acc[i][0] += a.x * w0.x + a.y * w1.x + a.z * w2.x + a.w * w3.x;
            acc[i][1] += a.x * w0.y + a.y * w1.y + a.z * w2.y + a.w * w3.y;
            acc[i][2] += a.x * w0.z + a.y * w1.z + a.z * w2.z + a.w * w3.z;
            acc[i][3] += a.x * w0.w + a.y * w1.w + a.z * w2.w + a.w * w3.w;
        }
    }
    for (; k < K; ++k) {
        float4 w0 = *reinterpret_cast<const float4*>(wp + k * DD);
#pragma unroll
        for (int i = 0; i < RPG; ++i) {
            float a = act[(RPG * tr + i) * lda + k];
            acc[i][0] += a * w0.x; acc[i][1] += a * w0.y;
            acc[i][2] += a * w0.z; acc[i][3] += a * w0.w;
        }
    }
    float4 bb = *reinterpret_cast<const float4*>(bias + 4 * tc);
#pragma unroll
    for (int i = 0; i < RPG; ++i) {
        float4 o;
        o.x = acc[i][0] + bb.x; o.y = acc[i][1] + bb.y;
        o.z = acc[i][2] + bb.z; o.w = acc[i][3] + bb.w;
        if (RELU) {
            o.x = fmaxf(o.x, 0.f); o.y = fmaxf(o.y, 0.f);
            o.z = fmaxf(o.z, 0.f); o.w = fmaxf(o.w, 0.f);
        }
        *reinterpret_cast<float4*>(out + (RPG * tr + i) * ldo + 4 * tc) = o;
    }
}

template<int TM>
__device__ __forceinline__ void head1c(
    const float* h, int ldh, const float* __restrict__ W, int wstr, int col, float bias,
    float* __restrict__ gout, int gbase)
{
    const int wv = threadIdx.x >> 6;
    const int lane = threadIdx.x & 63;
    for (int rr = wv; rr < TM; rr += 4) {
        float p = 0.f;
#pragma unroll
        for (int t = 0; t < 4; ++t) {
            int k = lane + 64 * t;
            p += h[rr * ldh + k] * W[k * wstr + col];
        }
#pragma unroll
        for (int m = 1; m < 64; m <<= 1) p += __shfl_xor(p, m);
        if (lane == 0) gout[gbase + rr] = p + bias;
    }
}

// ---------------------------------------------------------------------------
// front_kernel: blocks 0-63 prep (weight split, both layouts), 64 prep2 (w5,b5),
// 65-72 value_x (TM=4), 73-132 stage1 (TM=8).
// ---------------------------------------------------------------------------
__global__ __launch_bounds__(256) void front_kernel(
    const float* __restrict__ x,
    const float* __restrict__ emW0, const float* __restrict__ emB0,
    const float* __restrict__ emW1, const float* __restrict__ emB1,
    const float* __restrict__ emW2, const float* __restrict__ emB2,
    const float* __restrict__ vW, const float* __restrict__ vb,
    const float* __restrict__ crW0, const float* __restrict__ crB0,
    const float* __restrict__ crW1, const float* __restrict__ crB1,
    const float* __restrict__ crW2, const float* __restrict__ crB2,
    const float* __restrict__ tmW0, const float* __restrict__ tmB0,
    const float* __restrict__ tmW1, const float* __restrict__ tmB1,
    const float* __restrict__ tmW2, const float* __restrict__ tmB2,
    short* __restrict__ planes, float* __restrict__ w5, float* __restrict__ b5,
    float* __restrict__ vout, float* __restrict__ s1, float* __restrict__ rews0)
{
    __shared__ __align__(16) char smem[24704];
    const int blk = blockIdx.x;
    const int tid = threadIdx.x;

    if (blk < 64) {
        const int mat = blk >> 3;
        const int kk  = blk & 7;
        const float* W;
        switch (mat) {
            case 0: W = crW0; break;
            case 1: W = crW1; break;
            case 2: W = tmW0; break;
            case 3: W = tmW1; break;
            case 4: W = tmW2; break;
            case 5: W = emW0; break;
            case 6: W = emW1; break;
            default: W = emW2; break;
        }
        const int col = tid;
        short bh[32], bm[32], bl[32];
#pragma unroll
        for (int j = 0; j < 32; ++j) {
            float w = W[(kk * 32 + j) * 256 + col];
            unsigned short h = f2bf(w); float fh = bf2f(h);
            float r1 = w - fh;
            unsigned short m = f2bf(r1); float fm = bf2f(m);
            bh[j] = (short)h; bm[j] = (short)m; bl[j] = (short)f2bf(r1 - fm);
        }
        short* pH = planes + (size_t)(mat * 3 + 0) * PL + kk * 8192 + col * 32;
        short* pM = planes + (size_t)(mat * 3 + 1) * PL + kk * 8192 + col * 32;
        short* pLp = planes + (size_t)(mat * 3 + 2) * PL + kk * 8192 + col * 32;
#pragma unroll
        for (int j = 0; j < 32; j += 4) {
            *(short4*)(pH + j) = make_short4(bh[j], bh[j+1], bh[j+2], bh[j+3]);
            *(short4*)(pM + j) = make_short4(bm[j], bm[j+1], bm[j+2], bm[j+3]);
            *(short4*)(pLp + j) = make_short4(bl[j], bl[j+1], bl[j+2], bl[j+3]);
        }
        // 32x32 layout copies
        int p32 = -1, np32 = 0;
        if (mat == 3) { p32 = 0; np32 = 2; }
        else if (mat == 4) { p32 = 2; np32 = 2; }
        else if (mat == 5) { p32 = 4; np32 = 2; }
        else if (mat == 6) { p32 = 6; np32 = 2; }
        else if (mat == 1) { p32 = 8; np32 = 3; }
        if (p32 >= 0) {
            short* qH = planes + P32 + (size_t)p32 * PL;
            short* qM = qH + PL;
            short* qL = qM + PL;
#pragma unroll
            for (int j = 0; j < 32; j += 4) {
                int off = (2 * kk + (j >> 4)) * 4096 + col * 16 + (j & 15);
                *(short4*)(qH + off) = make_short4(bh[j], bh[j+1], bh[j+2], bh[j+3]);
                *(short4*)(qM + off) = make_short4(bm[j], bm[j+1], bm[j+2], bm[j+3]);
                if (np32 == 3)
                    *(short4*)(qL + off) = make_short4(bl[j], bl[j+1], bl[j+2], bl[j+3]);
            }
        }
    } else if (blk == 64) {
        float acc = 0.f;
        for (int j = 0; j < 256; j += 4) {
            float4 wrow = *(const float4*)(emW2 + tid * 256 + j);
            float4 vv   = *(const float4*)(vW + j);
            acc += wrow.x * vv.x + wrow.y * vv.y + wrow.z * vv.z + wrow.w * vv.w;
        }
        w5[tid] = acc;
        if (tid == 0) {
            float b = 0.f;
            for (int j = 0; j < 256; ++j) b += emB2[j] * vW[j];
            b5[0] = b + vb[0];
        }
    } else if (blk < 73) {
        constexpr int TM = 4;
        float* bufA = (float*)smem;
        float* bufB = bufA + TM * DD;
        float* bufC = bufB + TM * DD;
        const int row0 = (blk - 65) * TM;
        for (int i = 0; i < TM; ++i) bufA[i * DD + tid] = x[(row0 + i) * DD + tid];
        __syncthreads();
        layer256<TM, true >(emW0, emB0, bufA, 256, DD, bufB, DD); __syncthreads();
        layer256<TM, true >(emW1, emB1, bufB, 256, DD, bufC, DD); __syncthreads();
        layer256<TM, false>(emW2, emB2, bufC, 256, DD, bufB, DD); __syncthreads();
        head1c<TM>(bufB, DD, vW, 1, 0, vb[0], vout, row0);
    } else {
        constexpr int TM = 8;
        float* bufA = (float*)smem;                // [TM][LDA]
        float* bufB = bufA + TM * LDA;             // [TM][DD]
        float* bufC = bufB + TM * DD;              // [TM][DD]
        const int row0 = (blk - 73) * TM;
        for (int i = 0; i < TM; ++i) bufA[i * LDA + tid] = x[((row0 + i) / 15) * DD + tid];
        if (tid < TM) bufA[tid * LDA + DD] = (float)((row0 + tid) % 15);
        __syncthreads();
        layer256<TM, true >(crW0, crB0, bufA, 257, LDA, bufB, DD); __syncthreads();
        layer256<TM, true >(crW1, crB1, bufB, 256, DD, bufC, DD); __syncthreads();
        head1c<TM>(bufC, DD, crW2, 2, 1, crB2[1], rews0, row0);
        layer256<TM, true >(tmW0, tmB0, bufA, 257, LDA, bufB, DD); __syncthreads();
        layer256<TM, true >(tmW1, tmB1, bufB, 256, DD, bufC, DD); __syncthreads();
        layer256<TM, false>(tmW2, tmB2, bufC, 256, DD, bufB, DD); __syncthreads();
        for (int i = 0; i < TM; ++i) s1[(row0 + i) * DD + tid] = bufB[i * DD + tid];
    }
}

__global__ __launch_bounds__(256) void finalize_kernel(
    const float* __restrict__ Vns3, const float* __restrict__ cont2,
    const float* __restrict__ rews0, const float* __restrict__ rews1,
    const float* __restrict__ cont1, float* __restrict__ out)
{
    const int b = blockIdx.x;
    const int tid = threadIdx.x;
    __shared__ float vs2[NA][NA];
    __shared__ float vs3[NA];
    if (tid < NA * NA) {
        const int x = tid / NA, y = tid % NA;
        float vals[NA];
        float m = -INFINITY;
#pragma unroll
        for (int z = 0; z < NA; ++z) {
            int vidx = ((b * NA + y) * NA + z) * NA + x;
            int cidx = ((b * NA + x) * NA + y) * NA + z;
            float c1 = rews0[b * NA + z] * 0.99f;
            float c2 = (c1 + rews1[(b * NA + x) * NA + z]) * 0.99f;
            float v = Vns3[vidx] * 0.970299f + c2;
            if (cont2[cidx] > 0.f) v = 0.f;
            vals[z] = v;
            m = fmaxf(m, v);
        }
        float se = 0.f, sw = 0.f;
#pragma unroll
        for (int z = 0; z < NA; ++z) { float e = expf(vals[z] - m); se += e; sw += e * vals[z]; }
        vs2[x][y] = sw / se;
    }
    __syncthreads();
    if (tid < NA) {
        const int x = tid;
        float vals[NA];
        float m = -INFINITY;
#pragma unroll
        for (int y = 0; y < NA; ++y) {
            float v = vs2[x][y];
            if (cont1[(b * NA + x) * NA + y] > 0.f) v = 0.f;
            vals[y] = v;
            m = fmaxf(m, v);
        }
        float se = 0.f, sw = 0.f;
#pragma unroll
        for (int y = 0; y < NA; ++y) { float e = expf(vals[y] - m); se += e; sw += e * vals[y]; }
        vs3[x] = sw / se;
    }
    __syncthreads();
    if (tid == 0) {
        float m = -INFINITY;
#pragma unroll
        for (int x = 0; x < NA; ++x) m = fmaxf(m, vs3[x]);
        float se = 0.f;
#pragma unroll
        for (int x = 0; x < NA; ++x) se += expf(vs3[x] - m);
        float l = logf(se);
#pragma unroll
        for (int x = 0; x < NA; ++x) out[b * NA + x] = vs3[x] - m - l;
    }
}

// ---------------------------------------------------------------------------
// mm3 (16x16x32 path): RT row-tiles x 4 col-tiles over K=256, NP passes.
// ---------------------------------------------------------------------------
template<int RT, int NP>
__device__ __forceinline__ void mm3(
    const short* __restrict__ plH, const short* __restrict__ plM, const short* __restrict__ plL,
    const short* actH, const short* actM, const short* actL,
    f32x4 (&acc)[4][RT])
{
    const int tid = threadIdx.x;
    const int ln15 = tid & 15, lng = (tid >> 4) & 3, wv = tid >> 6;
    const int wo = (wv * 64 + ln15) * 32 + lng * 8;
#pragma unroll
    for (int kk = 0; kk < 8; ++kk) {
        bf16x8 wH[4], wM[4], wL[4], xH[RT], xM[RT], xL[RT];
#pragma unroll
        for (int ct = 0; ct < 4; ++ct) {
            wH[ct] = *(const bf16x8*)(plH + wo + kk * 8192 + ct * 512);
            wM[ct] = *(const bf16x8*)(plM + wo + kk * 8192 + ct * 512);
            if (NP == 6) wL[ct] = *(const bf16x8*)(plL + wo + kk * 8192 + ct * 512);
        }
#pragma unroll
        for (int rt = 0; rt < RT; ++rt) {
            int off = (rt * 16 + ln15) * ASTR + kk * 32 + lng * 8;
            xH[rt] = *(const bf16x8*)(actH + off);
            xM[rt] = *(const bf16x8*)(actM + off);
            if (NP == 6) xL[rt] = *(const bf16x8*)(actL + off);
        }
        __builtin_amdgcn_s_setprio(1);
#pragma unroll
        for (int ct = 0; ct < 4; ++ct)
#pragma unroll
            for (int rt = 0; rt < RT; ++rt) {
                acc[ct][rt] = __builtin_amdgcn_mfma_f32_16x16x32_bf16(wH[ct], xH[rt], acc[ct][rt], 0, 0, 0);
                acc[ct][rt] = __builtin_amdgcn_mfma_f32_16x16x32_bf16(wH[ct], xM[rt], acc[ct][rt], 0, 0, 0);
                acc[ct][rt] = __builtin_amdgcn_mfma_f32_16x16x32_bf16(wM[ct], xH[rt], acc[ct][rt], 0, 0, 0);
                if (NP == 6) {
                    acc[ct][rt] = __builtin_amdgcn_mfma_f32_16x16x32_bf16(wM[ct], xM[rt], acc[ct][rt], 0, 0, 0);
                    acc[ct][rt] = __builtin_amdgcn_mfma_f32_16x16x32_bf16(wH[ct], xL[rt], acc[ct][rt], 0, 0, 0);
                    acc[ct][rt] = __builtin_amdgcn_mfma_f32_16x16x32_bf16(wL[ct], xH[rt], acc[ct][rt], 0, 0, 0);
                }
            }
        __builtin_amdgcn_s_setprio(0);
    }
}

// stage a 3-way-split activation row block from U + a*wrow + bias (relu)
template<int ROWS>
__device__ __forceinline__ void stage3w(
    const float* __restrict__ U, const float* __restrict__ wrow256,
    const float* __restrict__ bias, int row0,
    short* actH, short* actM, short* actL)
{
    const int tid = threadIdx.x;
    const int wv = tid >> 6, ln = tid & 63;
    constexpr int RPW = ROWS / 4;
    const float4 wr = *(const float4*)(wrow256 + ln * 4);
    const float4 bb = *(const float4*)(bias + ln * 4);
    for (int i = wv * RPW; i < wv * RPW + RPW; ++i) {
        int r = row0 + i;
        int srow = r / 15;
        float a = (float)(r % 15);
        float4 u = *(const float4*)(U + srow * 256 + ln * 4);
        float sv[4];
        sv[0] = fmaxf(u.x + a * wr.x + bb.x, 0.f);
        sv[1] = fmaxf(u.y + a * wr.y + bb.y, 0.f);
        sv[2] = fmaxf(u.z + a * wr.z + bb.z, 0.f);
        sv[3] = fmaxf(u.w + a * wr.w + bb.w, 0.f);
        split3_write(sv, actH + i * ASTR + ln * 4, actM + i * ASTR + ln * 4, actL + i * ASTR + ln * 4);
    }
}

// ---------------------------------------------------------------------------
// u2_kernel: U2cr = s1 @ crW0[:256], U2tm = s1 @ tmW0[:256], both 6-pass.
// ---------------------------------------------------------------------------
__global__ __launch_bounds__(256, 1) void u2_kernel(
    const float* __restrict__ s1, const short* __restrict__ planes,
    float* __restrict__ U2cr, float* __restrict__ U2tm)
{
    __shared__ short actH[64 * ASTR];
    __shared__ short actM[64 * ASTR];
    __shared__ short actL[64 * ASTR];
    const int tid = threadIdx.x;
    const int row0 = blockIdx.x * 64;
    const int wv = tid >> 6, ln = tid & 63;
    const int ln15 = tid & 15, lng = (tid >> 4) & 3;
    for (int i = wv * 16; i < wv * 16 + 16; ++i) {
        int srow = row0 + i; if (srow > 479) srow = 479;
        float4 s = *(const float4*)(s1 + srow * 256 + ln * 4);
        float sv[4] = {s.x, s.y, s.z, s.w};
        split3_write(sv, actH + i * ASTR + ln * 4, actM + i * ASTR + ln * 4, actL + i * ASTR + ln * 4);
    }
    __syncthreads();
    f32x4 acc[4][4];
#pragma unroll
    for (int a = 0; a < 4; ++a)
#pragma unroll
        for (int b = 0; b < 4; ++b) acc[a][b] = f32x4{0.f,0.f,0.f,0.f};
    mm3<4, 6>(planes + 0*PL, planes + 1*PL, planes + 2*PL, actH, actM, actL, acc);
#pragma unroll
    for (int ct = 0; ct < 4; ++ct)
#pragma unroll
        for (int rt = 0; rt < 4; ++rt) {
            int r = row0 + rt * 16 + ln15;
            if (r < 480) {
                float4 o; o.x = acc[ct][rt][0]; o.y = acc[ct][rt][1];
                o.z = acc[ct][rt][2]; o.w = acc[ct][rt][3];
                *(float4*)(U2cr + r * 256 + wv * 64 + ct * 16 + lng * 4) = o;
            }
        }
#pragma unroll
    for (int a = 0; a < 4; ++a)
#pragma unroll
        for (int b = 0; b < 4; ++b) acc[a][b] = f32x4{0.f,0.f,0.f,0.f};
    mm3<4, 6>(planes + 6*PL, planes + 7*PL, planes + 8*PL, actH, actM, actL, acc);
#pragma unroll
    for (int ct = 0; ct < 4; ++ct)
#pragma unroll
        for (int rt = 0; rt < 4; ++rt) {
            int r = row0 + rt * 16 + ln15;
            if (r < 480) {
                float4 o; o.x = acc[ct][rt][0]; o.y = acc[ct][rt][1];
                o.z = acc[ct][rt][2]; o.w = acc[ct][rt][3];
                *(float4*)(U2tm + r * 256 + wv * 64 + ct * 16 + lng * 4) = o;
            }
        }
}

// ---------------------------------------------------------------------------
// stage2m: 7200 rows, 225 blocks x 32 rows. cont1/rews1 + Ucr/Utm (permuted).
// ---------------------------------------------------------------------------
__global__ __launch_bounds__(256, 2) void stage2m_kernel(
    const float* __restrict__ U2cr, const float* __restrict__ U2tm,
    const short* __restrict__ planes,
    const float* __restrict__ crW0, const float* __restrict__ crB0,
    const float* __restrict__ crB1, const float* __restrict__ crW2, const float* __restrict__ crB2,
    const float* __restrict__ tmW0, const float* __restrict__ tmB0,
    const float* __restrict__ tmB1, const float* __restrict__ tmB2,
    float* __restrict__ cont1, float* __restrict__ rews1,
    float* __restrict__ Ucr, float* __restrict__ Utm)
{
    __shared__ short actH[32 * ASTR];
    __shared__ short actM[32 * ASTR];
    __shared__ short actL[32 * ASTR];
    __shared__ float hred[2][128];
    const int tid = threadIdx.x;
    const int row0 = blockIdx.x * 32;
    const int ln15 = tid & 15, lng = (tid >> 4) & 3, wv = tid >> 6;

    // ---- Phase A: cr chain -> cont1, rews1 ----
    stage3w<32>(U2cr, crW0 + 65536, crB0, row0, actH, actM, actL);
    __syncthreads();
    {
        f32x4 acc[4][2];
#pragma unroll
        for (int a = 0; a < 4; ++a) { acc[a][0] = f32x4{0.f,0.f,0.f,0.f}; acc[a][1] = f32x4{0.f,0.f,0.f,0.f}; }
        mm3<2, 6>(planes + 3*PL, planes + 4*PL, planes + 5*PL, actH, actM, actL, acc);
        float hp0[2] = {0.f,0.f}, hp1[2] = {0.f,0.f};
#pragma unroll
        for (int ct = 0; ct < 4; ++ct) {
            const int colb = wv * 64 + ct * 16 + lng * 4;
            const float4 b1 = *(const float4*)(crB1 + colb);
#pragma unroll
            for (int rt = 0; rt < 2; ++rt) {
                f32x4 v = acc[ct][rt];
                v[0] += b1.x; v[1] += b1.y; v[2] += b1.z; v[3] += b1.w;
#pragma unroll
                for (int j = 0; j < 4; ++j) v[j] = fmaxf(v[j], 0.f);
#pragma unroll
                for (int j = 0; j < 4; ++j) {
                    hp0[rt] += v[j] * crW2[(colb + j) * 2 + 0];
                    hp1[rt] += v[j] * crW2[(colb + j) * 2 + 1];
                }
            }
        }
#pragma unroll
        for (int rt = 0; rt < 2; ++rt) {
            hp0[rt] += __shfl_xor(hp0[rt], 16); hp0[rt] += __shfl_xor(hp0[rt], 32);
            hp1[rt] += __shfl_xor(hp1[rt], 16); hp1[rt] += __shfl_xor(hp1[rt], 32);
        }
        if (lng == 0) {
#pragma unroll
            for (int rt = 0; rt < 2; ++rt) {
                hred[0][wv * 32 + rt * 16 + ln15] = hp0[rt];
                hred[1][wv * 32 + rt * 16 + ln15] = hp1[rt];
            }
        }
        __syncthreads();
        if (tid < 32)
            cont1[row0 + tid] = hred[0][tid] + hred[0][32 + tid] + hred[0][64 + tid] + hred[0][96 + tid] + crB2[0];
        else if (tid >= 64 && tid < 96)
            rews1[row0 + tid - 64] = hred[1][tid - 64] + hred[1][32 + tid - 64] + hred[1][64 + tid - 64] + hred[1][96 + tid - 64] + crB2[1];
        __syncthreads();
    }

    // ---- Phase B: tm chain -> s2 (LDS) -> Ucr, Utm ----
    stage3w<32>(U2tm, tmW0 + 65536, tmB0, row0, actH, actM, actL);
    __syncthreads();
#pragma unroll
    for (int layer = 0; layer < 2; ++layer) {
        const short* pB = planes + (layer == 0 ? 9 : 12) * PL;
        const float* bias = (layer == 0) ? tmB1 : tmB2;
        f32x4 acc[4][2];
#pragma unroll
        for (int a = 0; a < 4; ++a) { acc[a][0] = f32x4{0.f,0.f,0.f,0.f}; acc[a][1] = f32x4{0.f,0.f,0.f,0.f}; }
        mm3<2, 6>(pB, pB + PL, pB + 2*PL, actH, actM, actL, acc);
        __syncthreads();
#pragma unroll
        for (int ct = 0; ct < 4; ++ct) {
            const int colb = wv * 64 + ct * 16 + lng * 4;
            const float4 bb = *(const float4*)(bias + colb);
#pragma unroll
            for (int rt = 0; rt < 2; ++rt) {
                f32x4 v = acc[ct][rt];
                v[0] += bb.x; v[1] += bb.y; v[2] += bb.z; v[3] += bb.w;
                if (layer == 0) {
#pragma unroll
                    for (int j = 0; j < 4; ++j) v[j] = fmaxf(v[j], 0.f);
                }
                float sv[4] = {v[0], v[1], v[2], v[3]};
                const int ao = (rt * 16 + ln15) * ASTR + colb;
                split3_write(sv, actH + ao, actM + ao, actL + ao);
            }
        }
        __syncthreads();
    }
    int pr[2];
#pragma unroll
    for (int rt = 0; rt < 2; ++rt) {
        int r = row0 + rt * 16 + ln15;
        int b = r / 225, a1 = (r / 15) % 15, a2 = r % 15;
        pr[rt] = (b * 15 + a2) * 15 + a1;
    }
    {
        f32x4 acc[4][2];
#pragma unroll
        for (int a = 0; a < 4; ++a) { acc[a][0] = f32x4{0.f,0.f,0.f,0.f}; acc[a][1] = f32x4{0.f,0.f,0.f,0.f}; }
        mm3<2, 6>(planes + 0*PL, planes + 1*PL, planes + 2*PL, actH, actM, actL, acc);
#pragma unroll
        for (int ct = 0; ct < 4; ++ct)
#pragma unroll
            for (int rt = 0; rt < 2; ++rt) {
                float4 o; o.x = acc[ct][rt][0]; o.y = acc[ct][rt][1];
                o.z = acc[ct][rt][2]; o.w = acc[ct][rt][3];
                *(float4*)(Ucr + pr[rt] * 256 + wv * 64 + ct * 16 + lng * 4) = o;
            }
    }
    {
        f32x4 acc[4][2];
#pragma unroll
        for (int a = 0; a < 4; ++a) { acc[a][0] = f32x4{0.f,0.f,0.f,0.f}; acc[a][1] = f32x4{0.f,0.f,0.f,0.f}; }
        mm3<2, 3>(planes + 6*PL, planes + 7*PL, planes + 8*PL, actH, actM, actL, acc);
#pragma unroll
        for (int ct = 0; ct < 4; ++ct)
#pragma unroll
            for (int rt = 0; rt < 2; ++rt) {
                float4 o; o.x = acc[ct][rt][0]; o.y = acc[ct][rt][1];
                o.z = acc[ct][rt][2]; o.w = acc[ct][rt][3];
                *(float4*)(Utm + pr[rt] * 256 + wv * 64 + ct * 16 + lng * 4) = o;
            }
    }
}

// ---------------------------------------------------------------------------
// layer32: 32x32x16 2-way 3-pass layer, PASS-SPLIT accumulators (one MFMA per
// acc per kk -> 6 independent chains, no accumulator dependency stalls).
// ---------------------------------------------------------------------------
template<bool RELU, bool HEAD, bool WRITEACT>
__device__ __forceinline__ void layer32(
    const short* __restrict__ plH, const short* __restrict__ plM,
    const float* __restrict__ bias,
    const float* __restrict__ headW, const float* __restrict__ headB,
    float* __restrict__ headOut, int row0,
    short* actH, short* actL, float* hred)
{
    const int tid = threadIdx.x;
    const int ln31 = tid & 31, hi = (tid >> 5) & 1, wv = tid >> 6;
    f32x16 acc[3][2];
#pragma unroll
    for (int p = 0; p < 3; ++p)
#pragma unroll
        for (int ct = 0; ct < 2; ++ct)
#pragma unroll
            for (int e = 0; e < 16; ++e) acc[p][ct][e] = 0.f;

#pragma unroll
    for (int kk = 0; kk < 16; ++kk) {
        bf16x8 aH[2], aM[2], bH, bL;
#pragma unroll
        for (int ct = 0; ct < 2; ++ct) {
            int off = kk * 4096 + (wv * 64 + ct * 32 + ln31) * 16 + hi * 8;
            aH[ct] = *(const bf16x8*)(plH + off);
            aM[ct] = *(const bf16x8*)(plM + off);
        }
        {
            int boff = ln31 * ASTR + kk * 16 + hi * 8;
            bH = *(const bf16x8*)(actH + boff);
            bL = *(const bf16x8*)(actL + boff);
        }
        __builtin_amdgcn_s_setprio(1);
#pragma unroll
        for (int ct = 0; ct < 2; ++ct) {
            acc[0][ct] = __builtin_amdgcn_mfma_f32_32x32x16_bf16(aH[ct], bH, acc[0][ct], 0, 0, 0);
            acc[1][ct] = __builtin_amdgcn_mfma_f32_32x32x16_bf16(aH[ct], bL, acc[1][ct], 0, 0, 0);
            acc[2][ct] = __builtin_amdgcn_mfma_f32_32x32x16_bf16(aM[ct], bH, acc[2][ct], 0, 0, 0);
        }
        __builtin_amdgcn_s_setprio(0);
    }
    __syncthreads();   // all act reads done before in-place overwrite

    float hp = 0.f;
#pragma unroll
    for (int ct = 0; ct < 2; ++ct) {
#pragma unroll
        for (int g = 0; g < 4; ++g) {
            const int col0 = wv * 64 + ct * 32 + g * 8 + hi * 4;
            const float4 bb = *(const float4*)(bias + col0);
            float v[4];
#pragma unroll
            for (int q = 0; q < 4; ++q)
                v[q] = acc[0][ct][g * 4 + q] + acc[1][ct][g * 4 + q] + acc[2][ct][g * 4 + q];
            v[0] += bb.x; v[1] += bb.y; v[2] += bb.z; v[3] += bb.w;
            if (RELU) {
#pragma unroll
                for (int q = 0; q < 4; ++q) v[q] = fmaxf(v[q], 0.f);
            }
            if (HEAD) {
                const float4 hw = *(const float4*)(headW + col0);
                hp += v[0] * hw.x + v[1] * hw.y + v[2] * hw.z + v[3] * hw.w;
            }
            if (WRITEACT) {
                const int ao = ln31 * ASTR + col0;
                split2_write(v, actH + ao, actL + ao);
            }
        }
    }
    if constexpr (HEAD) {
        hp += __shfl_xor(hp, 32);
        if (hi == 0) hred[wv * 32 + ln31] = hp;
        __syncthreads();
        if (tid < 32)
            headOut[row0 + tid] = hred[tid] + hred[32 + tid] + hred[64 + tid] + hred[96 + tid] + headB[0];
    }
    if constexpr (WRITEACT) __syncthreads();
}

// ---------------------------------------------------------------------------
// k3ab: fused stage-3, 32x32x16 with pass-split accumulators.
// 6750 blocks: even -> k3b (32-row), odd -> k3a (32-row).
// ---------------------------------------------------------------------------
__global__ __launch_bounds__(256, 3) void k3ab_kernel(
    const float* __restrict__ Ucr, const float* __restrict__ Utm,
    const short* __restrict__ planes,
    const float* __restrict__ crW0, const float* __restrict__ crB0,
    const float* __restrict__ crB1, const float* __restrict__ crW2,
    const float* __restrict__ crB2,
    const float* __restrict__ tmW0, const float* __restrict__ tmB0,
    const float* __restrict__ tmB1, const float* __restrict__ tmB2,
    const float* __restrict__ emB0, const float* __restrict__ emB1,
    const float* __restrict__ w5, const float* __restrict__ b5,
    float* __restrict__ cont2, float* __restrict__ Vns3)
{
    __shared__ short lds[3 * 32 * ASTR];
    __shared__ float hred[128];
    const int tid = threadIdx.x;
    const bool isB = (blockIdx.x & 1) == 0;
    const int row0 = (blockIdx.x >> 1) * 32;
    const int ln31 = tid & 31, hi = (tid >> 5) & 1, wv = tid >> 6;
    const short* Q = planes + P32;

    if (isB) {
        // ---- k3b: tm1, tm2, em0, em1+head(w5) ----
        short* actH = lds;
        short* actL = lds + 32 * ASTR;
        const int ln = tid & 63;
        const float4 wr = *(const float4*)(tmW0 + 65536 + ln * 4);
        const float4 bb = *(const float4*)(tmB0 + ln * 4);
        for (int i = wv * 8; i < wv * 8 + 8; ++i) {
            int r = row0 + i;
            int srow = r / 15;
            float a = (float)(r % 15);
            float4 u = *(const float4*)(Utm + srow * 256 + ln * 4);
            float sv[4];
            sv[0] = fmaxf(u.x + a * wr.x + bb.x, 0.f);
            sv[1] = fmaxf(u.y + a * wr.y + bb.y, 0.f);
            sv[2] = fmaxf(u.z + a * wr.z + bb.z, 0.f);
            sv[3] = fmaxf(u.w + a * wr.w + bb.w, 0.f);
            split2_write(sv, actH + i * ASTR + ln * 4, actL + i * ASTR + ln * 4);
        }
        __syncthreads();
        layer32<true,  false, true >(Q + 0 * PL, Q + 1 * PL, tmB1, nullptr, nullptr, nullptr, row0, actH, actL, hred);
        layer32<false, false, true >(Q + 2 * PL, Q + 3 * PL, tmB2, nullptr, nullptr, nullptr, row0, actH, actL, hred);
        layer32<true,  false, true >(Q + 4 * PL, Q + 5 * PL, emB0, nullptr, nullptr, nullptr, row0, actH, actL, hred);
        layer32<true,  true,  false>(Q + 6 * PL, Q + 7 * PL, emB1, w5, b5, Vns3, row0, actH, actL, hred);
    } else {
        // ---- k3a: stage 3-way, crW1 6-pass 32x32 (pass-split accs), head ----
        short* actH = lds;
        short* actM = lds + 32 * ASTR;
        short* actL = lds + 2 * 32 * ASTR;
        stage3w<32>(Ucr, crW0 + 65536, crB0, row0, actH, actM, actL);
        __syncthreads();
        f32x16 acc[3][2];
#pragma unroll
        for (int p = 0; p < 3; ++p)
#pragma unroll
            for (int ct = 0; ct < 2; ++ct)
#pragma unroll
                for (int e = 0; e < 16; ++e) acc[p][ct][e] = 0.f;
#pragma unroll
        for (int kk = 0; kk < 16; ++kk) {
            bf16x8 aH[2], aM[2], aL[2], bH, bM, bL;
#pragma unroll
            for (int ct = 0; ct < 2; ++ct) {
                int off = kk * 4096 + (wv * 64 + ct * 32 + ln31) * 16 + hi * 8;
                aH[ct] = *(const bf16x8*)(Q + 8 * PL + off);
                aM[ct] = *(const bf16x8*)(Q + 9 * PL + off);
                aL[ct] = *(const bf16x8*)(Q + 10 * PL + off);
            }
            {
                int boff = ln31 * ASTR + kk * 16 + hi * 8;
                bH = *(const bf16x8*)(actH + boff);
                bM = *(const bf16x8*)(actM + boff);
                bL = *(const bf16x8*)(actL + boff);
            }
            __builtin_amdgcn_s_setprio(1);
            // 12 MFMAs ordered so same-acc writes are 6 apart
#pragma unroll
            for (int ct = 0; ct < 2; ++ct)
                acc[0][ct] = __builtin_amdgcn_mfma_f32_32x32x16_bf16(aH[ct], bH, acc[0][ct], 0, 0, 0);
#pragma unroll
            for (int ct = 0; ct < 2; ++ct)
                acc[1][ct] = __builtin_amdgcn_mfma_f32_32x32x16_bf16(aH[ct], bM, acc[1][ct], 0, 0, 0);
#pragma unroll
            for (int ct = 0; ct < 2; ++ct)
                acc[2][ct] = __builtin_amdgcn_mfma_f32_32x32x16_bf16(aM[ct], bH, acc[2][ct], 0, 0, 0);
#pragma unroll
            for (int ct = 0; ct < 2; ++ct)
                acc[0][ct] = __builtin_amdgcn_mfma_f32_32x32x16_bf16(aM[ct], bM, acc[0][ct], 0, 0, 0);
#pragma unroll
            for (int ct = 0; ct < 2; ++ct)
                acc[1][ct] = __builtin_amdgcn_mfma_f32_32x32x16_bf16(aH[ct], bL, acc[1][ct], 0, 0, 0);
#pragma unroll
            for (int ct = 0; ct < 2; ++ct)
                acc[2][ct] = __builtin_amdgcn_mfma_f32_32x32x16_bf16(aL[ct], bH, acc[2][ct], 0, 0, 0);
            __builtin_amdgcn_s_setprio(0);
        }
        float hp = 0.f;
#pragma unroll
        for (int ct = 0; ct < 2; ++ct) {
#pragma unroll
            for (int g = 0; g < 4; ++g) {
                const int col0 = wv * 64 + ct * 32 + g * 8 + hi * 4;
                const float4 b1 = *(const float4*)(crB1 + col0);
                float v[4];
#pragma unroll
                for (int q = 0; q < 4; ++q)
                    v[q] = acc[0][ct][g * 4 + q] + acc[1][ct][g * 4 + q] + acc[2][ct][g * 4 + q];
                v[0] += b1.x; v[1] += b1.y; v[2] += b1.z; v[3] += b1.w;
#pragma unroll
                for (int q = 0; q < 4; ++q) v[q] = fmaxf(v[q], 0.f);
#pragma unroll
                for (int q = 0; q < 4; ++q) hp += v[q] * crW2[(col0 + q) * 2];
            }
        }
        hp += __shfl_xor(hp, 32);
        if (hi == 0) hred[wv * 32 + ln31] = hp;
        __syncthreads();
        if (tid < 32)
            cont2[row0 + tid] = hred[tid] + hred[32 + tid] + hred[64 + tid] + hred[96 + tid] + crB2[0];
    }
}

extern "C" void kernel_launch(void* const* d_in, const int* in_sizes, int n_in,
                              void* d_out, int out_size, void* d_ws, size_t ws_size,
                              hipStream_t stream)
{
    (void)in_sizes; (void)n_in; (void)out_size; (void)ws_size;
    const float* x    = (const float*)d_in[0];
    const float* emW0 = (const float*)d_in[1];
    const float* emB0 = (const float*)d_in[2];
    const float* emW1 = (const float*)d_in[3];
    const float* emB1 = (const float*)d_in[4];
    const float* emW2 = (const float*)d_in[5];
    const float* emB2 = (const float*)d_in[6];
    const float* vW   = (const float*)d_in[7];
    const float* vb   = (const float*)d_in[8];
    const float* crW0 = (const float*)d_in[9];
    const float* crB0 = (const float*)d_in[10];
    const float* crW1 = (const float*)d_in[11];
    const float* crB1 = (const float*)d_in[12];
    const float* crW2 = (const float*)d_in[13];
    const float* crB2 = (const float*)d_in[14];
    const float* tmW0 = (const float*)d_in[15];
    const float* tmB0 = (const float*)d_in[16];
    const float* tmW1 = (const float*)d_in[17];
    const float* tmB1 = (const float*)d_in[18];
    const float* tmW2 = (const float*)d_in[19];
    const float* tmB2 = (const float*)d_in[20];
    float* out = (float*)d_out;

    float* w     = (float*)d_ws;
    float* rews0 = w;                     // 480
    float* cont1 = rews0 + 480;           // 7200
    float* rews1 = cont1 + 7200;          // 7200
    float* cont2 = rews1 + 7200;          // 108000
    float* Vns3  = cont2 + 108000;        // 108000
    float* s1    = Vns3 + 108000;         // 480*256
    short* planes = (short*)(s1 + 480 * 256);   // (24 + 11) * PL shorts = 4.4 MB
    float* U2cr  = (float*)(planes + 35 * PL);  // 480*256
    float* U2tm  = U2cr + 480 * 256;            // 480*256
    float* Ucr   = U2tm + 480 * 256;            // 7200*256
    float* Utm   = Ucr + 7200 * 256;            // 7200*256
    float* w5    = Utm + 7200 * 256;            // 256
    float* b5    = w5 + 256;                    // 1

    front_kernel<<<133, 256, 0, stream>>>(x,
        emW0, emB0, emW1, emB1, emW2, emB2, vW, vb,
        crW0, crB0, crW1, crB1, crW2, crB2,
        tmW0, tmB0, tmW1, tmB1, tmW2, tmB2,
        planes, w5, b5, out + NB * NA, s1, rews0);
    u2_kernel<<<8, 256, 0, stream>>>(s1, planes, U2cr, U2tm);
    stage2m_kernel<<<225, 256, 0, stream>>>(U2cr, U2tm, planes,
        crW0, crB0, crB1, crW2, crB2, tmW0, tmB0, tmB1, tmB2,
        cont1, rews1, Ucr, Utm);
    k3ab_kernel<<<6750, 256, 0, stream>>>(Ucr, Utm, planes,
        crW0, crB0, crB1, crW2, crB2,
        tmW0, tmB0, tmB1, tmB2, emB0, emB1, w5, b5, cont2, Vns3);
    finalize_kernel<<<NB, 256, 0, stream>>>(Vns3, cont2, rews0, rews1, cont1, out);
}

// Round 13
// 403.689 us; speedup vs baseline: 1.0799x; 1.0799x over previous
//
#include <hip/hip_runtime.h>

#define NA 15
#define NB 32
#define DD 256
#define LDA 260   // 257 rounded to mult of 4 (fp32 stage1)
#define PL 65536  // shorts per weight plane (8 slices x 256 cols x 32 k)
#define ASTR 264  // act LDS row stride (shorts)

using bf16x8 = __attribute__((ext_vector_type(8))) short;
using f32x4  = __attribute__((ext_vector_type(4))) float;

__device__ __forceinline__ unsigned short f2bf(float f){
  unsigned int u = __float_as_uint(f);
  u = u + 0x7fffu + ((u >> 16) & 1u);
  return (unsigned short)(u >> 16);
}
__device__ __forceinline__ float bf2f(unsigned short h){
  return __uint_as_float(((unsigned int)h) << 16);
}
__device__ __forceinline__ unsigned int cvtpk_bf16(float lo, float hi){
    unsigned int r;
    asm("v_cvt_pk_bf16_f32 %0, %1, %2" : "=v"(r) : "v"(lo), "v"(hi));
    return r;
}
__device__ __forceinline__ void split2_write(const float v[4], short* pH, short* pL){
    unsigned int h01 = cvtpk_bf16(v[0], v[1]);
    unsigned int h23 = cvtpk_bf16(v[2], v[3]);
    float r0 = v[0] - __uint_as_float(h01 << 16);
    float r1 = v[1] - __uint_as_float(h01 & 0xffff0000u);
    float r2 = v[2] - __uint_as_float(h23 << 16);
    float r3 = v[3] - __uint_as_float(h23 & 0xffff0000u);
    unsigned int l01 = cvtpk_bf16(r0, r1);
    unsigned int l23 = cvtpk_bf16(r2, r3);
    *(uint2*)pH = make_uint2(h01, h23);
    *(uint2*)pL = make_uint2(l01, l23);
}
__device__ __forceinline__ void split3_write(const float v[4], short* pH, short* pM, short* pL){
    unsigned int h01 = cvtpk_bf16(v[0], v[1]);
    unsigned int h23 = cvtpk_bf16(v[2], v[3]);
    float r0 = v[0] - __uint_as_float(h01 << 16);
    float r1 = v[1] - __uint_as_float(h01 & 0xffff0000u);
    float r2 = v[2] - __uint_as_float(h23 << 16);
    float r3 = v[3] - __uint_as_float(h23 & 0xffff0000u);
    unsigned int m01 = cvtpk_bf16(r0, r1);
    unsigned int m23 = cvtpk_bf16(r2, r3);
    float s0 = r0 - __uint_as_float(m01 << 16);
    float s1 = r1 - __uint_as_float(m01 & 0xffff0000u);
    float s2 = r2 - __uint_as_float(m23 << 16);
    float s3 = r3 - __uint_as_float(m23 & 0xffff0000u);
    unsigned int l01 = cvtpk_bf16(s0, s1);
    unsigned int l23 = cvtpk_bf16(s2, s3);
    *(uint2*)pH = make_uint2(h01, h23);
    *(uint2*)pM = make_uint2(m01, m23);
    *(uint2*)pL = make_uint2(l01, l23);
}

// ---------------------------------------------------------------------------
// fp32 VALU primitives (value_x / stage1 branches of front kernel)
// ---------------------------------------------------------------------------
template<int TM, bool RELU>
__device__ __forceinline__ void layer256(
    const float* __restrict__ W, const float* __restrict__ bias,
    const float* act, int K, int lda, float* out, int ldo)
{
    constexpr int RPG = TM / 4;
    const int tid = threadIdx.x;
    const int tr = tid >> 6;
    const int tc = tid & 63;
    float acc[RPG][4];
#pragma unroll
    for (int i = 0; i < RPG; ++i) { acc[i][0]=0.f; acc[i][1]=0.f; acc[i][2]=0.f; acc[i][3]=0.f; }
    const float* wp = W + 4 * tc;
    int k = 0;
    for (; k + 4 <= K; k += 4) {
        float4 w0 = *reinterpret_cast<const float4*>(wp + (k + 0) * DD);
        float4 w1 = *reinterpret_cast<const float4*>(wp + (k + 1) * DD);
        float4 w2 = *reinterpret_cast<const float4*>(wp + (k + 2) * DD);
        float4 w3 = *reinterpret_cast<const float4*>(wp + (k + 3) * DD);
#pragma unroll
        for (int i = 0; i < RPG; ++i) {
            float4 a = *reinterpret_cast<const float4*>(act + (RPG * tr + i) * lda + k);
            acc[i][0] += a.x * w0.x + a.y * w1.x + a.z * w2.x + a.w * w3.x;
            acc[i][1] += a.x * w0.y + a.y * w1.y + a.z * w2.y + a.w * w3.y;
            acc[i][2] += a.x * w0.z + a.y * w1.z + a.z * w2.z + a.w * w3.z;
            acc[i][3] += a.x * w0.w + a.y * w1.w + a.z * w2.w + a.w * w3.w;
        }
    }
    for (; k < K; ++k) {
        float4 w0 = *reinterpret_cast<const float4*>(wp + k * DD);
#pragma unroll
        for (int i = 0; i < RPG; ++i) {
            float a = act[(RPG * tr + i) * lda + k];
            acc[i][0] += a * w0.x; acc[i][1] += a * w0.y;
            acc[i][2] += a * w0.z; acc[i][3] += a * w0.w;
        }
    }
    float4 bb = *reinterpret_cast<const float4*>(bias + 4 * tc);
#pragma unroll
    for (int i = 0; i < RPG; ++i) {
        float4 o;
        o.x = acc[i][0] + bb.x; o.y = acc[i][1] + bb.y;
        o.z = acc[i][2] + bb.z; o.w = acc[i][3] + bb.w;
        if (RELU) {
            o.x = fmaxf(o.x, 0.f); o.y = fmaxf(o.y, 0.f);
            o.z = fmaxf(o.z, 0.f); o.w = fmaxf(o.w, 0.f);
        }
        *reinterpret_cast<float4*>(out + (RPG * tr + i) * ldo + 4 * tc) = o;
    }
}

template<int TM>
__device__ __forceinline__ void head1c(
    const float* h, int ldh, const float* __restrict__ W, int wstr, int col, float bias,
    float* __restrict__ gout, int gbase)
{
    const int wv = threadIdx.x >> 6;
    const int lane = threadIdx.x & 63;
    for (int rr = wv; rr < TM; rr += 4) {
        float p = 0.f;
#pragma unroll
        for (int t = 0; t < 4; ++t) {
            int k = lane + 64 * t;
            p += h[rr * ldh + k] * W[k * wstr + col];
        }
#pragma unroll
        for (int m = 1; m < 64; m <<= 1) p += __shfl_xor(p, m);
        if (lane == 0) gout[gbase + rr] = p + bias;
    }
}

// ---------------------------------------------------------------------------
// front_kernel: blocks 0-63 prep (weight split), 64 prep2 (w5,b5),
// 65-72 value_x (TM=4), 73-132 stage1 (TM=8). All mutually independent.
// ---------------------------------------------------------------------------
__global__ __launch_bounds__(256) void front_kernel(
    const float* __restrict__ x,
    const float* __restrict__ emW0, const float* __restrict__ emB0,
    const float* __restrict__ emW1, const float* __restrict__ emB1,
    const float* __restrict__ emW2, const float* __restrict__ emB2,
    const float* __restrict__ vW, const float* __restrict__ vb,
    const float* __restrict__ crW0, const float* __restrict__ crB0,
    const float* __restrict__ crW1, const float* __restrict__ crB1,
    const float* __restrict__ crW2, const float* __restrict__ crB2,
    const float* __restrict__ tmW0, const float* __restrict__ tmB0,
    const float* __restrict__ tmW1, const float* __restrict__ tmB1,
    const float* __restrict__ tmW2, const float* __restrict__ tmB2,
    short* __restrict__ planes, float* __restrict__ w5, float* __restrict__ b5,
    float* __restrict__ vout, float* __restrict__ s1, float* __restrict__ rews0)
{
    __shared__ __align__(16) char smem[24704];
    const int blk = blockIdx.x;
    const int tid = threadIdx.x;

    if (blk < 64) {
        const int mat = blk >> 3;
        const int kk  = blk & 7;
        const float* W;
        switch (mat) {
            case 0: W = crW0; break;
            case 1: W = crW1; break;
            case 2: W = tmW0; break;
            case 3: W = tmW1; break;
            case 4: W = tmW2; break;
            case 5: W = emW0; break;
            case 6: W = emW1; break;
            default: W = emW2; break;
        }
        const int col = tid;
        short bh[32], bm[32], bl[32];
#pragma unroll
        for (int j = 0; j < 32; ++j) {
            float w = W[(kk * 32 + j) * 256 + col];
            unsigned short h = f2bf(w); float fh = bf2f(h);
            float r1 = w - fh;
            unsigned short m = f2bf(r1); float fm = bf2f(m);
            bh[j] = (short)h; bm[j] = (short)m; bl[j] = (short)f2bf(r1 - fm);
        }
        short* pH = planes + (size_t)(mat * 3 + 0) * PL + kk * 8192 + col * 32;
        short* pM = planes + (size_t)(mat * 3 + 1) * PL + kk * 8192 + col * 32;
        short* pLp = planes + (size_t)(mat * 3 + 2) * PL + kk * 8192 + col * 32;
#pragma unroll
        for (int j = 0; j < 32; j += 4) {
            *(short4*)(pH + j) = make_short4(bh[j], bh[j+1], bh[j+2], bh[j+3]);
            *(short4*)(pM + j) = make_short4(bm[j], bm[j+1], bm[j+2], bm[j+3]);
            *(short4*)(pLp + j) = make_short4(bl[j], bl[j+1], bl[j+2], bl[j+3]);
        }
    } else if (blk == 64) {
        float acc = 0.f;
        for (int j = 0; j < 256; j += 4) {
            float4 wrow = *(const float4*)(emW2 + tid * 256 + j);
            float4 vv   = *(const float4*)(vW + j);
            acc += wrow.x * vv.x + wrow.y * vv.y + wrow.z * vv.z + wrow.w * vv.w;
        }
        w5[tid] = acc;
        if (tid == 0) {
            float b = 0.f;
            for (int j = 0; j < 256; ++j) b += emB2[j] * vW[j];
            b5[0] = b + vb[0];
        }
    } else if (blk < 73) {
        constexpr int TM = 4;
        float* bufA = (float*)smem;
        float* bufB = bufA + TM * DD;
        float* bufC = bufB + TM * DD;
        const int row0 = (blk - 65) * TM;
        for (int i = 0; i < TM; ++i) bufA[i * DD + tid] = x[(row0 + i) * DD + tid];
        __syncthreads();
        layer256<TM, true >(emW0, emB0, bufA, 256, DD, bufB, DD); __syncthreads();
        layer256<TM, true >(emW1, emB1, bufB, 256, DD, bufC, DD); __syncthreads();
        layer256<TM, false>(emW2, emB2, bufC, 256, DD, bufB, DD); __syncthreads();
        head1c<TM>(bufB, DD, vW, 1, 0, vb[0], vout, row0);
    } else {
        constexpr int TM = 8;
        float* bufA = (float*)smem;                // [TM][LDA]
        float* bufB = bufA + TM * LDA;             // [TM][DD]
        float* bufC = bufB + TM * DD;              // [TM][DD]
        const int row0 = (blk - 73) * TM;
        for (int i = 0; i < TM; ++i) bufA[i * LDA + tid] = x[((row0 + i) / 15) * DD + tid];
        if (tid < TM) bufA[tid * LDA + DD] = (float)((row0 + tid) % 15);
        __syncthreads();
        layer256<TM, true >(crW0, crB0, bufA, 257, LDA, bufB, DD); __syncthreads();
        layer256<TM, true >(crW1, crB1, bufB, 256, DD, bufC, DD); __syncthreads();
        head1c<TM>(bufC, DD, crW2, 2, 1, crB2[1], rews0, row0);
        layer256<TM, true >(tmW0, tmB0, bufA, 257, LDA, bufB, DD); __syncthreads();
        layer256<TM, true >(tmW1, tmB1, bufB, 256, DD, bufC, DD); __syncthreads();
        layer256<TM, false>(tmW2, tmB2, bufC, 256, DD, bufB, DD); __syncthreads();
        for (int i = 0; i < TM; ++i) s1[(row0 + i) * DD + tid] = bufB[i * DD + tid];
    }
}

__global__ __launch_bounds__(256) void finalize_kernel(
    const float* __restrict__ Vns3, const float* __restrict__ cont2,
    const float* __restrict__ rews0, const float* __restrict__ rews1,
    const float* __restrict__ cont1, float* __restrict__ out)
{
    const int b = blockIdx.x;
    const int tid = threadIdx.x;
    __shared__ float vs2[NA][NA];
    __shared__ float vs3[NA];
    if (tid < NA * NA) {
        const int x = tid / NA, y = tid % NA;
        float vals[NA];
        float m = -INFINITY;
#pragma unroll
        for (int z = 0; z < NA; ++z) {
            int vidx = ((b * NA + y) * NA + z) * NA + x;
            int cidx = ((b * NA + x) * NA + y) * NA + z;
            float c1 = rews0[b * NA + z] * 0.99f;
            float c2 = (c1 + rews1[(b * NA + x) * NA + z]) * 0.99f;
            float v = Vns3[vidx] * 0.970299f + c2;
            if (cont2[cidx] > 0.f) v = 0.f;
            vals[z] = v;
            m = fmaxf(m, v);
        }
        float se = 0.f, sw = 0.f;
#pragma unroll
        for (int z = 0; z < NA; ++z) { float e = expf(vals[z] - m); se += e; sw += e * vals[z]; }
        vs2[x][y] = sw / se;
    }
    __syncthreads();
    if (tid < NA) {
        const int x = tid;
        float vals[NA];
        float m = -INFINITY;
#pragma unroll
        for (int y = 0; y < NA; ++y) {
            float v = vs2[x][y];
            if (cont1[(b * NA + x) * NA + y] > 0.f) v = 0.f;
            vals[y] = v;
            m = fmaxf(m, v);
        }
        float se = 0.f, sw = 0.f;
#pragma unroll
        for (int y = 0; y < NA; ++y) { float e = expf(vals[y] - m); se += e; sw += e * vals[y]; }
        vs3[x] = sw / se;
    }
    __syncthreads();
    if (tid == 0) {
        float m = -INFINITY;
#pragma unroll
        for (int x = 0; x < NA; ++x) m = fmaxf(m, vs3[x]);
        float se = 0.f;
#pragma unroll
        for (int x = 0; x < NA; ++x) se += expf(vs3[x] - m);
        float l = logf(se);
#pragma unroll
        for (int x = 0; x < NA; ++x) out[b * NA + x] = vs3[x] - m - l;
    }
}

// ---------------------------------------------------------------------------
// mm3: accumulate RT row-tiles x 4 col-tiles over K=256 with NP passes.
// NP=6: fp32 grade (~1e-6). NP=3: 2-way grade (~5e-5).
// ---------------------------------------------------------------------------
template<int RT, int NP>
__device__ __forceinline__ void mm3(
    const short* __restrict__ plH, const short* __restrict__ plM, const short* __restrict__ plL,
    const short* actH, const short* actM, const short* actL,
    f32x4 (&acc)[4][RT])
{
    const int tid = threadIdx.x;
    const int ln15 = tid & 15, lng = (tid >> 4) & 3, wv = tid >> 6;
    const int wo = (wv * 64 + ln15) * 32 + lng * 8;
#pragma unroll
    for (int kk = 0; kk < 8; ++kk) {
        bf16x8 wH[4], wM[4], wL[4], xH[RT], xM[RT], xL[RT];
#pragma unroll
        for (int ct = 0; ct < 4; ++ct) {
            wH[ct] = *(const bf16x8*)(plH + wo + kk * 8192 + ct * 512);
            wM[ct] = *(const bf16x8*)(plM + wo + kk * 8192 + ct * 512);
            if (NP == 6) wL[ct] = *(const bf16x8*)(plL + wo + kk * 8192 + ct * 512);
        }
#pragma unroll
        for (int rt = 0; rt < RT; ++rt) {
            int off = (rt * 16 + ln15) * ASTR + kk * 32 + lng * 8;
            xH[rt] = *(const bf16x8*)(actH + off);
            xM[rt] = *(const bf16x8*)(actM + off);
            if (NP == 6) xL[rt] = *(const bf16x8*)(actL + off);
        }
        __builtin_amdgcn_s_setprio(1);
#pragma unroll
        for (int ct = 0; ct < 4; ++ct)
#pragma unroll
            for (int rt = 0; rt < RT; ++rt) {
                acc[ct][rt] = __builtin_amdgcn_mfma_f32_16x16x32_bf16(wH[ct], xH[rt], acc[ct][rt], 0, 0, 0);
                acc[ct][rt] = __builtin_amdgcn_mfma_f32_16x16x32_bf16(wH[ct], xM[rt], acc[ct][rt], 0, 0, 0);
                acc[ct][rt] = __builtin_amdgcn_mfma_f32_16x16x32_bf16(wM[ct], xH[rt], acc[ct][rt], 0, 0, 0);
                if (NP == 6) {
                    acc[ct][rt] = __builtin_amdgcn_mfma_f32_16x16x32_bf16(wM[ct], xM[rt], acc[ct][rt], 0, 0, 0);
                    acc[ct][rt] = __builtin_amdgcn_mfma_f32_16x16x32_bf16(wH[ct], xL[rt], acc[ct][rt], 0, 0, 0);
                    acc[ct][rt] = __builtin_amdgcn_mfma_f32_16x16x32_bf16(wL[ct], xH[rt], acc[ct][rt], 0, 0, 0);
                }
            }
        __builtin_amdgcn_s_setprio(0);
    }
}

// stage a 3-way-split activation row block from U + a*wrow + bias (relu)
template<int ROWS>
__device__ __forceinline__ void stage3w(
    const float* __restrict__ U, const float* __restrict__ wrow256,
    const float* __restrict__ bias, int row0,
    short* actH, short* actM, short* actL)
{
    const int tid = threadIdx.x;
    const int wv = tid >> 6, ln = tid & 63;
    constexpr int RPW = ROWS / 4;
    const float4 wr = *(const float4*)(wrow256 + ln * 4);
    const float4 bb = *(const float4*)(bias + ln * 4);
    for (int i = wv * RPW; i < wv * RPW + RPW; ++i) {
        int r = row0 + i;
        int srow = r / 15;
        float a = (float)(r % 15);
        float4 u = *(const float4*)(U + srow * 256 + ln * 4);
        float sv[4];
        sv[0] = fmaxf(u.x + a * wr.x + bb.x, 0.f);
        sv[1] = fmaxf(u.y + a * wr.y + bb.y, 0.f);
        sv[2] = fmaxf(u.z + a * wr.z + bb.z, 0.f);
        sv[3] = fmaxf(u.w + a * wr.w + bb.w, 0.f);
        split3_write(sv, actH + i * ASTR + ln * 4, actM + i * ASTR + ln * 4, actL + i * ASTR + ln * 4);
    }
}

// ---------------------------------------------------------------------------
// u2_kernel: U2cr = s1 @ crW0[:256], U2tm = s1 @ tmW0[:256], both 6-pass.
// ---------------------------------------------------------------------------
__global__ __launch_bounds__(256, 1) void u2_kernel(
    const float* __restrict__ s1, const short* __restrict__ planes,
    float* __restrict__ U2cr, float* __restrict__ U2tm)
{
    __shared__ short actH[64 * ASTR];
    __shared__ short actM[64 * ASTR];
    __shared__ short actL[64 * ASTR];
    const int tid = threadIdx.x;
    const int row0 = blockIdx.x * 64;
    const int wv = tid >> 6, ln = tid & 63;
    const int ln15 = tid & 15, lng = (tid >> 4) & 3;
    for (int i = wv * 16; i < wv * 16 + 16; ++i) {
        int srow = row0 + i; if (srow > 479) srow = 479;
        float4 s = *(const float4*)(s1 + srow * 256 + ln * 4);
        float sv[4] = {s.x, s.y, s.z, s.w};
        split3_write(sv, actH + i * ASTR + ln * 4, actM + i * ASTR + ln * 4, actL + i * ASTR + ln * 4);
    }
    __syncthreads();
    f32x4 acc[4][4];
#pragma unroll
    for (int a = 0; a < 4; ++a)
#pragma unroll
        for (int b = 0; b < 4; ++b) acc[a][b] = f32x4{0.f,0.f,0.f,0.f};
    mm3<4, 6>(planes + 0*PL, planes + 1*PL, planes + 2*PL, actH, actM, actL, acc);
#pragma unroll
    for (int ct = 0; ct < 4; ++ct)
#pragma unroll
        for (int rt = 0; rt < 4; ++rt) {
            int r = row0 + rt * 16 + ln15;
            if (r < 480) {
                float4 o; o.x = acc[ct][rt][0]; o.y = acc[ct][rt][1];
                o.z = acc[ct][rt][2]; o.w = acc[ct][rt][3];
                *(float4*)(U2cr + r * 256 + wv * 64 + ct * 16 + lng * 4) = o;
            }
        }
#pragma unroll
    for (int a = 0; a < 4; ++a)
#pragma unroll
        for (int b = 0; b < 4; ++b) acc[a][b] = f32x4{0.f,0.f,0.f,0.f};
    mm3<4, 6>(planes + 6*PL, planes + 7*PL, planes + 8*PL, actH, actM, actL, acc);
#pragma unroll
    for (int ct = 0; ct < 4; ++ct)
#pragma unroll
        for (int rt = 0; rt < 4; ++rt) {
            int r = row0 + rt * 16 + ln15;
            if (r < 480) {
                float4 o; o.x = acc[ct][rt][0]; o.y = acc[ct][rt][1];
                o.z = acc[ct][rt][2]; o.w = acc[ct][rt][3];
                *(float4*)(U2tm + r * 256 + wv * 64 + ct * 16 + lng * 4) = o;
            }
        }
}

// ---------------------------------------------------------------------------
// stage2m: 7200 rows, 225 blocks x 32 rows. cont1/rews1 + Ucr/Utm (permuted).
// ---------------------------------------------------------------------------
__global__ __launch_bounds__(256, 2) void stage2m_kernel(
    const float* __restrict__ U2cr, const float* __restrict__ U2tm,
    const short* __restrict__ planes,
    const float* __restrict__ crW0, const float* __restrict__ crB0,
    const float* __restrict__ crB1, const float* __restrict__ crW2, const float* __restrict__ crB2,
    const float* __restrict__ tmW0, const float* __restrict__ tmB0,
    const float* __restrict__ tmB1, const float* __restrict__ tmB2,
    float* __restrict__ cont1, float* __restrict__ rews1,
    float* __restrict__ Ucr, float* __restrict__ Utm)
{
    __shared__ short actH[32 * ASTR];
    __shared__ short actM[32 * ASTR];
    __shared__ short actL[32 * ASTR];
    __shared__ float hred[2][128];
    const int tid = threadIdx.x;
    const int row0 = blockIdx.x * 32;
    const int ln15 = tid & 15, lng = (tid >> 4) & 3, wv = tid >> 6;

    // ---- Phase A: cr chain -> cont1, rews1 ----
    stage3w<32>(U2cr, crW0 + 65536, crB0, row0, actH, actM, actL);
    __syncthreads();
    {
        f32x4 acc[4][2];
#pragma unroll
        for (int a = 0; a < 4; ++a) { acc[a][0] = f32x4{0.f,0.f,0.f,0.f}; acc[a][1] = f32x4{0.f,0.f,0.f,0.f}; }
        mm3<2, 6>(planes + 3*PL, planes + 4*PL, planes + 5*PL, actH, actM, actL, acc);
        float hp0[2] = {0.f,0.f}, hp1[2] = {0.f,0.f};
#pragma unroll
        for (int ct = 0; ct < 4; ++ct) {
            const int colb = wv * 64 + ct * 16 + lng * 4;
            const float4 b1 = *(const float4*)(crB1 + colb);
#pragma unroll
            for (int rt = 0; rt < 2; ++rt) {
                f32x4 v = acc[ct][rt];
                v[0] += b1.x; v[1] += b1.y; v[2] += b1.z; v[3] += b1.w;
#pragma unroll
                for (int j = 0; j < 4; ++j) v[j] = fmaxf(v[j], 0.f);
#pragma unroll
                for (int j = 0; j < 4; ++j) {
                    hp0[rt] += v[j] * crW2[(colb + j) * 2 + 0];
                    hp1[rt] += v[j] * crW2[(colb + j) * 2 + 1];
                }
            }
        }
#pragma unroll
        for (int rt = 0; rt < 2; ++rt) {
            hp0[rt] += __shfl_xor(hp0[rt], 16); hp0[rt] += __shfl_xor(hp0[rt], 32);
            hp1[rt] += __shfl_xor(hp1[rt], 16); hp1[rt] += __shfl_xor(hp1[rt], 32);
        }
        if (lng == 0) {
#pragma unroll
            for (int rt = 0; rt < 2; ++rt) {
                hred[0][wv * 32 + rt * 16 + ln15] = hp0[rt];
                hred[1][wv * 32 + rt * 16 + ln15] = hp1[rt];
            }
        }
        __syncthreads();
        if (tid < 32)
            cont1[row0 + tid] = hred[0][tid] + hred[0][32 + tid] + hred[0][64 + tid] + hred[0][96 + tid] + crB2[0];
        else if (tid >= 64 && tid < 96)
            rews1[row0 + tid - 64] = hred[1][tid - 64] + hred[1][32 + tid - 64] + hred[1][64 + tid - 64] + hred[1][96 + tid - 64] + crB2[1];
        __syncthreads();
    }

    // ---- Phase B: tm chain -> s2 (LDS) -> Ucr, Utm ----
    stage3w<32>(U2tm, tmW0 + 65536, tmB0, row0, actH, actM, actL);
    __syncthreads();
#pragma unroll
    for (int layer = 0; layer < 2; ++layer) {
        const short* pB = planes + (layer == 0 ? 9 : 12) * PL;
        const float* bias = (layer == 0) ? tmB1 : tmB2;
        f32x4 acc[4][2];
#pragma unroll
        for (int a = 0; a < 4; ++a) { acc[a][0] = f32x4{0.f,0.f,0.f,0.f}; acc[a][1] = f32x4{0.f,0.f,0.f,0.f}; }
        mm3<2, 6>(pB, pB + PL, pB + 2*PL, actH, actM, actL, acc);
        __syncthreads();
#pragma unroll
        for (int ct = 0; ct < 4; ++ct) {
            const int colb = wv * 64 + ct * 16 + lng * 4;
            const float4 bb = *(const float4*)(bias + colb);
#pragma unroll
            for (int rt = 0; rt < 2; ++rt) {
                f32x4 v = acc[ct][rt];
                v[0] += bb.x; v[1] += bb.y; v[2] += bb.z; v[3] += bb.w;
                if (layer == 0) {
#pragma unroll
                    for (int j = 0; j < 4; ++j) v[j] = fmaxf(v[j], 0.f);
                }
                float sv[4] = {v[0], v[1], v[2], v[3]};
                const int ao = (rt * 16 + ln15) * ASTR + colb;
                split3_write(sv, actH + ao, actM + ao, actL + ao);
            }
        }
        __syncthreads();
    }
    int pr[2];
#pragma unroll
    for (int rt = 0; rt < 2; ++rt) {
        int r = row0 + rt * 16 + ln15;
        int b = r / 225, a1 = (r / 15) % 15, a2 = r % 15;
        pr[rt] = (b * 15 + a2) * 15 + a1;
    }
    {
        f32x4 acc[4][2];
#pragma unroll
        for (int a = 0; a < 4; ++a) { acc[a][0] = f32x4{0.f,0.f,0.f,0.f}; acc[a][1] = f32x4{0.f,0.f,0.f,0.f}; }
        mm3<2, 6>(planes + 0*PL, planes + 1*PL, planes + 2*PL, actH, actM, actL, acc);
#pragma unroll
        for (int ct = 0; ct < 4; ++ct)
#pragma unroll
            for (int rt = 0; rt < 2; ++rt) {
                float4 o; o.x = acc[ct][rt][0]; o.y = acc[ct][rt][1];
                o.z = acc[ct][rt][2]; o.w = acc[ct][rt][3];
                *(float4*)(Ucr + pr[rt] * 256 + wv * 64 + ct * 16 + lng * 4) = o;
            }
    }
    {
        f32x4 acc[4][2];
#pragma unroll
        for (int a = 0; a < 4; ++a) { acc[a][0] = f32x4{0.f,0.f,0.f,0.f}; acc[a][1] = f32x4{0.f,0.f,0.f,0.f}; }
        mm3<2, 3>(planes + 6*PL, planes + 7*PL, planes + 8*PL, actH, actM, actL, acc);
#pragma unroll
        for (int ct = 0; ct < 4; ++ct)
#pragma unroll
            for (int rt = 0; rt < 2; ++rt) {
                float4 o; o.x = acc[ct][rt][0]; o.y = acc[ct][rt][1];
                o.z = acc[ct][rt][2]; o.w = acc[ct][rt][3];
                *(float4*)(Utm + pr[rt] * 256 + wv * 64 + ct * 16 + lng * 4) = o;
            }
    }
}

// ---------------------------------------------------------------------------
// layer_g2: 2-way (H,M) 3-pass 16x16x32 layer over RT*16-row act tile.
// ---------------------------------------------------------------------------
template<int RT, bool RELU, bool HEAD, bool WRITEACT>
__device__ __forceinline__ void layer_g2(
    const short* __restrict__ plH, const short* __restrict__ plL,
    const float* __restrict__ bias,
    const float* __restrict__ headW, const float* __restrict__ headB,
    float* __restrict__ headOut, int row0,
    short* actH, short* actL, float* hred)
{
    const int tid = threadIdx.x;
    const int ln15 = tid & 15, lng = (tid >> 4) & 3, wv = tid >> 6;
    const int wo = (wv * 64 + ln15) * 32 + lng * 8;
    f32x4 acc[4][RT];
#pragma unroll
    for (int a = 0; a < 4; ++a)
#pragma unroll
        for (int b = 0; b < RT; ++b) acc[a][b] = f32x4{0.f, 0.f, 0.f, 0.f};

#pragma unroll
    for (int kk = 0; kk < 8; ++kk) {
        bf16x8 aH[4], aL[4], bH[RT], bL[RT];
#pragma unroll
        for (int ct = 0; ct < 4; ++ct) {
            aH[ct] = *(const bf16x8*)(plH + wo + kk * 8192 + ct * 512);
            aL[ct] = *(const bf16x8*)(plL + wo + kk * 8192 + ct * 512);
        }
#pragma unroll
        for (int rt = 0; rt < RT; ++rt) {
            int off = (rt * 16 + ln15) * ASTR + kk * 32 + lng * 8;
            bH[rt] = *(const bf16x8*)(actH + off);
            bL[rt] = *(const bf16x8*)(actL + off);
        }
        __builtin_amdgcn_s_setprio(1);
#pragma unroll
        for (int ct = 0; ct < 4; ++ct)
#pragma unroll
            for (int rt = 0; rt < RT; ++rt) {
                acc[ct][rt] = __builtin_amdgcn_mfma_f32_16x16x32_bf16(aH[ct], bH[rt], acc[ct][rt], 0, 0, 0);
                acc[ct][rt] = __builtin_amdgcn_mfma_f32_16x16x32_bf16(aH[ct], bL[rt], acc[ct][rt], 0, 0, 0);
                acc[ct][rt] = __builtin_amdgcn_mfma_f32_16x16x32_bf16(aL[ct], bH[rt], acc[ct][rt], 0, 0, 0);
            }
        __builtin_amdgcn_s_setprio(0);
    }
    __syncthreads();

    float hp[RT];
#pragma unroll
    for (int rt = 0; rt < RT; ++rt) hp[rt] = 0.f;
#pragma unroll
    for (int ct = 0; ct < 4; ++ct) {
        const int colb = wv * 64 + ct * 16 + lng * 4;
        const float4 bb = *(const float4*)(bias + colb);
#pragma unroll
        for (int rt = 0; rt < RT; ++rt) {
            f32x4 v = acc[ct][rt];
            v[0] += bb.x; v[1] += bb.y; v[2] += bb.z; v[3] += bb.w;
            if (RELU) {
#pragma unroll
                for (int j = 0; j < 4; ++j) v[j] = fmaxf(v[j], 0.f);
            }
            if (HEAD) {
                const float4 hw = *(const float4*)(headW + colb);
                hp[rt] += v[0] * hw.x + v[1] * hw.y + v[2] * hw.z + v[3] * hw.w;
            }
            if (WRITEACT) {
                float sv[4] = {v[0], v[1], v[2], v[3]};
                const int ao = (rt * 16 + ln15) * ASTR + colb;
                split2_write(sv, actH + ao, actL + ao);
            }
        }
    }
    if constexpr (HEAD) {
        constexpr int NR = RT * 16;
#pragma unroll
        for (int rt = 0; rt < RT; ++rt) {
            hp[rt] += __shfl_xor(hp[rt], 16);
            hp[rt] += __shfl_xor(hp[rt], 32);
        }
        if (lng == 0) {
#pragma unroll
            for (int rt = 0; rt < RT; ++rt) hred[wv * NR + rt * 16 + ln15] = hp[rt];
        }
        __syncthreads();
        if (tid < NR) {
            float s = hred[tid] + hred[NR + tid] + hred[2 * NR + tid] + hred[3 * NR + tid] + headB[0];
            headOut[row0 + tid] = s;
        }
    }
    if constexpr (WRITEACT) __syncthreads();
}

// ---------------------------------------------------------------------------
// k3ab: fused stage-3 with EQUAL LDS footprints -> 3 blocks/CU. 16x16x32 MFMA.
// 5625 blocks in groups of 5: 2x k3b (48-row tiles) + 3x k3a (32-row tiles).
// k3b: 2 planes x 48 rows = 50688 B. k3a: 3 planes x 32 rows = 50688 B.
// ---------------------------------------------------------------------------
__global__ __launch_bounds__(256, 3) void k3ab_kernel(
    const float* __restrict__ Ucr, const float* __restrict__ Utm,
    const short* __restrict__ planes,
    const float* __restrict__ crW0, const float* __restrict__ crB0,
    const float* __restrict__ crB1, const float* __restrict__ crW2,
    const float* __restrict__ crB2,
    const float* __restrict__ tmW0, const float* __restrict__ tmB0,
    const float* __restrict__ tmB1, const float* __restrict__ tmB2,
    const float* __restrict__ emB0, const float* __restrict__ emB1,
    const float* __restrict__ w5, const float* __restrict__ b5,
    float* __restrict__ cont2, float* __restrict__ Vns3)
{
    __shared__ short lds[2 * 48 * ASTR];   // == 3 * 32 * ASTR
    __shared__ float hred[192];
    const int tid = threadIdx.x;
    const int g = blockIdx.x / 5, rm = blockIdx.x % 5;
    const bool isB = rm < 2;
    const int ln15 = tid & 15, lng = (tid >> 4) & 3, wv = tid >> 6;
    const short* P = planes;

    if (isB) {
        // ---- k3b: 48-row tile; tm1, tm2, em0, em1+head(w5) ----
        const int row0 = (g * 2 + rm) * 48;
        short* actH = lds;
        short* actL = lds + 48 * ASTR;
        const int ln = tid & 63;
        const float4 wr = *(const float4*)(tmW0 + 65536 + ln * 4);
        const float4 bb = *(const float4*)(tmB0 + ln * 4);
        for (int i = wv * 12; i < wv * 12 + 12; ++i) {
            int r = row0 + i;
            int srow = r / 15;
            float a = (float)(r % 15);
            float4 u = *(const float4*)(Utm + srow * 256 + ln * 4);
            float sv[4];
            sv[0] = fmaxf(u.x + a * wr.x + bb.x, 0.f);
            sv[1] = fmaxf(u.y + a * wr.y + bb.y, 0.f);
            sv[2] = fmaxf(u.z + a * wr.z + bb.z, 0.f);
            sv[3] = fmaxf(u.w + a * wr.w + bb.w, 0.f);
            split2_write(sv, actH + i * ASTR + ln * 4, actL + i * ASTR + ln * 4);
        }
        __syncthreads();
        layer_g2<3, true,  false, true >(P + 9 * PL,  P + 10 * PL, tmB1, nullptr, nullptr, nullptr, row0, actH, actL, hred);
        layer_g2<3, false, false, true >(P + 12 * PL, P + 13 * PL, tmB2, nullptr, nullptr, nullptr, row0, actH, actL, hred);
        layer_g2<3, true,  false, true >(P + 15 * PL, P + 16 * PL, emB0, nullptr, nullptr, nullptr, row0, actH, actL, hred);
        layer_g2<3, true,  true,  false>(P + 18 * PL, P + 19 * PL, emB1, w5, b5, Vns3, row0, actH, actL, hred);
    } else {
        // ---- k3a: 32-row tile; stage 3-way, crW1 6-pass, head col0 ----
        const int row0 = (g * 3 + (rm - 2)) * 32;
        short* actH = lds;
        short* actM = lds + 32 * ASTR;
        short* actL = lds + 2 * 32 * ASTR;
        stage3w<32>(Ucr, crW0 + 65536, crB0, row0, actH, actM, actL);
        __syncthreads();
        f32x4 acc[4][2];
#pragma unroll
        for (int a = 0; a < 4; ++a) { acc[a][0] = f32x4{0.f,0.f,0.f,0.f}; acc[a][1] = f32x4{0.f,0.f,0.f,0.f}; }
        mm3<2, 6>(P + 3*PL, P + 4*PL, P + 5*PL, actH, actM, actL, acc);
        float hp[2] = {0.f, 0.f};
#pragma unroll
        for (int ct = 0; ct < 4; ++ct) {
            const int colb = wv * 64 + ct * 16 + lng * 4;
            const float4 b1 = *(const float4*)(crB1 + colb);
#pragma unroll
            for (int rt = 0; rt < 2; ++rt) {
                f32x4 v = acc[ct][rt];
                v[0] += b1.x; v[1] += b1.y; v[2] += b1.z; v[3] += b1.w;
#pragma unroll
                for (int j = 0; j < 4; ++j) v[j] = fmaxf(v[j], 0.f);
#pragma unroll
                for (int j = 0; j < 4; ++j) hp[rt] += v[j] * crW2[(colb + j) * 2];
            }
        }
#pragma unroll
        for (int rt = 0; rt < 2; ++rt) {
            hp[rt] += __shfl_xor(hp[rt], 16);
            hp[rt] += __shfl_xor(hp[rt], 32);
        }
        if (lng == 0) {
#pragma unroll
            for (int rt = 0; rt < 2; ++rt) hred[wv * 32 + rt * 16 + ln15] = hp[rt];
        }
        __syncthreads();
        if (tid < 32)
            cont2[row0 + tid] = hred[tid] + hred[32 + tid] + hred[64 + tid] + hred[96 + tid] + crB2[0];
    }
}

extern "C" void kernel_launch(void* const* d_in, const int* in_sizes, int n_in,
                              void* d_out, int out_size, void* d_ws, size_t ws_size,
                              hipStream_t stream)
{
    (void)in_sizes; (void)n_in; (void)out_size; (void)ws_size;
    const float* x    = (const float*)d_in[0];
    const float* emW0 = (const float*)d_in[1];
    const float* emB0 = (const float*)d_in[2];
    const float* emW1 = (const float*)d_in[3];
    const float* emB1 = (const float*)d_in[4];
    const float* emW2 = (const float*)d_in[5];
    const float* emB2 = (const float*)d_in[6];
    const float* vW   = (const float*)d_in[7];
    const float* vb   = (const float*)d_in[8];
    const float* crW0 = (const float*)d_in[9];
    const float* crB0 = (const float*)d_in[10];
    const float* crW1 = (const float*)d_in[11];
    const float* crB1 = (const float*)d_in[12];
    const float* crW2 = (const float*)d_in[13];
    const float* crB2 = (const float*)d_in[14];
    const float* tmW0 = (const float*)d_in[15];
    const float* tmB0 = (const float*)d_in[16];
    const float* tmW1 = (const float*)d_in[17];
    const float* tmB1 = (const float*)d_in[18];
    const float* tmW2 = (const float*)d_in[19];
    const float* tmB2 = (const float*)d_in[20];
    float* out = (float*)d_out;

    float* w     = (float*)d_ws;
    float* rews0 = w;                     // 480
    float* cont1 = rews0 + 480;           // 7200
    float* rews1 = cont1 + 7200;          // 7200
    float* cont2 = rews1 + 7200;          // 108000
    float* Vns3  = cont2 + 108000;        // 108000
    float* s1    = Vns3 + 108000;         // 480*256
    short* planes = (short*)(s1 + 480 * 256);   // 24 * PL shorts = 3 MB
    float* U2cr  = (float*)(planes + 24 * PL);  // 480*256
    float* U2tm  = U2cr + 480 * 256;            // 480*256
    float* Ucr   = U2tm + 480 * 256;            // 7200*256
    float* Utm   = Ucr + 7200 * 256;            // 7200*256
    float* w5    = Utm + 7200 * 256;            // 256
    float* b5    = w5 + 256;                    // 1

    front_kernel<<<133, 256, 0, stream>>>(x,
        emW0, emB0, emW1, emB1, emW2, emB2, vW, vb,
        crW0, crB0, crW1, crB1, crW2, crB2,
        tmW0, tmB0, tmW1, tmB1, tmW2, tmB2,
        planes, w5, b5, out + NB * NA, s1, rews0);
    u2_kernel<<<8, 256, 0, stream>>>(s1, planes, U2cr, U2tm);
    stage2m_kernel<<<225, 256, 0, stream>>>(U2cr, U2tm, planes,
        crW0, crB0, crB1, crW2, crB2, tmW0, tmB0, tmB1, tmB2,
        cont1, rews1, Ucr, Utm);
    k3ab_kernel<<<5625, 256, 0, stream>>>(Ucr, Utm, planes,
        crW0, crB0, crB1, crW2, crB2,
        tmW0, tmB0, tmB1, tmB2, emB0, emB1, w5, b5, cont2, Vns3);
    finalize_kernel<<<NB, 256, 0, stream>>>(Vns3, cont2, rews0, rews1, cont1, out);
}

// Round 14
// 384.815 us; speedup vs baseline: 1.1328x; 1.0490x over previous
//
#include <hip/hip_runtime.h>

#define NA 15
#define NB 32
#define DD 256
#define PL 65536  // shorts per weight plane (8 slices x 256 cols x 32 k)
#define ASTR 264  // act LDS row stride (shorts)

using bf16x8 = __attribute__((ext_vector_type(8))) short;
using f32x4  = __attribute__((ext_vector_type(4))) float;

__device__ __forceinline__ unsigned short f2bf(float f){
  unsigned int u = __float_as_uint(f);
  u = u + 0x7fffu + ((u >> 16) & 1u);
  return (unsigned short)(u >> 16);
}
__device__ __forceinline__ float bf2f(unsigned short h){
  return __uint_as_float(((unsigned int)h) << 16);
}
__device__ __forceinline__ unsigned int cvtpk_bf16(float lo, float hi){
    unsigned int r;
    asm("v_cvt_pk_bf16_f32 %0, %1, %2" : "=v"(r) : "v"(lo), "v"(hi));
    return r;
}
__device__ __forceinline__ void split2_write(const float v[4], short* pH, short* pL){
    unsigned int h01 = cvtpk_bf16(v[0], v[1]);
    unsigned int h23 = cvtpk_bf16(v[2], v[3]);
    float r0 = v[0] - __uint_as_float(h01 << 16);
    float r1 = v[1] - __uint_as_float(h01 & 0xffff0000u);
    float r2 = v[2] - __uint_as_float(h23 << 16);
    float r3 = v[3] - __uint_as_float(h23 & 0xffff0000u);
    unsigned int l01 = cvtpk_bf16(r0, r1);
    unsigned int l23 = cvtpk_bf16(r2, r3);
    *(uint2*)pH = make_uint2(h01, h23);
    *(uint2*)pL = make_uint2(l01, l23);
}
__device__ __forceinline__ void split3_write(const float v[4], short* pH, short* pM, short* pL){
    unsigned int h01 = cvtpk_bf16(v[0], v[1]);
    unsigned int h23 = cvtpk_bf16(v[2], v[3]);
    float r0 = v[0] - __uint_as_float(h01 << 16);
    float r1 = v[1] - __uint_as_float(h01 & 0xffff0000u);
    float r2 = v[2] - __uint_as_float(h23 << 16);
    float r3 = v[3] - __uint_as_float(h23 & 0xffff0000u);
    unsigned int m01 = cvtpk_bf16(r0, r1);
    unsigned int m23 = cvtpk_bf16(r2, r3);
    float s0 = r0 - __uint_as_float(m01 << 16);
    float s1 = r1 - __uint_as_float(m01 & 0xffff0000u);
    float s2 = r2 - __uint_as_float(m23 << 16);
    float s3 = r3 - __uint_as_float(m23 & 0xffff0000u);
    unsigned int l01 = cvtpk_bf16(s0, s1);
    unsigned int l23 = cvtpk_bf16(s2, s3);
    *(uint2*)pH = make_uint2(h01, h23);
    *(uint2*)pM = make_uint2(m01, m23);
    *(uint2*)pL = make_uint2(l01, l23);
}

// ---------------------------------------------------------------------------
// fp32 VALU primitives (value_x branch of front kernel)
// ---------------------------------------------------------------------------
template<int TM, bool RELU>
__device__ __forceinline__ void layer256(
    const float* __restrict__ W, const float* __restrict__ bias,
    const float* act, int K, int lda, float* out, int ldo)
{
    constexpr int RPG = TM / 4;
    const int tid = threadIdx.x;
    const int tr = tid >> 6;
    const int tc = tid & 63;
    float acc[RPG][4];
#pragma unroll
    for (int i = 0; i < RPG; ++i) { acc[i][0]=0.f; acc[i][1]=0.f; acc[i][2]=0.f; acc[i][3]=0.f; }
    const float* wp = W + 4 * tc;
    int k = 0;
    for (; k + 4 <= K; k += 4) {
        float4 w0 = *reinterpret_cast<const float4*>(wp + (k + 0) * DD);
        float4 w1 = *reinterpret_cast<const float4*>(wp + (k + 1) * DD);
        float4 w2 = *reinterpret_cast<const float4*>(wp + (k + 2) * DD);
        float4 w3 = *reinterpret_cast<const float4*>(wp + (k + 3) * DD);
#pragma unroll
        for (int i = 0; i < RPG; ++i) {
            float4 a = *reinterpret_cast<const float4*>(act + (RPG * tr + i) * lda + k);
            acc[i][0] += a.x * w0.x + a.y * w1.x + a.z * w2.x + a.w * w3.x;
            acc[i][1] += a.x * w0.y + a.y * w1.y + a.z * w2.y + a.w * w3.y;
            acc[i][2] += a.x * w0.z + a.y * w1.z + a.z * w2.z + a.w * w3.z;
            acc[i][3] += a.x * w0.w + a.y * w1.w + a.z * w2.w + a.w * w3.w;
        }
    }
    for (; k < K; ++k) {
        float4 w0 = *reinterpret_cast<const float4*>(wp + k * DD);
#pragma unroll
        for (int i = 0; i < RPG; ++i) {
            float a = act[(RPG * tr + i) * lda + k];
            acc[i][0] += a * w0.x; acc[i][1] += a * w0.y;
            acc[i][2] += a * w0.z; acc[i][3] += a * w0.w;
        }
    }
    float4 bb = *reinterpret_cast<const float4*>(bias + 4 * tc);
#pragma unroll
    for (int i = 0; i < RPG; ++i) {
        float4 o;
        o.x = acc[i][0] + bb.x; o.y = acc[i][1] + bb.y;
        o.z = acc[i][2] + bb.z; o.w = acc[i][3] + bb.w;
        if (RELU) {
            o.x = fmaxf(o.x, 0.f); o.y = fmaxf(o.y, 0.f);
            o.z = fmaxf(o.z, 0.f); o.w = fmaxf(o.w, 0.f);
        }
        *reinterpret_cast<float4*>(out + (RPG * tr + i) * ldo + 4 * tc) = o;
    }
}

template<int TM>
__device__ __forceinline__ void head1c(
    const float* h, int ldh, const float* __restrict__ W, int wstr, int col, float bias,
    float* __restrict__ gout, int gbase)
{
    const int wv = threadIdx.x >> 6;
    const int lane = threadIdx.x & 63;
    for (int rr = wv; rr < TM; rr += 4) {
        float p = 0.f;
#pragma unroll
        for (int t = 0; t < 4; ++t) {
            int k = lane + 64 * t;
            p += h[rr * ldh + k] * W[k * wstr + col];
        }
#pragma unroll
        for (int m = 1; m < 64; m <<= 1) p += __shfl_xor(p, m);
        if (lane == 0) gout[gbase + rr] = p + bias;
    }
}

// ---------------------------------------------------------------------------
// front_kernel: blocks 0-63 prep (weight split), 64 prep2 (w5,b5),
// 65-72 value_x (TM=4), 73-80 U1 (x @ crW0/tmW0, fp32 exact-grade).
// ---------------------------------------------------------------------------
__global__ __launch_bounds__(256) void front_kernel(
    const float* __restrict__ x,
    const float* __restrict__ emW0, const float* __restrict__ emB0,
    const float* __restrict__ emW1, const float* __restrict__ emB1,
    const float* __restrict__ emW2, const float* __restrict__ emB2,
    const float* __restrict__ vW, const float* __restrict__ vb,
    const float* __restrict__ crW0, const float* __restrict__ crW1,
    const float* __restrict__ tmW0, const float* __restrict__ tmW1,
    const float* __restrict__ tmW2,
    short* __restrict__ planes, float* __restrict__ w5, float* __restrict__ b5,
    float* __restrict__ vout, float* __restrict__ U1cr, float* __restrict__ U1tm)
{
    __shared__ __align__(16) float smem[3 * 4 * DD];
    const int blk = blockIdx.x;
    const int tid = threadIdx.x;

    if (blk < 64) {
        const int mat = blk >> 3;
        const int kk  = blk & 7;
        const float* W;
        switch (mat) {
            case 0: W = crW0; break;
            case 1: W = crW1; break;
            case 2: W = tmW0; break;
            case 3: W = tmW1; break;
            case 4: W = tmW2; break;
            case 5: W = emW0; break;
            case 6: W = emW1; break;
            default: W = emW2; break;
        }
        const int col = tid;
        short bh[32], bm[32], bl[32];
#pragma unroll
        for (int j = 0; j < 32; ++j) {
            float w = W[(kk * 32 + j) * 256 + col];
            unsigned short h = f2bf(w); float fh = bf2f(h);
            float r1 = w - fh;
            unsigned short m = f2bf(r1); float fm = bf2f(m);
            bh[j] = (short)h; bm[j] = (short)m; bl[j] = (short)f2bf(r1 - fm);
        }
        short* pH = planes + (size_t)(mat * 3 + 0) * PL + kk * 8192 + col * 32;
        short* pM = planes + (size_t)(mat * 3 + 1) * PL + kk * 8192 + col * 32;
        short* pLp = planes + (size_t)(mat * 3 + 2) * PL + kk * 8192 + col * 32;
#pragma unroll
        for (int j = 0; j < 32; j += 4) {
            *(short4*)(pH + j) = make_short4(bh[j], bh[j+1], bh[j+2], bh[j+3]);
            *(short4*)(pM + j) = make_short4(bm[j], bm[j+1], bm[j+2], bm[j+3]);
            *(short4*)(pLp + j) = make_short4(bl[j], bl[j+1], bl[j+2], bl[j+3]);
        }
    } else if (blk == 64) {
        float acc = 0.f;
        for (int j = 0; j < 256; j += 4) {
            float4 wrow = *(const float4*)(emW2 + tid * 256 + j);
            float4 vv   = *(const float4*)(vW + j);
            acc += wrow.x * vv.x + wrow.y * vv.y + wrow.z * vv.z + wrow.w * vv.w;
        }
        w5[tid] = acc;
        if (tid == 0) {
            float b = 0.f;
            for (int j = 0; j < 256; ++j) b += emB2[j] * vW[j];
            b5[0] = b + vb[0];
        }
    } else if (blk < 73) {
        constexpr int TM = 4;
        float* bufA = smem;
        float* bufB = bufA + TM * DD;
        float* bufC = bufB + TM * DD;
        const int row0 = (blk - 65) * TM;
        for (int i = 0; i < TM; ++i) bufA[i * DD + tid] = x[(row0 + i) * DD + tid];
        __syncthreads();
        layer256<TM, true >(emW0, emB0, bufA, 256, DD, bufB, DD); __syncthreads();
        layer256<TM, true >(emW1, emB1, bufB, 256, DD, bufC, DD); __syncthreads();
        layer256<TM, false>(emW2, emB2, bufC, 256, DD, bufB, DD); __syncthreads();
        head1c<TM>(bufB, DD, vW, 1, 0, vb[0], vout, row0);
    } else {
        // U1: 4 x-rows per block; U1cr = x @ crW0[:256], U1tm = x @ tmW0[:256]
        const int row0 = (blk - 73) * 4;
        float* xs = smem;   // [4][256]
        for (int i = 0; i < 4; ++i) xs[i * 256 + tid] = x[(row0 + i) * 256 + tid];
        __syncthreads();
        float acr[4] = {0.f,0.f,0.f,0.f}, atm[4] = {0.f,0.f,0.f,0.f};
        for (int k = 0; k < 256; ++k) {
            float wc = crW0[k * 256 + tid];
            float wt = tmW0[k * 256 + tid];
#pragma unroll
            for (int i = 0; i < 4; ++i) {
                acr[i] += xs[i * 256 + k] * wc;
                atm[i] += xs[i * 256 + k] * wt;
            }
        }
        for (int i = 0; i < 4; ++i) {
            U1cr[(row0 + i) * 256 + tid] = acr[i];
            U1tm[(row0 + i) * 256 + tid] = atm[i];
        }
    }
}

__global__ __launch_bounds__(256) void finalize_kernel(
    const float* __restrict__ Vns3, const float* __restrict__ cont2,
    const float* __restrict__ rews0, const float* __restrict__ rews1,
    const float* __restrict__ cont1, float* __restrict__ out)
{
    const int b = blockIdx.x;
    const int tid = threadIdx.x;
    __shared__ float vs2[NA][NA];
    __shared__ float vs3[NA];
    if (tid < NA * NA) {
        const int x = tid / NA, y = tid % NA;
        float vals[NA];
        float m = -INFINITY;
#pragma unroll
        for (int z = 0; z < NA; ++z) {
            int vidx = ((b * NA + y) * NA + z) * NA + x;
            int cidx = ((b * NA + x) * NA + y) * NA + z;
            float c1 = rews0[b * NA + z] * 0.99f;
            float c2 = (c1 + rews1[(b * NA + x) * NA + z]) * 0.99f;
            float v = Vns3[vidx] * 0.970299f + c2;
            if (cont2[cidx] > 0.f) v = 0.f;
            vals[z] = v;
            m = fmaxf(m, v);
        }
        float se = 0.f, sw = 0.f;
#pragma unroll
        for (int z = 0; z < NA; ++z) { float e = expf(vals[z] - m); se += e; sw += e * vals[z]; }
        vs2[x][y] = sw / se;
    }
    __syncthreads();
    if (tid < NA) {
        const int x = tid;
        float vals[NA];
        float m = -INFINITY;
#pragma unroll
        for (int y = 0; y < NA; ++y) {
            float v = vs2[x][y];
            if (cont1[(b * NA + x) * NA + y] > 0.f) v = 0.f;
            vals[y] = v;
            m = fmaxf(m, v);
        }
        float se = 0.f, sw = 0.f;
#pragma unroll
        for (int y = 0; y < NA; ++y) { float e = expf(vals[y] - m); se += e; sw += e * vals[y]; }
        vs3[x] = sw / se;
    }
    __syncthreads();
    if (tid == 0) {
        float m = -INFINITY;
#pragma unroll
        for (int x = 0; x < NA; ++x) m = fmaxf(m, vs3[x]);
        float se = 0.f;
#pragma unroll
        for (int x = 0; x < NA; ++x) se += expf(vs3[x] - m);
        float l = logf(se);
#pragma unroll
        for (int x = 0; x < NA; ++x) out[b * NA + x] = vs3[x] - m - l;
    }
}

// ---------------------------------------------------------------------------
// mm3: accumulate RT row-tiles x 4 col-tiles over K=256 with NP passes.
// NP=6: fp32 grade (~1e-6). NP=3: 2-way grade (~5e-5).
// ---------------------------------------------------------------------------
template<int RT, int NP>
__device__ __forceinline__ void mm3(
    const short* __restrict__ plH, const short* __restrict__ plM, const short* __restrict__ plL,
    const short* actH, const short* actM, const short* actL,
    f32x4 (&acc)[4][RT])
{
    const int tid = threadIdx.x;
    const int ln15 = tid & 15, lng = (tid >> 4) & 3, wv = tid >> 6;
    const int wo = (wv * 64 + ln15) * 32 + lng * 8;
#pragma unroll
    for (int kk = 0; kk < 8; ++kk) {
        bf16x8 wH[4], wM[4], wL[4], xH[RT], xM[RT], xL[RT];
#pragma unroll
        for (int ct = 0; ct < 4; ++ct) {
            wH[ct] = *(const bf16x8*)(plH + wo + kk * 8192 + ct * 512);
            wM[ct] = *(const bf16x8*)(plM + wo + kk * 8192 + ct * 512);
            if (NP == 6) wL[ct] = *(const bf16x8*)(plL + wo + kk * 8192 + ct * 512);
        }
#pragma unroll
        for (int rt = 0; rt < RT; ++rt) {
            int off = (rt * 16 + ln15) * ASTR + kk * 32 + lng * 8;
            xH[rt] = *(const bf16x8*)(actH + off);
            xM[rt] = *(const bf16x8*)(actM + off);
            if (NP == 6) xL[rt] = *(const bf16x8*)(actL + off);
        }
        __builtin_amdgcn_s_setprio(1);
#pragma unroll
        for (int ct = 0; ct < 4; ++ct)
#pragma unroll
            for (int rt = 0; rt < RT; ++rt) {
                acc[ct][rt] = __builtin_amdgcn_mfma_f32_16x16x32_bf16(wH[ct], xH[rt], acc[ct][rt], 0, 0, 0);
                acc[ct][rt] = __builtin_amdgcn_mfma_f32_16x16x32_bf16(wH[ct], xM[rt], acc[ct][rt], 0, 0, 0);
                acc[ct][rt] = __builtin_amdgcn_mfma_f32_16x16x32_bf16(wM[ct], xH[rt], acc[ct][rt], 0, 0, 0);
                if (NP == 6) {
                    acc[ct][rt] = __builtin_amdgcn_mfma_f32_16x16x32_bf16(wM[ct], xM[rt], acc[ct][rt], 0, 0, 0);
                    acc[ct][rt] = __builtin_amdgcn_mfma_f32_16x16x32_bf16(wH[ct], xL[rt], acc[ct][rt], 0, 0, 0);
                    acc[ct][rt] = __builtin_amdgcn_mfma_f32_16x16x32_bf16(wL[ct], xH[rt], acc[ct][rt], 0, 0, 0);
                }
            }
        __builtin_amdgcn_s_setprio(0);
    }
}

// stage a 3-way-split activation row block from U + a*wrow + bias (relu)
template<int ROWS>
__device__ __forceinline__ void stage3w(
    const float* __restrict__ U, const float* __restrict__ wrow256,
    const float* __restrict__ bias, int row0,
    short* actH, short* actM, short* actL)
{
    const int tid = threadIdx.x;
    const int wv = tid >> 6, ln = tid & 63;
    constexpr int RPW = ROWS / 4;
    const float4 wr = *(const float4*)(wrow256 + ln * 4);
    const float4 bb = *(const float4*)(bias + ln * 4);
    for (int i = wv * RPW; i < wv * RPW + RPW; ++i) {
        int r = row0 + i;
        int srow = r / 15;
        float a = (float)(r % 15);
        float4 u = *(const float4*)(U + srow * 256 + ln * 4);
        float sv[4];
        sv[0] = fmaxf(u.x + a * wr.x + bb.x, 0.f);
        sv[1] = fmaxf(u.y + a * wr.y + bb.y, 0.f);
        sv[2] = fmaxf(u.z + a * wr.z + bb.z, 0.f);
        sv[3] = fmaxf(u.w + a * wr.w + bb.w, 0.f);
        split3_write(sv, actH + i * ASTR + ln * 4, actM + i * ASTR + ln * 4, actL + i * ASTR + ln * 4);
    }
}

// ---------------------------------------------------------------------------
// stage1m: 480 rows (b,a1), 30 blocks x 16 rows. rews0 + U2cr/U2tm.
// ---------------------------------------------------------------------------
__global__ __launch_bounds__(256, 2) void stage1m_kernel(
    const float* __restrict__ U1cr, const float* __restrict__ U1tm,
    const short* __restrict__ planes,
    const float* __restrict__ crW0, const float* __restrict__ crB0,
    const float* __restrict__ crB1, const float* __restrict__ crW2, const float* __restrict__ crB2,
    const float* __restrict__ tmW0, const float* __restrict__ tmB0,
    const float* __restrict__ tmB1, const float* __restrict__ tmB2,
    float* __restrict__ rews0, float* __restrict__ U2cr, float* __restrict__ U2tm)
{
    __shared__ short actH[16 * ASTR];
    __shared__ short actM[16 * ASTR];
    __shared__ short actL[16 * ASTR];
    __shared__ float hred[64];
    const int tid = threadIdx.x;
    const int row0 = blockIdx.x * 16;
    const int ln15 = tid & 15, lng = (tid >> 4) & 3, wv = tid >> 6;

    // ---- Phase A: cr chain -> rews0 (col 1) ----
    stage3w<16>(U1cr, crW0 + 65536, crB0, row0, actH, actM, actL);
    __syncthreads();
    {
        f32x4 acc[4][1];
#pragma unroll
        for (int a = 0; a < 4; ++a) acc[a][0] = f32x4{0.f,0.f,0.f,0.f};
        mm3<1, 6>(planes + 3*PL, planes + 4*PL, planes + 5*PL, actH, actM, actL, acc);
        float hp = 0.f;
#pragma unroll
        for (int ct = 0; ct < 4; ++ct) {
            const int colb = wv * 64 + ct * 16 + lng * 4;
            const float4 b1 = *(const float4*)(crB1 + colb);
            f32x4 v = acc[ct][0];
            v[0] += b1.x; v[1] += b1.y; v[2] += b1.z; v[3] += b1.w;
#pragma unroll
            for (int j = 0; j < 4; ++j) v[j] = fmaxf(v[j], 0.f);
#pragma unroll
            for (int j = 0; j < 4; ++j) hp += v[j] * crW2[(colb + j) * 2 + 1];
        }
        hp += __shfl_xor(hp, 16);
        hp += __shfl_xor(hp, 32);
        if (lng == 0) hred[wv * 16 + ln15] = hp;
        __syncthreads();
        if (tid < 16) rews0[row0 + tid] = hred[tid] + hred[16 + tid] + hred[32 + tid] + hred[48 + tid] + crB2[1];
        __syncthreads();
    }

    // ---- Phase B: tm chain -> s1 (LDS) -> U2cr, U2tm ----
    stage3w<16>(U1tm, tmW0 + 65536, tmB0, row0, actH, actM, actL);
    __syncthreads();
#pragma unroll
    for (int layer = 0; layer < 2; ++layer) {
        const short* pB = planes + (layer == 0 ? 9 : 12) * PL;
        const float* bias = (layer == 0) ? tmB1 : tmB2;
        f32x4 acc[4][1];
#pragma unroll
        for (int a = 0; a < 4; ++a) acc[a][0] = f32x4{0.f,0.f,0.f,0.f};
        mm3<1, 6>(pB, pB + PL, pB + 2*PL, actH, actM, actL, acc);
        __syncthreads();
#pragma unroll
        for (int ct = 0; ct < 4; ++ct) {
            const int colb = wv * 64 + ct * 16 + lng * 4;
            const float4 bb = *(const float4*)(bias + colb);
            f32x4 v = acc[ct][0];
            v[0] += bb.x; v[1] += bb.y; v[2] += bb.z; v[3] += bb.w;
            if (layer == 0) {
#pragma unroll
                for (int j = 0; j < 4; ++j) v[j] = fmaxf(v[j], 0.f);
            }
            float sv[4] = {v[0], v[1], v[2], v[3]};
            const int ao = ln15 * ASTR + colb;
            split3_write(sv, actH + ao, actM + ao, actL + ao);
        }
        __syncthreads();
    }
    // acts = s1 rows (3-way). U2cr (6-pass crW0), U2tm (6-pass tmW0).
    {
        f32x4 acc[4][1];
#pragma unroll
        for (int a = 0; a < 4; ++a) acc[a][0] = f32x4{0.f,0.f,0.f,0.f};
        mm3<1, 6>(planes + 0*PL, planes + 1*PL, planes + 2*PL, actH, actM, actL, acc);
#pragma unroll
        for (int ct = 0; ct < 4; ++ct) {
            float4 o; o.x = acc[ct][0][0]; o.y = acc[ct][0][1];
            o.z = acc[ct][0][2]; o.w = acc[ct][0][3];
            *(float4*)(U2cr + (row0 + ln15) * 256 + wv * 64 + ct * 16 + lng * 4) = o;
        }
    }
    {
        f32x4 acc[4][1];
#pragma unroll
        for (int a = 0; a < 4; ++a) acc[a][0] = f32x4{0.f,0.f,0.f,0.f};
        mm3<1, 6>(planes + 6*PL, planes + 7*PL, planes + 8*PL, actH, actM, actL, acc);
#pragma unroll
        for (int ct = 0; ct < 4; ++ct) {
            float4 o; o.x = acc[ct][0][0]; o.y = acc[ct][0][1];
            o.z = acc[ct][0][2]; o.w = acc[ct][0][3];
            *(float4*)(U2tm + (row0 + ln15) * 256 + wv * 64 + ct * 16 + lng * 4) = o;
        }
    }
}

// ---------------------------------------------------------------------------
// stage2m: 7200 rows, 450 blocks x 16 rows. cont1/rews1 + Ucr/Utm (permuted).
// ---------------------------------------------------------------------------
__global__ __launch_bounds__(256, 2) void stage2m_kernel(
    const float* __restrict__ U2cr, const float* __restrict__ U2tm,
    const short* __restrict__ planes,
    const float* __restrict__ crW0, const float* __restrict__ crB0,
    const float* __restrict__ crB1, const float* __restrict__ crW2, const float* __restrict__ crB2,
    const float* __restrict__ tmW0, const float* __restrict__ tmB0,
    const float* __restrict__ tmB1, const float* __restrict__ tmB2,
    float* __restrict__ cont1, float* __restrict__ rews1,
    float* __restrict__ Ucr, float* __restrict__ Utm)
{
    __shared__ short actH[16 * ASTR];
    __shared__ short actM[16 * ASTR];
    __shared__ short actL[16 * ASTR];
    __shared__ float hred[2][64];
    const int tid = threadIdx.x;
    const int row0 = blockIdx.x * 16;
    const int ln15 = tid & 15, lng = (tid >> 4) & 3, wv = tid >> 6;

    // ---- Phase A: cr chain -> cont1, rews1 ----
    stage3w<16>(U2cr, crW0 + 65536, crB0, row0, actH, actM, actL);
    __syncthreads();
    {
        f32x4 acc[4][1];
#pragma unroll
        for (int a = 0; a < 4; ++a) acc[a][0] = f32x4{0.f,0.f,0.f,0.f};
        mm3<1, 6>(planes + 3*PL, planes + 4*PL, planes + 5*PL, actH, actM, actL, acc);
        float hp0 = 0.f, hp1 = 0.f;
#pragma unroll
        for (int ct = 0; ct < 4; ++ct) {
            const int colb = wv * 64 + ct * 16 + lng * 4;
            const float4 b1 = *(const float4*)(crB1 + colb);
            f32x4 v = acc[ct][0];
            v[0] += b1.x; v[1] += b1.y; v[2] += b1.z; v[3] += b1.w;
#pragma unroll
            for (int j = 0; j < 4; ++j) v[j] = fmaxf(v[j], 0.f);
#pragma unroll
            for (int j = 0; j < 4; ++j) {
                hp0 += v[j] * crW2[(colb + j) * 2 + 0];
                hp1 += v[j] * crW2[(colb + j) * 2 + 1];
            }
        }
        hp0 += __shfl_xor(hp0, 16); hp0 += __shfl_xor(hp0, 32);
        hp1 += __shfl_xor(hp1, 16); hp1 += __shfl_xor(hp1, 32);
        if (lng == 0) {
            hred[0][wv * 16 + ln15] = hp0;
            hred[1][wv * 16 + ln15] = hp1;
        }
        __syncthreads();
        if (tid < 16)
            cont1[row0 + tid] = hred[0][tid] + hred[0][16 + tid] + hred[0][32 + tid] + hred[0][48 + tid] + crB2[0];
        else if (tid >= 64 && tid < 80)
            rews1[row0 + tid - 64] = hred[1][tid - 64] + hred[1][16 + tid - 64] + hred[1][32 + tid - 64] + hred[1][48 + tid - 64] + crB2[1];
        __syncthreads();
    }

    // ---- Phase B: tm chain -> s2 (LDS) -> Ucr, Utm ----
    stage3w<16>(U2tm, tmW0 + 65536, tmB0, row0, actH, actM, actL);
    __syncthreads();
#pragma unroll
    for (int layer = 0; layer < 2; ++layer) {
        const short* pB = planes + (layer == 0 ? 9 : 12) * PL;
        const float* bias = (layer == 0) ? tmB1 : tmB2;
        f32x4 acc[4][1];
#pragma unroll
        for (int a = 0; a < 4; ++a) acc[a][0] = f32x4{0.f,0.f,0.f,0.f};
        mm3<1, 6>(pB, pB + PL, pB + 2*PL, actH, actM, actL, acc);
        __syncthreads();
#pragma unroll
        for (int ct = 0; ct < 4; ++ct) {
            const int colb = wv * 64 + ct * 16 + lng * 4;
            const float4 bb = *(const float4*)(bias + colb);
            f32x4 v = acc[ct][0];
            v[0] += bb.x; v[1] += bb.y; v[2] += bb.z; v[3] += bb.w;
            if (layer == 0) {
#pragma unroll
                for (int j = 0; j < 4; ++j) v[j] = fmaxf(v[j], 0.f);
            }
            float sv[4] = {v[0], v[1], v[2], v[3]};
            const int ao = ln15 * ASTR + colb;
            split3_write(sv, actH + ao, actM + ao, actL + ao);
        }
        __syncthreads();
    }
    int pr;
    {
        int r = row0 + ln15;
        int b = r / 225, a1 = (r / 15) % 15, a2 = r % 15;
        pr = (b * 15 + a2) * 15 + a1;
    }
    {
        f32x4 acc[4][1];
#pragma unroll
        for (int a = 0; a < 4; ++a) acc[a][0] = f32x4{0.f,0.f,0.f,0.f};
        mm3<1, 6>(planes + 0*PL, planes + 1*PL, planes + 2*PL, actH, actM, actL, acc);
#pragma unroll
        for (int ct = 0; ct < 4; ++ct) {
            float4 o; o.x = acc[ct][0][0]; o.y = acc[ct][0][1];
            o.z = acc[ct][0][2]; o.w = acc[ct][0][3];
            *(float4*)(Ucr + pr * 256 + wv * 64 + ct * 16 + lng * 4) = o;
        }
    }
    {
        f32x4 acc[4][1];
#pragma unroll
        for (int a = 0; a < 4; ++a) acc[a][0] = f32x4{0.f,0.f,0.f,0.f};
        mm3<1, 3>(planes + 6*PL, planes + 7*PL, planes + 8*PL, actH, actM, actL, acc);
#pragma unroll
        for (int ct = 0; ct < 4; ++ct) {
            float4 o; o.x = acc[ct][0][0]; o.y = acc[ct][0][1];
            o.z = acc[ct][0][2]; o.w = acc[ct][0][3];
            *(float4*)(Utm + pr * 256 + wv * 64 + ct * 16 + lng * 4) = o;
        }
    }
}

// ---------------------------------------------------------------------------
// layer_g2: 2-way (H,M) 3-pass 16x16x32 layer over RT*16-row act tile.
// ---------------------------------------------------------------------------
template<int RT, bool RELU, bool HEAD, bool WRITEACT>
__device__ __forceinline__ void layer_g2(
    const short* __restrict__ plH, const short* __restrict__ plL,
    const float* __restrict__ bias,
    const float* __restrict__ headW, const float* __restrict__ headB,
    float* __restrict__ headOut, int row0,
    short* actH, short* actL, float* hred)
{
    const int tid = threadIdx.x;
    const int ln15 = tid & 15, lng = (tid >> 4) & 3, wv = tid >> 6;
    const int wo = (wv * 64 + ln15) * 32 + lng * 8;
    f32x4 acc[4][RT];
#pragma unroll
    for (int a = 0; a < 4; ++a)
#pragma unroll
        for (int b = 0; b < RT; ++b) acc[a][b] = f32x4{0.f, 0.f, 0.f, 0.f};

#pragma unroll
    for (int kk = 0; kk < 8; ++kk) {
        bf16x8 aH[4], aL[4], bH[RT], bL[RT];
#pragma unroll
        for (int ct = 0; ct < 4; ++ct) {
            aH[ct] = *(const bf16x8*)(plH + wo + kk * 8192 + ct * 512);
            aL[ct] = *(const bf16x8*)(plL + wo + kk * 8192 + ct * 512);
        }
#pragma unroll
        for (int rt = 0; rt < RT; ++rt) {
            int off = (rt * 16 + ln15) * ASTR + kk * 32 + lng * 8;
            bH[rt] = *(const bf16x8*)(actH + off);
            bL[rt] = *(const bf16x8*)(actL + off);
        }
        __builtin_amdgcn_s_setprio(1);
#pragma unroll
        for (int ct = 0; ct < 4; ++ct)
#pragma unroll
            for (int rt = 0; rt < RT; ++rt) {
                acc[ct][rt] = __builtin_amdgcn_mfma_f32_16x16x32_bf16(aH[ct], bH[rt], acc[ct][rt], 0, 0, 0);
                acc[ct][rt] = __builtin_amdgcn_mfma_f32_16x16x32_bf16(aH[ct], bL[rt], acc[ct][rt], 0, 0, 0);
                acc[ct][rt] = __builtin_amdgcn_mfma_f32_16x16x32_bf16(aL[ct], bH[rt], acc[ct][rt], 0, 0, 0);
            }
        __builtin_amdgcn_s_setprio(0);
    }
    __syncthreads();

    float hp[RT];
#pragma unroll
    for (int rt = 0; rt < RT; ++rt) hp[rt] = 0.f;
#pragma unroll
    for (int ct = 0; ct < 4; ++ct) {
        const int colb = wv * 64 + ct * 16 + lng * 4;
        const float4 bb = *(const float4*)(bias + colb);
#pragma unroll
        for (int rt = 0; rt < RT; ++rt) {
            f32x4 v = acc[ct][rt];
            v[0] += bb.x; v[1] += bb.y; v[2] += bb.z; v[3] += bb.w;
            if (RELU) {
#pragma unroll
                for (int j = 0; j < 4; ++j) v[j] = fmaxf(v[j], 0.f);
            }
            if (HEAD) {
                const float4 hw = *(const float4*)(headW + colb);
                hp[rt] += v[0] * hw.x + v[1] * hw.y + v[2] * hw.z + v[3] * hw.w;
            }
            if (WRITEACT) {
                float sv[4] = {v[0], v[1], v[2], v[3]};
                const int ao = (rt * 16 + ln15) * ASTR + colb;
                split2_write(sv, actH + ao, actL + ao);
            }
        }
    }
    if constexpr (HEAD) {
        constexpr int NR = RT * 16;
#pragma unroll
        for (int rt = 0; rt < RT; ++rt) {
            hp[rt] += __shfl_xor(hp[rt], 16);
            hp[rt] += __shfl_xor(hp[rt], 32);
        }
        if (lng == 0) {
#pragma unroll
            for (int rt = 0; rt < RT; ++rt) hred[wv * NR + rt * 16 + ln15] = hp[rt];
        }
        __syncthreads();
        if (tid < NR) {
            float s = hred[tid] + hred[NR + tid] + hred[2 * NR + tid] + hred[3 * NR + tid] + headB[0];
            headOut[row0 + tid] = s;
        }
    }
    if constexpr (WRITEACT) __syncthreads();
}

// ---------------------------------------------------------------------------
// k3ab: fused stage-3 with EQUAL LDS footprints -> 3 blocks/CU. 16x16x32 MFMA.
// 5625 blocks in groups of 5: 2x k3b (48-row tiles) + 3x k3a (32-row tiles).
// ---------------------------------------------------------------------------
__global__ __launch_bounds__(256, 3) void k3ab_kernel(
    const float* __restrict__ Ucr, const float* __restrict__ Utm,
    const short* __restrict__ planes,
    const float* __restrict__ crW0, const float* __restrict__ crB0,
    const float* __restrict__ crB1, const float* __restrict__ crW2,
    const float* __restrict__ crB2,
    const float* __restrict__ tmW0, const float* __restrict__ tmB0,
    const float* __restrict__ tmB1, const float* __restrict__ tmB2,
    const float* __restrict__ emB0, const float* __restrict__ emB1,
    const float* __restrict__ w5, const float* __restrict__ b5,
    float* __restrict__ cont2, float* __restrict__ Vns3)
{
    __shared__ short lds[2 * 48 * ASTR];   // == 3 * 32 * ASTR
    __shared__ float hred[192];
    const int tid = threadIdx.x;
    const int g = blockIdx.x / 5, rm = blockIdx.x % 5;
    const bool isB = rm < 2;
    const int ln15 = tid & 15, lng = (tid >> 4) & 3, wv = tid >> 6;
    const short* P = planes;

    if (isB) {
        const int row0 = (g * 2 + rm) * 48;
        short* actH = lds;
        short* actL = lds + 48 * ASTR;
        const int ln = tid & 63;
        const float4 wr = *(const float4*)(tmW0 + 65536 + ln * 4);
        const float4 bb = *(const float4*)(tmB0 + ln * 4);
        for (int i = wv * 12; i < wv * 12 + 12; ++i) {
            int r = row0 + i;
            int srow = r / 15;
            float a = (float)(r % 15);
            float4 u = *(const float4*)(Utm + srow * 256 + ln * 4);
            float sv[4];
            sv[0] = fmaxf(u.x + a * wr.x + bb.x, 0.f);
            sv[1] = fmaxf(u.y + a * wr.y + bb.y, 0.f);
            sv[2] = fmaxf(u.z + a * wr.z + bb.z, 0.f);
            sv[3] = fmaxf(u.w + a * wr.w + bb.w, 0.f);
            split2_write(sv, actH + i * ASTR + ln * 4, actL + i * ASTR + ln * 4);
        }
        __syncthreads();
        layer_g2<3, true,  false, true >(P + 9 * PL,  P + 10 * PL, tmB1, nullptr, nullptr, nullptr, row0, actH, actL, hred);
        layer_g2<3, false, false, true >(P + 12 * PL, P + 13 * PL, tmB2, nullptr, nullptr, nullptr, row0, actH, actL, hred);
        layer_g2<3, true,  false, true >(P + 15 * PL, P + 16 * PL, emB0, nullptr, nullptr, nullptr, row0, actH, actL, hred);
        layer_g2<3, true,  true,  false>(P + 18 * PL, P + 19 * PL, emB1, w5, b5, Vns3, row0, actH, actL, hred);
    } else {
        const int row0 = (g * 3 + (rm - 2)) * 32;
        short* actH = lds;
        short* actM = lds + 32 * ASTR;
        short* actL = lds + 2 * 32 * ASTR;
        stage3w<32>(Ucr, crW0 + 65536, crB0, row0, actH, actM, actL);
        __syncthreads();
        f32x4 acc[4][2];
#pragma unroll
        for (int a = 0; a < 4; ++a) { acc[a][0] = f32x4{0.f,0.f,0.f,0.f}; acc[a][1] = f32x4{0.f,0.f,0.f,0.f}; }
        mm3<2, 6>(P + 3*PL, P + 4*PL, P + 5*PL, actH, actM, actL, acc);
        float hp[2] = {0.f, 0.f};
#pragma unroll
        for (int ct = 0; ct < 4; ++ct) {
            const int colb = wv * 64 + ct * 16 + lng * 4;
            const float4 b1 = *(const float4*)(crB1 + colb);
#pragma unroll
            for (int rt = 0; rt < 2; ++rt) {
                f32x4 v = acc[ct][rt];
                v[0] += b1.x; v[1] += b1.y; v[2] += b1.z; v[3] += b1.w;
#pragma unroll
                for (int j = 0; j < 4; ++j) v[j] = fmaxf(v[j], 0.f);
#pragma unroll
                for (int j = 0; j < 4; ++j) hp[rt] += v[j] * crW2[(colb + j) * 2];
            }
        }
#pragma unroll
        for (int rt = 0; rt < 2; ++rt) {
            hp[rt] += __shfl_xor(hp[rt], 16);
            hp[rt] += __shfl_xor(hp[rt], 32);
        }
        if (lng == 0) {
#pragma unroll
            for (int rt = 0; rt < 2; ++rt) hred[wv * 32 + rt * 16 + ln15] = hp[rt];
        }
        __syncthreads();
        if (tid < 32)
            cont2[row0 + tid] = hred[tid] + hred[32 + tid] + hred[64 + tid] + hred[96 + tid] + crB2[0];
    }
}

extern "C" void kernel_launch(void* const* d_in, const int* in_sizes, int n_in,
                              void* d_out, int out_size, void* d_ws, size_t ws_size,
                              hipStream_t stream)
{
    (void)in_sizes; (void)n_in; (void)out_size; (void)ws_size;
    const float* x    = (const float*)d_in[0];
    const float* emW0 = (const float*)d_in[1];
    const float* emB0 = (const float*)d_in[2];
    const float* emW1 = (const float*)d_in[3];
    const float* emB1 = (const float*)d_in[4];
    const float* emW2 = (const float*)d_in[5];
    const float* emB2 = (const float*)d_in[6];
    const float* vW   = (const float*)d_in[7];
    const float* vb   = (const float*)d_in[8];
    const float* crW0 = (const float*)d_in[9];
    const float* crB0 = (const float*)d_in[10];
    const float* crW1 = (const float*)d_in[11];
    const float* crB1 = (const float*)d_in[12];
    const float* crW2 = (const float*)d_in[13];
    const float* crB2 = (const float*)d_in[14];
    const float* tmW0 = (const float*)d_in[15];
    const float* tmB0 = (const float*)d_in[16];
    const float* tmW1 = (const float*)d_in[17];
    const float* tmB1 = (const float*)d_in[18];
    const float* tmW2 = (const float*)d_in[19];
    const float* tmB2 = (const float*)d_in[20];
    float* out = (float*)d_out;

    float* w     = (float*)d_ws;
    float* rews0 = w;                     // 480
    float* cont1 = rews0 + 480;           // 7200
    float* rews1 = cont1 + 7200;          // 7200
    float* cont2 = rews1 + 7200;          // 108000
    float* Vns3  = cont2 + 108000;        // 108000
    float* U1cr  = Vns3 + 108000;         // 32*256
    float* U1tm  = U1cr + 32 * 256;       // 32*256
    short* planes = (short*)(U1tm + 32 * 256);  // 24 * PL shorts = 3 MB
    float* U2cr  = (float*)(planes + 24 * PL);  // 480*256
    float* U2tm  = U2cr + 480 * 256;            // 480*256
    float* Ucr   = U2tm + 480 * 256;            // 7200*256
    float* Utm   = Ucr + 7200 * 256;            // 7200*256
    float* w5    = Utm + 7200 * 256;            // 256
    float* b5    = w5 + 256;                    // 1

    front_kernel<<<81, 256, 0, stream>>>(x,
        emW0, emB0, emW1, emB1, emW2, emB2, vW, vb,
        crW0, crW1, tmW0, tmW1, tmW2,
        planes, w5, b5, out + NB * NA, U1cr, U1tm);
    stage1m_kernel<<<30, 256, 0, stream>>>(U1cr, U1tm, planes,
        crW0, crB0, crB1, crW2, crB2, tmW0, tmB0, tmB1, tmB2,
        rews0, U2cr, U2tm);
    stage2m_kernel<<<450, 256, 0, stream>>>(U2cr, U2tm, planes,
        crW0, crB0, crB1, crW2, crB2, tmW0, tmB0, tmB1, tmB2,
        cont1, rews1, Ucr, Utm);
    k3ab_kernel<<<5625, 256, 0, stream>>>(Ucr, Utm, planes,
        crW0, crB0, crB1, crW2, crB2,
        tmW0, tmB0, tmB1, tmB2, emB0, emB1, w5, b5, cont2, Vns3);
    finalize_kernel<<<NB, 256, 0, stream>>>(Vns3, cont2, rews0, rews1, cont1, out);
}

// Round 15
// 328.830 us; speedup vs baseline: 1.3257x; 1.1703x over previous
//
#include <hip/hip_runtime.h>

#define NA 15
#define NB 32
#define DD 256
#define PL 65536  // shorts per weight plane (8 slices x 256 cols x 32 k)
#define ASTR 264  // act LDS row stride (shorts)

using bf16x8 = __attribute__((ext_vector_type(8))) short;
using f32x4  = __attribute__((ext_vector_type(4))) float;

__device__ __forceinline__ unsigned short f2bf(float f){
  unsigned int u = __float_as_uint(f);
  u = u + 0x7fffu + ((u >> 16) & 1u);
  return (unsigned short)(u >> 16);
}
__device__ __forceinline__ float bf2f(unsigned short h){
  return __uint_as_float(((unsigned int)h) << 16);
}
__device__ __forceinline__ unsigned int cvtpk_bf16(float lo, float hi){
    unsigned int r;
    asm("v_cvt_pk_bf16_f32 %0, %1, %2" : "=v"(r) : "v"(lo), "v"(hi));
    return r;
}
__device__ __forceinline__ void split2_write(const float v[4], short* pH, short* pL){
    unsigned int h01 = cvtpk_bf16(v[0], v[1]);
    unsigned int h23 = cvtpk_bf16(v[2], v[3]);
    float r0 = v[0] - __uint_as_float(h01 << 16);
    float r1 = v[1] - __uint_as_float(h01 & 0xffff0000u);
    float r2 = v[2] - __uint_as_float(h23 << 16);
    float r3 = v[3] - __uint_as_float(h23 & 0xffff0000u);
    unsigned int l01 = cvtpk_bf16(r0, r1);
    unsigned int l23 = cvtpk_bf16(r2, r3);
    *(uint2*)pH = make_uint2(h01, h23);
    *(uint2*)pL = make_uint2(l01, l23);
}
__device__ __forceinline__ void split3_write(const float v[4], short* pH, short* pM, short* pL){
    unsigned int h01 = cvtpk_bf16(v[0], v[1]);
    unsigned int h23 = cvtpk_bf16(v[2], v[3]);
    float r0 = v[0] - __uint_as_float(h01 << 16);
    float r1 = v[1] - __uint_as_float(h01 & 0xffff0000u);
    float r2 = v[2] - __uint_as_float(h23 << 16);
    float r3 = v[3] - __uint_as_float(h23 & 0xffff0000u);
    unsigned int m01 = cvtpk_bf16(r0, r1);
    unsigned int m23 = cvtpk_bf16(r2, r3);
    float s0 = r0 - __uint_as_float(m01 << 16);
    float s1 = r1 - __uint_as_float(m01 & 0xffff0000u);
    float s2 = r2 - __uint_as_float(m23 << 16);
    float s3 = r3 - __uint_as_float(m23 & 0xffff0000u);
    unsigned int l01 = cvtpk_bf16(s0, s1);
    unsigned int l23 = cvtpk_bf16(s2, s3);
    *(uint2*)pH = make_uint2(h01, h23);
    *(uint2*)pM = make_uint2(m01, m23);
    *(uint2*)pL = make_uint2(l01, l23);
}

// ---------------------------------------------------------------------------
// fp32 VALU primitives (value_x branch of front kernel)
// ---------------------------------------------------------------------------
template<int TM, bool RELU>
__device__ __forceinline__ void layer256(
    const float* __restrict__ W, const float* __restrict__ bias,
    const float* act, int K, int lda, float* out, int ldo)
{
    constexpr int RPG = TM / 4;
    const int tid = threadIdx.x;
    const int tr = tid >> 6;
    const int tc = tid & 63;
    float acc[RPG][4];
#pragma unroll
    for (int i = 0; i < RPG; ++i) { acc[i][0]=0.f; acc[i][1]=0.f; acc[i][2]=0.f; acc[i][3]=0.f; }
    const float* wp = W + 4 * tc;
    int k = 0;
    for (; k + 4 <= K; k += 4) {
        float4 w0 = *reinterpret_cast<const float4*>(wp + (k + 0) * DD);
        float4 w1 = *reinterpret_cast<const float4*>(wp + (k + 1) * DD);
        float4 w2 = *reinterpret_cast<const float4*>(wp + (k + 2) * DD);
        float4 w3 = *reinterpret_cast<const float4*>(wp + (k + 3) * DD);
#pragma unroll
        for (int i = 0; i < RPG; ++i) {
            float4 a = *reinterpret_cast<const float4*>(act + (RPG * tr + i) * lda + k);
            acc[i][0] += a.x * w0.x + a.y * w1.x + a.z * w2.x + a.w * w3.x;
            acc[i][1] += a.x * w0.y + a.y * w1.y + a.z * w2.y + a.w * w3.y;
            acc[i][2] += a.x * w0.z + a.y * w1.z + a.z * w2.z + a.w * w3.z;
            acc[i][3] += a.x * w0.w + a.y * w1.w + a.z * w2.w + a.w * w3.w;
        }
    }
    for (; k < K; ++k) {
        float4 w0 = *reinterpret_cast<const float4*>(wp + k * DD);
#pragma unroll
        for (int i = 0; i < RPG; ++i) {
            float a = act[(RPG * tr + i) * lda + k];
            acc[i][0] += a * w0.x; acc[i][1] += a * w0.y;
            acc[i][2] += a * w0.z; acc[i][3] += a * w0.w;
        }
    }
    float4 bb = *reinterpret_cast<const float4*>(bias + 4 * tc);
#pragma unroll
    for (int i = 0; i < RPG; ++i) {
        float4 o;
        o.x = acc[i][0] + bb.x; o.y = acc[i][1] + bb.y;
        o.z = acc[i][2] + bb.z; o.w = acc[i][3] + bb.w;
        if (RELU) {
            o.x = fmaxf(o.x, 0.f); o.y = fmaxf(o.y, 0.f);
            o.z = fmaxf(o.z, 0.f); o.w = fmaxf(o.w, 0.f);
        }
        *reinterpret_cast<float4*>(out + (RPG * tr + i) * ldo + 4 * tc) = o;
    }
}

template<int TM>
__device__ __forceinline__ void head1c(
    const float* h, int ldh, const float* __restrict__ W, int wstr, int col, float bias,
    float* __restrict__ gout, int gbase)
{
    const int wv = threadIdx.x >> 6;
    const int lane = threadIdx.x & 63;
    for (int rr = wv; rr < TM; rr += 4) {
        float p = 0.f;
#pragma unroll
        for (int t = 0; t < 4; ++t) {
            int k = lane + 64 * t;
            p += h[rr * ldh + k] * W[k * wstr + col];
        }
#pragma unroll
        for (int m = 1; m < 64; m <<= 1) p += __shfl_xor(p, m);
        if (lane == 0) gout[gbase + rr] = p + bias;
    }
}

// ---------------------------------------------------------------------------
// front_kernel:
//  blocks 0-23  : bf16 split of crW1(planes 0-2), tmW1(3-5), emW1(6-8)
//  block  24    : w5 = emW2 @ vW, b5
//  blocks 25-32 : value_x (TM=4)
//  blocks 33-40 : U1 (x @ crW0/tmW0, fp32 exact)
//  blocks 41-64 : products W45=tmW2@emW0 (planes 9-11), W2cr=tmW2@crW0 (12-14),
//                 W2tm=tmW2@tmW0 (15-17); 32 rows/block, fp32 then split3
//  block  65    : constants c2cr = tmB2@crW0, c2tm = tmB2@tmW0, b45 = tmB2@emW0+emB0
// ---------------------------------------------------------------------------
__global__ __launch_bounds__(256) void front_kernel(
    const float* __restrict__ x,
    const float* __restrict__ emW0, const float* __restrict__ emB0,
    const float* __restrict__ emW1, const float* __restrict__ emB1,
    const float* __restrict__ emW2, const float* __restrict__ emB2,
    const float* __restrict__ vW, const float* __restrict__ vb,
    const float* __restrict__ crW0, const float* __restrict__ crW1,
    const float* __restrict__ tmW0, const float* __restrict__ tmW1,
    const float* __restrict__ tmW2, const float* __restrict__ tmB2,
    short* __restrict__ planes, float* __restrict__ w5, float* __restrict__ b5,
    float* __restrict__ c2cr, float* __restrict__ c2tm, float* __restrict__ b45,
    float* __restrict__ vout, float* __restrict__ U1cr, float* __restrict__ U1tm)
{
    __shared__ __align__(16) float smem[32 * DD];
    const int blk = blockIdx.x;
    const int tid = threadIdx.x;

    if (blk < 24) {
        const int mat = blk >> 3;
        const int kk  = blk & 7;
        const float* W = (mat == 0) ? crW1 : (mat == 1) ? tmW1 : emW1;
        const int col = tid;
        short bh[32], bm[32], bl[32];
#pragma unroll
        for (int j = 0; j < 32; ++j) {
            float w = W[(kk * 32 + j) * 256 + col];
            unsigned short h = f2bf(w); float fh = bf2f(h);
            float r1 = w - fh;
            unsigned short m = f2bf(r1); float fm = bf2f(m);
            bh[j] = (short)h; bm[j] = (short)m; bl[j] = (short)f2bf(r1 - fm);
        }
        short* pH = planes + (size_t)(mat * 3 + 0) * PL + kk * 8192 + col * 32;
        short* pM = planes + (size_t)(mat * 3 + 1) * PL + kk * 8192 + col * 32;
        short* pLp = planes + (size_t)(mat * 3 + 2) * PL + kk * 8192 + col * 32;
#pragma unroll
        for (int j = 0; j < 32; j += 4) {
            *(short4*)(pH + j) = make_short4(bh[j], bh[j+1], bh[j+2], bh[j+3]);
            *(short4*)(pM + j) = make_short4(bm[j], bm[j+1], bm[j+2], bm[j+3]);
            *(short4*)(pLp + j) = make_short4(bl[j], bl[j+1], bl[j+2], bl[j+3]);
        }
    } else if (blk == 24) {
        float acc = 0.f;
        for (int j = 0; j < 256; j += 4) {
            float4 wrow = *(const float4*)(emW2 + tid * 256 + j);
            float4 vv   = *(const float4*)(vW + j);
            acc += wrow.x * vv.x + wrow.y * vv.y + wrow.z * vv.z + wrow.w * vv.w;
        }
        w5[tid] = acc;
        if (tid == 0) {
            float b = 0.f;
            for (int j = 0; j < 256; ++j) b += emB2[j] * vW[j];
            b5[0] = b + vb[0];
        }
    } else if (blk < 33) {
        constexpr int TM = 4;
        float* bufA = smem;
        float* bufB = bufA + TM * DD;
        float* bufC = bufB + TM * DD;
        const int row0 = (blk - 25) * TM;
        for (int i = 0; i < TM; ++i) bufA[i * DD + tid] = x[(row0 + i) * DD + tid];
        __syncthreads();
        layer256<TM, true >(emW0, emB0, bufA, 256, DD, bufB, DD); __syncthreads();
        layer256<TM, true >(emW1, emB1, bufB, 256, DD, bufC, DD); __syncthreads();
        layer256<TM, false>(emW2, emB2, bufC, 256, DD, bufB, DD); __syncthreads();
        head1c<TM>(bufB, DD, vW, 1, 0, vb[0], vout, row0);
    } else if (blk < 41) {
        // U1: 4 x-rows per block; U1cr = x @ crW0[:256], U1tm = x @ tmW0[:256]
        const int row0 = (blk - 33) * 4;
        float* xs = smem;   // [4][256]
        for (int i = 0; i < 4; ++i) xs[i * 256 + tid] = x[(row0 + i) * 256 + tid];
        __syncthreads();
        float acr[4] = {0.f,0.f,0.f,0.f}, atm[4] = {0.f,0.f,0.f,0.f};
        for (int k = 0; k < 256; ++k) {
            float wc = crW0[k * 256 + tid];
            float wt = tmW0[k * 256 + tid];
#pragma unroll
            for (int i = 0; i < 4; ++i) {
                acr[i] += xs[i * 256 + k] * wc;
                atm[i] += xs[i * 256 + k] * wt;
            }
        }
        for (int i = 0; i < 4; ++i) {
            U1cr[(row0 + i) * 256 + tid] = acr[i];
            U1tm[(row0 + i) * 256 + tid] = atm[i];
        }
    } else if (blk < 65) {
        // products: 32 rows of tmW2 @ B, fp32 exact, then split3 into planes
        const int pb = blk - 41;
        const int prod = pb >> 3;           // 0=W45, 1=W2cr, 2=W2tm
        const int r0 = (pb & 7) * 32;
        const float* B = (prod == 0) ? emW0 : (prod == 1) ? crW0 : tmW0;
        const int pbase = 9 + prod * 3;
        float* As = smem;   // [32][256]
        for (int i = tid; i < 32 * 256; i += 256)
            As[i] = tmW2[(r0 + (i >> 8)) * 256 + (i & 255)];
        __syncthreads();
        float acc[32];
#pragma unroll
        for (int j = 0; j < 32; ++j) acc[j] = 0.f;
        for (int m = 0; m < 256; ++m) {
            float b = B[m * 256 + tid];
#pragma unroll
            for (int j = 0; j < 32; ++j) acc[j] += As[j * 256 + m] * b;
        }
        short bh[32], bm[32], bl[32];
#pragma unroll
        for (int j = 0; j < 32; ++j) {
            float w = acc[j];
            unsigned short h = f2bf(w); float fh = bf2f(h);
            float r1 = w - fh;
            unsigned short mm = f2bf(r1); float fm = bf2f(mm);
            bh[j] = (short)h; bm[j] = (short)mm; bl[j] = (short)f2bf(r1 - fm);
        }
        const int kk = r0 >> 5;
        short* pH = planes + (size_t)(pbase + 0) * PL + kk * 8192 + tid * 32;
        short* pM = planes + (size_t)(pbase + 1) * PL + kk * 8192 + tid * 32;
        short* pLp = planes + (size_t)(pbase + 2) * PL + kk * 8192 + tid * 32;
#pragma unroll
        for (int j = 0; j < 32; j += 4) {
            *(short4*)(pH + j) = make_short4(bh[j], bh[j+1], bh[j+2], bh[j+3]);
            *(short4*)(pM + j) = make_short4(bm[j], bm[j+1], bm[j+2], bm[j+3]);
            *(short4*)(pLp + j) = make_short4(bl[j], bl[j+1], bl[j+2], bl[j+3]);
        }
    } else {
        // constants
        const int j = tid;
        float a0 = 0.f, a1 = 0.f, a2 = 0.f;
        for (int k = 0; k < 256; ++k) {
            float t = tmB2[k];
            a0 += t * crW0[k * 256 + j];
            a1 += t * tmW0[k * 256 + j];
            a2 += t * emW0[k * 256 + j];
        }
        c2cr[j] = a0;
        c2tm[j] = a1;
        b45[j] = a2 + emB0[j];
    }
}

__global__ __launch_bounds__(256) void finalize_kernel(
    const float* __restrict__ Vns3, const float* __restrict__ cont2,
    const float* __restrict__ rews0, const float* __restrict__ rews1,
    const float* __restrict__ cont1, float* __restrict__ out)
{
    const int b = blockIdx.x;
    const int tid = threadIdx.x;
    __shared__ float vs2[NA][NA];
    __shared__ float vs3[NA];
    if (tid < NA * NA) {
        const int x = tid / NA, y = tid % NA;
        float vals[NA];
        float m = -INFINITY;
#pragma unroll
        for (int z = 0; z < NA; ++z) {
            int vidx = ((b * NA + y) * NA + z) * NA + x;
            int cidx = ((b * NA + x) * NA + y) * NA + z;
            float c1 = rews0[b * NA + z] * 0.99f;
            float c2 = (c1 + rews1[(b * NA + x) * NA + z]) * 0.99f;
            float v = Vns3[vidx] * 0.970299f + c2;
            if (cont2[cidx] > 0.f) v = 0.f;
            vals[z] = v;
            m = fmaxf(m, v);
        }
        float se = 0.f, sw = 0.f;
#pragma unroll
        for (int z = 0; z < NA; ++z) { float e = expf(vals[z] - m); se += e; sw += e * vals[z]; }
        vs2[x][y] = sw / se;
    }
    __syncthreads();
    if (tid < NA) {
        const int x = tid;
        float vals[NA];
        float m = -INFINITY;
#pragma unroll
        for (int y = 0; y < NA; ++y) {
            float v = vs2[x][y];
            if (cont1[(b * NA + x) * NA + y] > 0.f) v = 0.f;
            vals[y] = v;
            m = fmaxf(m, v);
        }
        float se = 0.f, sw = 0.f;
#pragma unroll
        for (int y = 0; y < NA; ++y) { float e = expf(vals[y] - m); se += e; sw += e * vals[y]; }
        vs3[x] = sw / se;
    }
    __syncthreads();
    if (tid == 0) {
        float m = -INFINITY;
#pragma unroll
        for (int x = 0; x < NA; ++x) m = fmaxf(m, vs3[x]);
        float se = 0.f;
#pragma unroll
        for (int x = 0; x < NA; ++x) se += expf(vs3[x] - m);
        float l = logf(se);
#pragma unroll
        for (int x = 0; x < NA; ++x) out[b * NA + x] = vs3[x] - m - l;
    }
}

// ---------------------------------------------------------------------------
// mm3: accumulate RT row-tiles x 4 col-tiles over K=256 with NP passes.
// ---------------------------------------------------------------------------
template<int RT, int NP>
__device__ __forceinline__ void mm3(
    const short* __restrict__ plH, const short* __restrict__ plM, const short* __restrict__ plL,
    const short* actH, const short* actM, const short* actL,
    f32x4 (&acc)[4][RT])
{
    const int tid = threadIdx.x;
    const int ln15 = tid & 15, lng = (tid >> 4) & 3, wv = tid >> 6;
    const int wo = (wv * 64 + ln15) * 32 + lng * 8;
#pragma unroll
    for (int kk = 0; kk < 8; ++kk) {
        bf16x8 wH[4], wM[4], wL[4], xH[RT], xM[RT], xL[RT];
#pragma unroll
        for (int ct = 0; ct < 4; ++ct) {
            wH[ct] = *(const bf16x8*)(plH + wo + kk * 8192 + ct * 512);
            wM[ct] = *(const bf16x8*)(plM + wo + kk * 8192 + ct * 512);
            if (NP == 6) wL[ct] = *(const bf16x8*)(plL + wo + kk * 8192 + ct * 512);
        }
#pragma unroll
        for (int rt = 0; rt < RT; ++rt) {
            int off = (rt * 16 + ln15) * ASTR + kk * 32 + lng * 8;
            xH[rt] = *(const bf16x8*)(actH + off);
            xM[rt] = *(const bf16x8*)(actM + off);
            if (NP == 6) xL[rt] = *(const bf16x8*)(actL + off);
        }
        __builtin_amdgcn_s_setprio(1);
#pragma unroll
        for (int ct = 0; ct < 4; ++ct)
#pragma unroll
            for (int rt = 0; rt < RT; ++rt) {
                acc[ct][rt] = __builtin_amdgcn_mfma_f32_16x16x32_bf16(wH[ct], xH[rt], acc[ct][rt], 0, 0, 0);
                acc[ct][rt] = __builtin_amdgcn_mfma_f32_16x16x32_bf16(wH[ct], xM[rt], acc[ct][rt], 0, 0, 0);
                acc[ct][rt] = __builtin_amdgcn_mfma_f32_16x16x32_bf16(wM[ct], xH[rt], acc[ct][rt], 0, 0, 0);
                if (NP == 6) {
                    acc[ct][rt] = __builtin_amdgcn_mfma_f32_16x16x32_bf16(wM[ct], xM[rt], acc[ct][rt], 0, 0, 0);
                    acc[ct][rt] = __builtin_amdgcn_mfma_f32_16x16x32_bf16(wH[ct], xL[rt], acc[ct][rt], 0, 0, 0);
                    acc[ct][rt] = __builtin_amdgcn_mfma_f32_16x16x32_bf16(wL[ct], xH[rt], acc[ct][rt], 0, 0, 0);
                }
            }
        __builtin_amdgcn_s_setprio(0);
    }
}

// stage a 3-way-split activation row block from U + a*wrow + bias (relu)
template<int ROWS>
__device__ __forceinline__ void stage3w(
    const float* __restrict__ U, const float* __restrict__ wrow256,
    const float* __restrict__ bias, int row0,
    short* actH, short* actM, short* actL)
{
    const int tid = threadIdx.x;
    const int wv = tid >> 6, ln = tid & 63;
    constexpr int RPW = ROWS / 4;
    const float4 wr = *(const float4*)(wrow256 + ln * 4);
    const float4 bb = *(const float4*)(bias + ln * 4);
    for (int i = wv * RPW; i < wv * RPW + RPW; ++i) {
        int r = row0 + i;
        int srow = r / 15;
        float a = (float)(r % 15);
        float4 u = *(const float4*)(U + srow * 256 + ln * 4);
        float sv[4];
        sv[0] = fmaxf(u.x + a * wr.x + bb.x, 0.f);
        sv[1] = fmaxf(u.y + a * wr.y + bb.y, 0.f);
        sv[2] = fmaxf(u.z + a * wr.z + bb.z, 0.f);
        sv[3] = fmaxf(u.w + a * wr.w + bb.w, 0.f);
        split3_write(sv, actH + i * ASTR + ln * 4, actM + i * ASTR + ln * 4, actL + i * ASTR + ln * 4);
    }
}

// ---------------------------------------------------------------------------
// stage1m: 480 rows (b,a1), 30 blocks x 16 rows. rews0 + U2cr/U2tm.
// Uses folded products: U2 = h1 @ W2 + c2 (tm2 collapsed).
// ---------------------------------------------------------------------------
__global__ __launch_bounds__(256, 2) void stage1m_kernel(
    const float* __restrict__ U1cr, const float* __restrict__ U1tm,
    const short* __restrict__ planes,
    const float* __restrict__ crW0, const float* __restrict__ crB0,
    const float* __restrict__ crB1, const float* __restrict__ crW2, const float* __restrict__ crB2,
    const float* __restrict__ tmW0, const float* __restrict__ tmB0,
    const float* __restrict__ tmB1,
    const float* __restrict__ c2cr, const float* __restrict__ c2tm,
    float* __restrict__ rews0, float* __restrict__ U2cr, float* __restrict__ U2tm)
{
    __shared__ short actH[16 * ASTR];
    __shared__ short actM[16 * ASTR];
    __shared__ short actL[16 * ASTR];
    __shared__ float hred[64];
    const int tid = threadIdx.x;
    const int row0 = blockIdx.x * 16;
    const int ln15 = tid & 15, lng = (tid >> 4) & 3, wv = tid >> 6;

    // ---- Phase A: cr chain -> rews0 (col 1) ----
    stage3w<16>(U1cr, crW0 + 65536, crB0, row0, actH, actM, actL);
    __syncthreads();
    {
        f32x4 acc[4][1];
#pragma unroll
        for (int a = 0; a < 4; ++a) acc[a][0] = f32x4{0.f,0.f,0.f,0.f};
        mm3<1, 6>(planes + 0*PL, planes + 1*PL, planes + 2*PL, actH, actM, actL, acc);
        float hp = 0.f;
#pragma unroll
        for (int ct = 0; ct < 4; ++ct) {
            const int colb = wv * 64 + ct * 16 + lng * 4;
            const float4 b1 = *(const float4*)(crB1 + colb);
            f32x4 v = acc[ct][0];
            v[0] += b1.x; v[1] += b1.y; v[2] += b1.z; v[3] += b1.w;
#pragma unroll
            for (int j = 0; j < 4; ++j) v[j] = fmaxf(v[j], 0.f);
#pragma unroll
            for (int j = 0; j < 4; ++j) hp += v[j] * crW2[(colb + j) * 2 + 1];
        }
        hp += __shfl_xor(hp, 16);
        hp += __shfl_xor(hp, 32);
        if (lng == 0) hred[wv * 16 + ln15] = hp;
        __syncthreads();
        if (tid < 16) rews0[row0 + tid] = hred[tid] + hred[16 + tid] + hred[32 + tid] + hred[48 + tid] + crB2[1];
        __syncthreads();
    }

    // ---- Phase B: tm0 staged, tm1, then folded U2 products ----
    stage3w<16>(U1tm, tmW0 + 65536, tmB0, row0, actH, actM, actL);
    __syncthreads();
    {
        f32x4 acc[4][1];
#pragma unroll
        for (int a = 0; a < 4; ++a) acc[a][0] = f32x4{0.f,0.f,0.f,0.f};
        mm3<1, 6>(planes + 3*PL, planes + 4*PL, planes + 5*PL, actH, actM, actL, acc);
        __syncthreads();
#pragma unroll
        for (int ct = 0; ct < 4; ++ct) {
            const int colb = wv * 64 + ct * 16 + lng * 4;
            const float4 bb = *(const float4*)(tmB1 + colb);
            f32x4 v = acc[ct][0];
            v[0] += bb.x; v[1] += bb.y; v[2] += bb.z; v[3] += bb.w;
#pragma unroll
            for (int j = 0; j < 4; ++j) v[j] = fmaxf(v[j], 0.f);
            float sv[4] = {v[0], v[1], v[2], v[3]};
            const int ao = ln15 * ASTR + colb;
            split3_write(sv, actH + ao, actM + ao, actL + ao);
        }
        __syncthreads();
    }
    {
        f32x4 acc[4][1];
#pragma unroll
        for (int a = 0; a < 4; ++a) acc[a][0] = f32x4{0.f,0.f,0.f,0.f};
        mm3<1, 6>(planes + 12*PL, planes + 13*PL, planes + 14*PL, actH, actM, actL, acc);
#pragma unroll
        for (int ct = 0; ct < 4; ++ct) {
            const int colb = wv * 64 + ct * 16 + lng * 4;
            const float4 cc = *(const float4*)(c2cr + colb);
            float4 o; o.x = acc[ct][0][0] + cc.x; o.y = acc[ct][0][1] + cc.y;
            o.z = acc[ct][0][2] + cc.z; o.w = acc[ct][0][3] + cc.w;
            *(float4*)(U2cr + (row0 + ln15) * 256 + colb) = o;
        }
    }
    {
        f32x4 acc[4][1];
#pragma unroll
        for (int a = 0; a < 4; ++a) acc[a][0] = f32x4{0.f,0.f,0.f,0.f};
        mm3<1, 6>(planes + 15*PL, planes + 16*PL, planes + 17*PL, actH, actM, actL, acc);
#pragma unroll
        for (int ct = 0; ct < 4; ++ct) {
            const int colb = wv * 64 + ct * 16 + lng * 4;
            const float4 cc = *(const float4*)(c2tm + colb);
            float4 o; o.x = acc[ct][0][0] + cc.x; o.y = acc[ct][0][1] + cc.y;
            o.z = acc[ct][0][2] + cc.z; o.w = acc[ct][0][3] + cc.w;
            *(float4*)(U2tm + (row0 + ln15) * 256 + colb) = o;
        }
    }
}

// ---------------------------------------------------------------------------
// stage2m: 7200 rows, 450 blocks x 16 rows. cont1/rews1 + Ucr/Utm (permuted).
// Folded products for Ucr/Utm.
// ---------------------------------------------------------------------------
__global__ __launch_bounds__(256, 2) void stage2m_kernel(
    const float* __restrict__ U2cr, const float* __restrict__ U2tm,
    const short* __restrict__ planes,
    const float* __restrict__ crW0, const float* __restrict__ crB0,
    const float* __restrict__ crB1, const float* __restrict__ crW2, const float* __restrict__ crB2,
    const float* __restrict__ tmW0, const float* __restrict__ tmB0,
    const float* __restrict__ tmB1,
    const float* __restrict__ c2cr, const float* __restrict__ c2tm,
    float* __restrict__ cont1, float* __restrict__ rews1,
    float* __restrict__ Ucr, float* __restrict__ Utm)
{
    __shared__ short actH[16 * ASTR];
    __shared__ short actM[16 * ASTR];
    __shared__ short actL[16 * ASTR];
    __shared__ float hred[2][64];
    const int tid = threadIdx.x;
    const int row0 = blockIdx.x * 16;
    const int ln15 = tid & 15, lng = (tid >> 4) & 3, wv = tid >> 6;

    // ---- Phase A: cr chain -> cont1, rews1 ----
    stage3w<16>(U2cr, crW0 + 65536, crB0, row0, actH, actM, actL);
    __syncthreads();
    {
        f32x4 acc[4][1];
#pragma unroll
        for (int a = 0; a < 4; ++a) acc[a][0] = f32x4{0.f,0.f,0.f,0.f};
        mm3<1, 6>(planes + 0*PL, planes + 1*PL, planes + 2*PL, actH, actM, actL, acc);
        float hp0 = 0.f, hp1 = 0.f;
#pragma unroll
        for (int ct = 0; ct < 4; ++ct) {
            const int colb = wv * 64 + ct * 16 + lng * 4;
            const float4 b1 = *(const float4*)(crB1 + colb);
            f32x4 v = acc[ct][0];
            v[0] += b1.x; v[1] += b1.y; v[2] += b1.z; v[3] += b1.w;
#pragma unroll
            for (int j = 0; j < 4; ++j) v[j] = fmaxf(v[j], 0.f);
#pragma unroll
            for (int j = 0; j < 4; ++j) {
                hp0 += v[j] * crW2[(colb + j) * 2 + 0];
                hp1 += v[j] * crW2[(colb + j) * 2 + 1];
            }
        }
        hp0 += __shfl_xor(hp0, 16); hp0 += __shfl_xor(hp0, 32);
        hp1 += __shfl_xor(hp1, 16); hp1 += __shfl_xor(hp1, 32);
        if (lng == 0) {
            hred[0][wv * 16 + ln15] = hp0;
            hred[1][wv * 16 + ln15] = hp1;
        }
        __syncthreads();
        if (tid < 16)
            cont1[row0 + tid] = hred[0][tid] + hred[0][16 + tid] + hred[0][32 + tid] + hred[0][48 + tid] + crB2[0];
        else if (tid >= 64 && tid < 80)
            rews1[row0 + tid - 64] = hred[1][tid - 64] + hred[1][16 + tid - 64] + hred[1][32 + tid - 64] + hred[1][48 + tid - 64] + crB2[1];
        __syncthreads();
    }

    // ---- Phase B: tm0 staged, tm1, folded Ucr/Utm (permuted) ----
    stage3w<16>(U2tm, tmW0 + 65536, tmB0, row0, actH, actM, actL);
    __syncthreads();
    {
        f32x4 acc[4][1];
#pragma unroll
        for (int a = 0; a < 4; ++a) acc[a][0] = f32x4{0.f,0.f,0.f,0.f};
        mm3<1, 6>(planes + 3*PL, planes + 4*PL, planes + 5*PL, actH, actM, actL, acc);
        __syncthreads();
#pragma unroll
        for (int ct = 0; ct < 4; ++ct) {
            const int colb = wv * 64 + ct * 16 + lng * 4;
            const float4 bb = *(const float4*)(tmB1 + colb);
            f32x4 v = acc[ct][0];
            v[0] += bb.x; v[1] += bb.y; v[2] += bb.z; v[3] += bb.w;
#pragma unroll
            for (int j = 0; j < 4; ++j) v[j] = fmaxf(v[j], 0.f);
            float sv[4] = {v[0], v[1], v[2], v[3]};
            const int ao = ln15 * ASTR + colb;
            split3_write(sv, actH + ao, actM + ao, actL + ao);
        }
        __syncthreads();
    }
    int pr;
    {
        int r = row0 + ln15;
        int b = r / 225, a1 = (r / 15) % 15, a2 = r % 15;
        pr = (b * 15 + a2) * 15 + a1;
    }
    {
        f32x4 acc[4][1];
#pragma unroll
        for (int a = 0; a < 4; ++a) acc[a][0] = f32x4{0.f,0.f,0.f,0.f};
        mm3<1, 6>(planes + 12*PL, planes + 13*PL, planes + 14*PL, actH, actM, actL, acc);
#pragma unroll
        for (int ct = 0; ct < 4; ++ct) {
            const int colb = wv * 64 + ct * 16 + lng * 4;
            const float4 cc = *(const float4*)(c2cr + colb);
            float4 o; o.x = acc[ct][0][0] + cc.x; o.y = acc[ct][0][1] + cc.y;
            o.z = acc[ct][0][2] + cc.z; o.w = acc[ct][0][3] + cc.w;
            *(float4*)(Ucr + pr * 256 + colb) = o;
        }
    }
    {
        f32x4 acc[4][1];
#pragma unroll
        for (int a = 0; a < 4; ++a) acc[a][0] = f32x4{0.f,0.f,0.f,0.f};
        mm3<1, 3>(planes + 15*PL, planes + 16*PL, planes + 17*PL, actH, actM, actL, acc);
#pragma unroll
        for (int ct = 0; ct < 4; ++ct) {
            const int colb = wv * 64 + ct * 16 + lng * 4;
            const float4 cc = *(const float4*)(c2tm + colb);
            float4 o; o.x = acc[ct][0][0] + cc.x; o.y = acc[ct][0][1] + cc.y;
            o.z = acc[ct][0][2] + cc.z; o.w = acc[ct][0][3] + cc.w;
            *(float4*)(Utm + pr * 256 + colb) = o;
        }
    }
}

// ---------------------------------------------------------------------------
// layer_g2: 2-way (H,M) 3-pass 16x16x32 layer over RT*16-row act tile.
// ---------------------------------------------------------------------------
template<int RT, bool RELU, bool HEAD, bool WRITEACT>
__device__ __forceinline__ void layer_g2(
    const short* __restrict__ plH, const short* __restrict__ plL,
    const float* __restrict__ bias,
    const float* __restrict__ headW, const float* __restrict__ headB,
    float* __restrict__ headOut, int row0,
    short* actH, short* actL, float* hred)
{
    const int tid = threadIdx.x;
    const int ln15 = tid & 15, lng = (tid >> 4) & 3, wv = tid >> 6;
    const int wo = (wv * 64 + ln15) * 32 + lng * 8;
    f32x4 acc[4][RT];
#pragma unroll
    for (int a = 0; a < 4; ++a)
#pragma unroll
        for (int b = 0; b < RT; ++b) acc[a][b] = f32x4{0.f, 0.f, 0.f, 0.f};

#pragma unroll
    for (int kk = 0; kk < 8; ++kk) {
        bf16x8 aH[4], aL[4], bH[RT], bL[RT];
#pragma unroll
        for (int ct = 0; ct < 4; ++ct) {
            aH[ct] = *(const bf16x8*)(plH + wo + kk * 8192 + ct * 512);
            aL[ct] = *(const bf16x8*)(plL + wo + kk * 8192 + ct * 512);
        }
#pragma unroll
        for (int rt = 0; rt < RT; ++rt) {
            int off = (rt * 16 + ln15) * ASTR + kk * 32 + lng * 8;
            bH[rt] = *(const bf16x8*)(actH + off);
            bL[rt] = *(const bf16x8*)(actL + off);
        }
        __builtin_amdgcn_s_setprio(1);
#pragma unroll
        for (int ct = 0; ct < 4; ++ct)
#pragma unroll
            for (int rt = 0; rt < RT; ++rt) {
                acc[ct][rt] = __builtin_amdgcn_mfma_f32_16x16x32_bf16(aH[ct], bH[rt], acc[ct][rt], 0, 0, 0);
                acc[ct][rt] = __builtin_amdgcn_mfma_f32_16x16x32_bf16(aH[ct], bL[rt], acc[ct][rt], 0, 0, 0);
                acc[ct][rt] = __builtin_amdgcn_mfma_f32_16x16x32_bf16(aL[ct], bH[rt], acc[ct][rt], 0, 0, 0);
            }
        __builtin_amdgcn_s_setprio(0);
    }
    __syncthreads();

    float hp[RT];
#pragma unroll
    for (int rt = 0; rt < RT; ++rt) hp[rt] = 0.f;
#pragma unroll
    for (int ct = 0; ct < 4; ++ct) {
        const int colb = wv * 64 + ct * 16 + lng * 4;
        const float4 bb = *(const float4*)(bias + colb);
#pragma unroll
        for (int rt = 0; rt < RT; ++rt) {
            f32x4 v = acc[ct][rt];
            v[0] += bb.x; v[1] += bb.y; v[2] += bb.z; v[3] += bb.w;
            if (RELU) {
#pragma unroll
                for (int j = 0; j < 4; ++j) v[j] = fmaxf(v[j], 0.f);
            }
            if (HEAD) {
                const float4 hw = *(const float4*)(headW + colb);
                hp[rt] += v[0] * hw.x + v[1] * hw.y + v[2] * hw.z + v[3] * hw.w;
            }
            if (WRITEACT) {
                float sv[4] = {v[0], v[1], v[2], v[3]};
                const int ao = (rt * 16 + ln15) * ASTR + colb;
                split2_write(sv, actH + ao, actL + ao);
            }
        }
    }
    if constexpr (HEAD) {
        constexpr int NR = RT * 16;
#pragma unroll
        for (int rt = 0; rt < RT; ++rt) {
            hp[rt] += __shfl_xor(hp[rt], 16);
            hp[rt] += __shfl_xor(hp[rt], 32);
        }
        if (lng == 0) {
#pragma unroll
            for (int rt = 0; rt < RT; ++rt) hred[wv * NR + rt * 16 + ln15] = hp[rt];
        }
        __syncthreads();
        if (tid < NR) {
            float s = hred[tid] + hred[NR + tid] + hred[2 * NR + tid] + hred[3 * NR + tid] + headB[0];
            headOut[row0 + tid] = s;
        }
    }
    if constexpr (WRITEACT) __syncthreads();
}

// ---------------------------------------------------------------------------
// k3ab: fused stage-3, 3 blocks/CU. k3b now only 3 layers (tm2·em0 folded).
// 5625 blocks in groups of 5: 2x k3b (48-row) + 3x k3a (32-row).
// ---------------------------------------------------------------------------
__global__ __launch_bounds__(256, 3) void k3ab_kernel(
    const float* __restrict__ Ucr, const float* __restrict__ Utm,
    const short* __restrict__ planes,
    const float* __restrict__ crW0, const float* __restrict__ crB0,
    const float* __restrict__ crB1, const float* __restrict__ crW2,
    const float* __restrict__ crB2,
    const float* __restrict__ tmW0, const float* __restrict__ tmB0,
    const float* __restrict__ tmB1,
    const float* __restrict__ b45, const float* __restrict__ emB1,
    const float* __restrict__ w5, const float* __restrict__ b5,
    float* __restrict__ cont2, float* __restrict__ Vns3)
{
    __shared__ short lds[2 * 48 * ASTR];   // == 3 * 32 * ASTR
    __shared__ float hred[192];
    const int tid = threadIdx.x;
    const int g = blockIdx.x / 5, rm = blockIdx.x % 5;
    const bool isB = rm < 2;
    const int ln15 = tid & 15, lng = (tid >> 4) & 3, wv = tid >> 6;
    const short* P = planes;

    if (isB) {
        const int row0 = (g * 2 + rm) * 48;
        short* actH = lds;
        short* actL = lds + 48 * ASTR;
        const int ln = tid & 63;
        const float4 wr = *(const float4*)(tmW0 + 65536 + ln * 4);
        const float4 bb = *(const float4*)(tmB0 + ln * 4);
        for (int i = wv * 12; i < wv * 12 + 12; ++i) {
            int r = row0 + i;
            int srow = r / 15;
            float a = (float)(r % 15);
            float4 u = *(const float4*)(Utm + srow * 256 + ln * 4);
            float sv[4];
            sv[0] = fmaxf(u.x + a * wr.x + bb.x, 0.f);
            sv[1] = fmaxf(u.y + a * wr.y + bb.y, 0.f);
            sv[2] = fmaxf(u.z + a * wr.z + bb.z, 0.f);
            sv[3] = fmaxf(u.w + a * wr.w + bb.w, 0.f);
            split2_write(sv, actH + i * ASTR + ln * 4, actL + i * ASTR + ln * 4);
        }
        __syncthreads();
        layer_g2<3, true,  false, true >(P + 3 * PL,  P + 4 * PL,  tmB1, nullptr, nullptr, nullptr, row0, actH, actL, hred);
        layer_g2<3, true,  false, true >(P + 9 * PL,  P + 10 * PL, b45,  nullptr, nullptr, nullptr, row0, actH, actL, hred);
        layer_g2<3, true,  true,  false>(P + 6 * PL,  P + 7 * PL,  emB1, w5, b5, Vns3, row0, actH, actL, hred);
    } else {
        const int row0 = (g * 3 + (rm - 2)) * 32;
        short* actH = lds;
        short* actM = lds + 32 * ASTR;
        short* actL = lds + 2 * 32 * ASTR;
        stage3w<32>(Ucr, crW0 + 65536, crB0, row0, actH, actM, actL);
        __syncthreads();
        f32x4 acc[4][2];
#pragma unroll
        for (int a = 0; a < 4; ++a) { acc[a][0] = f32x4{0.f,0.f,0.f,0.f}; acc[a][1] = f32x4{0.f,0.f,0.f,0.f}; }
        mm3<2, 6>(P + 0*PL, P + 1*PL, P + 2*PL, actH, actM, actL, acc);
        float hp[2] = {0.f, 0.f};
#pragma unroll
        for (int ct = 0; ct < 4; ++ct) {
            const int colb = wv * 64 + ct * 16 + lng * 4;
            const float4 b1 = *(const float4*)(crB1 + colb);
#pragma unroll
            for (int rt = 0; rt < 2; ++rt) {
                f32x4 v = acc[ct][rt];
                v[0] += b1.x; v[1] += b1.y; v[2] += b1.z; v[3] += b1.w;
#pragma unroll
                for (int j = 0; j < 4; ++j) v[j] = fmaxf(v[j], 0.f);
#pragma unroll
                for (int j = 0; j < 4; ++j) hp[rt] += v[j] * crW2[(colb + j) * 2];
            }
        }
#pragma unroll
        for (int rt = 0; rt < 2; ++rt) {
            hp[rt] += __shfl_xor(hp[rt], 16);
            hp[rt] += __shfl_xor(hp[rt], 32);
        }
        if (lng == 0) {
#pragma unroll
            for (int rt = 0; rt < 2; ++rt) hred[wv * 32 + rt * 16 + ln15] = hp[rt];
        }
        __syncthreads();
        if (tid < 32)
            cont2[row0 + tid] = hred[tid] + hred[32 + tid] + hred[64 + tid] + hred[96 + tid] + crB2[0];
    }
}

extern "C" void kernel_launch(void* const* d_in, const int* in_sizes, int n_in,
                              void* d_out, int out_size, void* d_ws, size_t ws_size,
                              hipStream_t stream)
{
    (void)in_sizes; (void)n_in; (void)out_size; (void)ws_size;
    const float* x    = (const float*)d_in[0];
    const float* emW0 = (const float*)d_in[1];
    const float* emB0 = (const float*)d_in[2];
    const float* emW1 = (const float*)d_in[3];
    const float* emB1 = (const float*)d_in[4];
    const float* emW2 = (const float*)d_in[5];
    const float* emB2 = (const float*)d_in[6];
    const float* vW   = (const float*)d_in[7];
    const float* vb   = (const float*)d_in[8];
    const float* crW0 = (const float*)d_in[9];
    const float* crB0 = (const float*)d_in[10];
    const float* crW1 = (const float*)d_in[11];
    const float* crB1 = (const float*)d_in[12];
    const float* crW2 = (const float*)d_in[13];
    const float* crB2 = (const float*)d_in[14];
    const float* tmW0 = (const float*)d_in[15];
    const float* tmB0 = (const float*)d_in[16];
    const float* tmW1 = (const float*)d_in[17];
    const float* tmB1 = (const float*)d_in[18];
    const float* tmW2 = (const float*)d_in[19];
    const float* tmB2 = (const float*)d_in[20];
    float* out = (float*)d_out;

    float* w     = (float*)d_ws;
    float* rews0 = w;                     // 480
    float* cont1 = rews0 + 480;           // 7200
    float* rews1 = cont1 + 7200;          // 7200
    float* cont2 = rews1 + 7200;          // 108000
    float* Vns3  = cont2 + 108000;        // 108000
    float* U1cr  = Vns3 + 108000;         // 32*256
    float* U1tm  = U1cr + 32 * 256;       // 32*256
    short* planes = (short*)(U1tm + 32 * 256);  // 18 * PL shorts = 2.25 MB
    float* U2cr  = (float*)(planes + 18 * PL);  // 480*256
    float* U2tm  = U2cr + 480 * 256;            // 480*256
    float* Ucr   = U2tm + 480 * 256;            // 7200*256
    float* Utm   = Ucr + 7200 * 256;            // 7200*256
    float* w5    = Utm + 7200 * 256;            // 256
    float* b5    = w5 + 256;                    // 1 (pad to 4)
    float* c2cr  = b5 + 4;                      // 256
    float* c2tm  = c2cr + 256;                  // 256
    float* b45   = c2tm + 256;                  // 256

    front_kernel<<<66, 256, 0, stream>>>(x,
        emW0, emB0, emW1, emB1, emW2, emB2, vW, vb,
        crW0, crW1, tmW0, tmW1, tmW2, tmB2,
        planes, w5, b5, c2cr, c2tm, b45,
        out + NB * NA, U1cr, U1tm);
    stage1m_kernel<<<30, 256, 0, stream>>>(U1cr, U1tm, planes,
        crW0, crB0, crB1, crW2, crB2, tmW0, tmB0, tmB1,
        c2cr, c2tm, rews0, U2cr, U2tm);
    stage2m_kernel<<<450, 256, 0, stream>>>(U2cr, U2tm, planes,
        crW0, crB0, crB1, crW2, crB2, tmW0, tmB0, tmB1,
        c2cr, c2tm, cont1, rews1, Ucr, Utm);
    k3ab_kernel<<<5625, 256, 0, stream>>>(Ucr, Utm, planes,
        crW0, crB0, crB1, crW2, crB2,
        tmW0, tmB0, tmB1, b45, emB1, w5, b5, cont2, Vns3);
    finalize_kernel<<<NB, 256, 0, stream>>>(Vns3, cont2, rews0, rews1, cont1, out);
}

// Round 16
// 306.503 us; speedup vs baseline: 1.4223x; 1.0728x over previous
//
#include <hip/hip_runtime.h>

#define NA 15
#define NB 32
#define DD 256
#define PL 65536  // shorts per weight plane (8 slices x 256 cols x 32 k)
#define ASTR 264  // act LDS row stride (shorts)

using bf16x8 = __attribute__((ext_vector_type(8))) short;
using f32x4  = __attribute__((ext_vector_type(4))) float;

__device__ __forceinline__ unsigned short f2bf(float f){
  unsigned int u = __float_as_uint(f);
  u = u + 0x7fffu + ((u >> 16) & 1u);
  return (unsigned short)(u >> 16);
}
__device__ __forceinline__ float bf2f(unsigned short h){
  return __uint_as_float(((unsigned int)h) << 16);
}
__device__ __forceinline__ unsigned int cvtpk_bf16(float lo, float hi){
    unsigned int r;
    asm("v_cvt_pk_bf16_f32 %0, %1, %2" : "=v"(r) : "v"(lo), "v"(hi));
    return r;
}
__device__ __forceinline__ void split2_write(const float v[4], short* pH, short* pL){
    unsigned int h01 = cvtpk_bf16(v[0], v[1]);
    unsigned int h23 = cvtpk_bf16(v[2], v[3]);
    float r0 = v[0] - __uint_as_float(h01 << 16);
    float r1 = v[1] - __uint_as_float(h01 & 0xffff0000u);
    float r2 = v[2] - __uint_as_float(h23 << 16);
    float r3 = v[3] - __uint_as_float(h23 & 0xffff0000u);
    unsigned int l01 = cvtpk_bf16(r0, r1);
    unsigned int l23 = cvtpk_bf16(r2, r3);
    *(uint2*)pH = make_uint2(h01, h23);
    *(uint2*)pL = make_uint2(l01, l23);
}
__device__ __forceinline__ void split3_write(const float v[4], short* pH, short* pM, short* pL){
    unsigned int h01 = cvtpk_bf16(v[0], v[1]);
    unsigned int h23 = cvtpk_bf16(v[2], v[3]);
    float r0 = v[0] - __uint_as_float(h01 << 16);
    float r1 = v[1] - __uint_as_float(h01 & 0xffff0000u);
    float r2 = v[2] - __uint_as_float(h23 << 16);
    float r3 = v[3] - __uint_as_float(h23 & 0xffff0000u);
    unsigned int m01 = cvtpk_bf16(r0, r1);
    unsigned int m23 = cvtpk_bf16(r2, r3);
    float s0 = r0 - __uint_as_float(m01 << 16);
    float s1 = r1 - __uint_as_float(m01 & 0xffff0000u);
    float s2 = r2 - __uint_as_float(m23 << 16);
    float s3 = r3 - __uint_as_float(m23 & 0xffff0000u);
    unsigned int l01 = cvtpk_bf16(s0, s1);
    unsigned int l23 = cvtpk_bf16(s2, s3);
    *(uint2*)pH = make_uint2(h01, h23);
    *(uint2*)pM = make_uint2(m01, m23);
    *(uint2*)pL = make_uint2(l01, l23);
}

// ---------------------------------------------------------------------------
// fp32 VALU primitives (value_x branch of front kernel)
// ---------------------------------------------------------------------------
template<int TM, bool RELU>
__device__ __forceinline__ void layer256(
    const float* __restrict__ W, const float* __restrict__ bias,
    const float* act, int K, int lda, float* out, int ldo)
{
    constexpr int RPG = TM / 4;
    const int tid = threadIdx.x;
    const int tr = tid >> 6;
    const int tc = tid & 63;
    float acc[RPG][4];
#pragma unroll
    for (int i = 0; i < RPG; ++i) { acc[i][0]=0.f; acc[i][1]=0.f; acc[i][2]=0.f; acc[i][3]=0.f; }
    const float* wp = W + 4 * tc;
    int k = 0;
    for (; k + 4 <= K; k += 4) {
        float4 w0 = *reinterpret_cast<const float4*>(wp + (k + 0) * DD);
        float4 w1 = *reinterpret_cast<const float4*>(wp + (k + 1) * DD);
        float4 w2 = *reinterpret_cast<const float4*>(wp + (k + 2) * DD);
        float4 w3 = *reinterpret_cast<const float4*>(wp + (k + 3) * DD);
#pragma unroll
        for (int i = 0; i < RPG; ++i) {
            float4 a = *reinterpret_cast<const float4*>(act + (RPG * tr + i) * lda + k);
            acc[i][0] += a.x * w0.x + a.y * w1.x + a.z * w2.x + a.w * w3.x;
            acc[i][1] += a.x * w0.y + a.y * w1.y + a.z * w2.y + a.w * w3.y;
            acc[i][2] += a.x * w0.z + a.y * w1.z + a.z * w2.z + a.w * w3.z;
            acc[i][3] += a.x * w0.w + a.y * w1.w + a.z * w2.w + a.w * w3.w;
        }
    }
    for (; k < K; ++k) {
        float4 w0 = *reinterpret_cast<const float4*>(wp + k * DD);
#pragma unroll
        for (int i = 0; i < RPG; ++i) {
            float a = act[(RPG * tr + i) * lda + k];
            acc[i][0] += a * w0.x; acc[i][1] += a * w0.y;
            acc[i][2] += a * w0.z; acc[i][3] += a * w0.w;
        }
    }
    float4 bb = *reinterpret_cast<const float4*>(bias + 4 * tc);
#pragma unroll
    for (int i = 0; i < RPG; ++i) {
        float4 o;
        o.x = acc[i][0] + bb.x; o.y = acc[i][1] + bb.y;
        o.z = acc[i][2] + bb.z; o.w = acc[i][3] + bb.w;
        if (RELU) {
            o.x = fmaxf(o.x, 0.f); o.y = fmaxf(o.y, 0.f);
            o.z = fmaxf(o.z, 0.f); o.w = fmaxf(o.w, 0.f);
        }
        *reinterpret_cast<float4*>(out + (RPG * tr + i) * ldo + 4 * tc) = o;
    }
}

template<int TM>
__device__ __forceinline__ void head1c(
    const float* h, int ldh, const float* __restrict__ W, int wstr, int col, float bias,
    float* __restrict__ gout, int gbase)
{
    const int wv = threadIdx.x >> 6;
    const int lane = threadIdx.x & 63;
    for (int rr = wv; rr < TM; rr += 4) {
        float p = 0.f;
#pragma unroll
        for (int t = 0; t < 4; ++t) {
            int k = lane + 64 * t;
            p += h[rr * ldh + k] * W[k * wstr + col];
        }
#pragma unroll
        for (int m = 1; m < 64; m <<= 1) p += __shfl_xor(p, m);
        if (lane == 0) gout[gbase + rr] = p + bias;
    }
}

// ---------------------------------------------------------------------------
// front_kernel (unchanged from R15)
// ---------------------------------------------------------------------------
__global__ __launch_bounds__(256) void front_kernel(
    const float* __restrict__ x,
    const float* __restrict__ emW0, const float* __restrict__ emB0,
    const float* __restrict__ emW1, const float* __restrict__ emB1,
    const float* __restrict__ emW2, const float* __restrict__ emB2,
    const float* __restrict__ vW, const float* __restrict__ vb,
    const float* __restrict__ crW0, const float* __restrict__ crW1,
    const float* __restrict__ tmW0, const float* __restrict__ tmW1,
    const float* __restrict__ tmW2, const float* __restrict__ tmB2,
    short* __restrict__ planes, float* __restrict__ w5, float* __restrict__ b5,
    float* __restrict__ c2cr, float* __restrict__ c2tm, float* __restrict__ b45,
    float* __restrict__ vout, float* __restrict__ U1cr, float* __restrict__ U1tm)
{
    __shared__ __align__(16) float smem[32 * DD];
    const int blk = blockIdx.x;
    const int tid = threadIdx.x;

    if (blk < 24) {
        const int mat = blk >> 3;
        const int kk  = blk & 7;
        const float* W = (mat == 0) ? crW1 : (mat == 1) ? tmW1 : emW1;
        const int col = tid;
        short bh[32], bm[32], bl[32];
#pragma unroll
        for (int j = 0; j < 32; ++j) {
            float w = W[(kk * 32 + j) * 256 + col];
            unsigned short h = f2bf(w); float fh = bf2f(h);
            float r1 = w - fh;
            unsigned short m = f2bf(r1); float fm = bf2f(m);
            bh[j] = (short)h; bm[j] = (short)m; bl[j] = (short)f2bf(r1 - fm);
        }
        short* pH = planes + (size_t)(mat * 3 + 0) * PL + kk * 8192 + col * 32;
        short* pM = planes + (size_t)(mat * 3 + 1) * PL + kk * 8192 + col * 32;
        short* pLp = planes + (size_t)(mat * 3 + 2) * PL + kk * 8192 + col * 32;
#pragma unroll
        for (int j = 0; j < 32; j += 4) {
            *(short4*)(pH + j) = make_short4(bh[j], bh[j+1], bh[j+2], bh[j+3]);
            *(short4*)(pM + j) = make_short4(bm[j], bm[j+1], bm[j+2], bm[j+3]);
            *(short4*)(pLp + j) = make_short4(bl[j], bl[j+1], bl[j+2], bl[j+3]);
        }
    } else if (blk == 24) {
        float acc = 0.f;
        for (int j = 0; j < 256; j += 4) {
            float4 wrow = *(const float4*)(emW2 + tid * 256 + j);
            float4 vv   = *(const float4*)(vW + j);
            acc += wrow.x * vv.x + wrow.y * vv.y + wrow.z * vv.z + wrow.w * vv.w;
        }
        w5[tid] = acc;
        if (tid == 0) {
            float b = 0.f;
            for (int j = 0; j < 256; ++j) b += emB2[j] * vW[j];
            b5[0] = b + vb[0];
        }
    } else if (blk < 33) {
        constexpr int TM = 4;
        float* bufA = smem;
        float* bufB = bufA + TM * DD;
        float* bufC = bufB + TM * DD;
        const int row0 = (blk - 25) * TM;
        for (int i = 0; i < TM; ++i) bufA[i * DD + tid] = x[(row0 + i) * DD + tid];
        __syncthreads();
        layer256<TM, true >(emW0, emB0, bufA, 256, DD, bufB, DD); __syncthreads();
        layer256<TM, true >(emW1, emB1, bufB, 256, DD, bufC, DD); __syncthreads();
        layer256<TM, false>(emW2, emB2, bufC, 256, DD, bufB, DD); __syncthreads();
        head1c<TM>(bufB, DD, vW, 1, 0, vb[0], vout, row0);
    } else if (blk < 41) {
        const int row0 = (blk - 33) * 4;
        float* xs = smem;   // [4][256]
        for (int i = 0; i < 4; ++i) xs[i * 256 + tid] = x[(row0 + i) * 256 + tid];
        __syncthreads();
        float acr[4] = {0.f,0.f,0.f,0.f}, atm[4] = {0.f,0.f,0.f,0.f};
        for (int k = 0; k < 256; ++k) {
            float wc = crW0[k * 256 + tid];
            float wt = tmW0[k * 256 + tid];
#pragma unroll
            for (int i = 0; i < 4; ++i) {
                acr[i] += xs[i * 256 + k] * wc;
                atm[i] += xs[i * 256 + k] * wt;
            }
        }
        for (int i = 0; i < 4; ++i) {
            U1cr[(row0 + i) * 256 + tid] = acr[i];
            U1tm[(row0 + i) * 256 + tid] = atm[i];
        }
    } else if (blk < 65) {
        const int pb = blk - 41;
        const int prod = pb >> 3;           // 0=W45, 1=W2cr, 2=W2tm
        const int r0 = (pb & 7) * 32;
        const float* B = (prod == 0) ? emW0 : (prod == 1) ? crW0 : tmW0;
        const int pbase = 9 + prod * 3;
        float* As = smem;   // [32][256]
        for (int i = tid; i < 32 * 256; i += 256)
            As[i] = tmW2[(r0 + (i >> 8)) * 256 + (i & 255)];
        __syncthreads();
        float acc[32];
#pragma unroll
        for (int j = 0; j < 32; ++j) acc[j] = 0.f;
        for (int m = 0; m < 256; ++m) {
            float b = B[m * 256 + tid];
#pragma unroll
            for (int j = 0; j < 32; ++j) acc[j] += As[j * 256 + m] * b;
        }
        short bh[32], bm[32], bl[32];
#pragma unroll
        for (int j = 0; j < 32; ++j) {
            float w = acc[j];
            unsigned short h = f2bf(w); float fh = bf2f(h);
            float r1 = w - fh;
            unsigned short mm = f2bf(r1); float fm = bf2f(mm);
            bh[j] = (short)h; bm[j] = (short)mm; bl[j] = (short)f2bf(r1 - fm);
        }
        const int kk = r0 >> 5;
        short* pH = planes + (size_t)(pbase + 0) * PL + kk * 8192 + tid * 32;
        short* pM = planes + (size_t)(pbase + 1) * PL + kk * 8192 + tid * 32;
        short* pLp = planes + (size_t)(pbase + 2) * PL + kk * 8192 + tid * 32;
#pragma unroll
        for (int j = 0; j < 32; j += 4) {
            *(short4*)(pH + j) = make_short4(bh[j], bh[j+1], bh[j+2], bh[j+3]);
            *(short4*)(pM + j) = make_short4(bm[j], bm[j+1], bm[j+2], bm[j+3]);
            *(short4*)(pLp + j) = make_short4(bl[j], bl[j+1], bl[j+2], bl[j+3]);
        }
    } else {
        const int j = tid;
        float a0 = 0.f, a1 = 0.f, a2 = 0.f;
        for (int k = 0; k < 256; ++k) {
            float t = tmB2[k];
            a0 += t * crW0[k * 256 + j];
            a1 += t * tmW0[k * 256 + j];
            a2 += t * emW0[k * 256 + j];
        }
        c2cr[j] = a0;
        c2tm[j] = a1;
        b45[j] = a2 + emB0[j];
    }
}

__global__ __launch_bounds__(256) void finalize_kernel(
    const float* __restrict__ Vns3, const float* __restrict__ cont2,
    const float* __restrict__ rews0, const float* __restrict__ rews1,
    const float* __restrict__ cont1, float* __restrict__ out)
{
    const int b = blockIdx.x;
    const int tid = threadIdx.x;
    __shared__ float vs2[NA][NA];
    __shared__ float vs3[NA];
    if (tid < NA * NA) {
        const int x = tid / NA, y = tid % NA;
        float vals[NA];
        float m = -INFINITY;
#pragma unroll
        for (int z = 0; z < NA; ++z) {
            int vidx = ((b * NA + y) * NA + z) * NA + x;
            int cidx = ((b * NA + x) * NA + y) * NA + z;
            float c1 = rews0[b * NA + z] * 0.99f;
            float c2 = (c1 + rews1[(b * NA + x) * NA + z]) * 0.99f;
            float v = Vns3[vidx] * 0.970299f + c2;
            if (cont2[cidx] > 0.f) v = 0.f;
            vals[z] = v;
            m = fmaxf(m, v);
        }
        float se = 0.f, sw = 0.f;
#pragma unroll
        for (int z = 0; z < NA; ++z) { float e = expf(vals[z] - m); se += e; sw += e * vals[z]; }
        vs2[x][y] = sw / se;
    }
    __syncthreads();
    if (tid < NA) {
        const int x = tid;
        float vals[NA];
        float m = -INFINITY;
#pragma unroll
        for (int y = 0; y < NA; ++y) {
            float v = vs2[x][y];
            if (cont1[(b * NA + x) * NA + y] > 0.f) v = 0.f;
            vals[y] = v;
            m = fmaxf(m, v);
        }
        float se = 0.f, sw = 0.f;
#pragma unroll
        for (int y = 0; y < NA; ++y) { float e = expf(vals[y] - m); se += e; sw += e * vals[y]; }
        vs3[x] = sw / se;
    }
    __syncthreads();
    if (tid == 0) {
        float m = -INFINITY;
#pragma unroll
        for (int x = 0; x < NA; ++x) m = fmaxf(m, vs3[x]);
        float se = 0.f;
#pragma unroll
        for (int x = 0; x < NA; ++x) se += expf(vs3[x] - m);
        float l = logf(se);
#pragma unroll
        for (int x = 0; x < NA; ++x) out[b * NA + x] = vs3[x] - m - l;
    }
}

// ---------------------------------------------------------------------------
// mm3: accumulate RT row-tiles x 4 col-tiles over K=256 with NP passes.
// ---------------------------------------------------------------------------
template<int RT, int NP>
__device__ __forceinline__ void mm3(
    const short* __restrict__ plH, const short* __restrict__ plM, const short* __restrict__ plL,
    const short* actH, const short* actM, const short* actL,
    f32x4 (&acc)[4][RT])
{
    const int tid = threadIdx.x;
    const int ln15 = tid & 15, lng = (tid >> 4) & 3, wv = tid >> 6;
    const int wo = (wv * 64 + ln15) * 32 + lng * 8;
#pragma unroll
    for (int kk = 0; kk < 8; ++kk) {
        bf16x8 wH[4], wM[4], wL[4], xH[RT], xM[RT], xL[RT];
#pragma unroll
        for (int ct = 0; ct < 4; ++ct) {
            wH[ct] = *(const bf16x8*)(plH + wo + kk * 8192 + ct * 512);
            wM[ct] = *(const bf16x8*)(plM + wo + kk * 8192 + ct * 512);
            if (NP == 6) wL[ct] = *(const bf16x8*)(plL + wo + kk * 8192 + ct * 512);
        }
#pragma unroll
        for (int rt = 0; rt < RT; ++rt) {
            int off = (rt * 16 + ln15) * ASTR + kk * 32 + lng * 8;
            xH[rt] = *(const bf16x8*)(actH + off);
            xM[rt] = *(const bf16x8*)(actM + off);
            if (NP == 6) xL[rt] = *(const bf16x8*)(actL + off);
        }
        __builtin_amdgcn_s_setprio(1);
#pragma unroll
        for (int ct = 0; ct < 4; ++ct)
#pragma unroll
            for (int rt = 0; rt < RT; ++rt) {
                acc[ct][rt] = __builtin_amdgcn_mfma_f32_16x16x32_bf16(wH[ct], xH[rt], acc[ct][rt], 0, 0, 0);
                acc[ct][rt] = __builtin_amdgcn_mfma_f32_16x16x32_bf16(wH[ct], xM[rt], acc[ct][rt], 0, 0, 0);
                acc[ct][rt] = __builtin_amdgcn_mfma_f32_16x16x32_bf16(wM[ct], xH[rt], acc[ct][rt], 0, 0, 0);
                if (NP == 6) {
                    acc[ct][rt] = __builtin_amdgcn_mfma_f32_16x16x32_bf16(wM[ct], xM[rt], acc[ct][rt], 0, 0, 0);
                    acc[ct][rt] = __builtin_amdgcn_mfma_f32_16x16x32_bf16(wH[ct], xL[rt], acc[ct][rt], 0, 0, 0);
                    acc[ct][rt] = __builtin_amdgcn_mfma_f32_16x16x32_bf16(wL[ct], xH[rt], acc[ct][rt], 0, 0, 0);
                }
            }
        __builtin_amdgcn_s_setprio(0);
    }
}

// stage a 3-way-split activation row block from U + a*wrow + bias (relu)
template<int ROWS, bool CLAMP>
__device__ __forceinline__ void stage3w(
    const float* __restrict__ U, const float* __restrict__ wrow256,
    const float* __restrict__ bias, int row0,
    short* actH, short* actM, short* actL)
{
    const int tid = threadIdx.x;
    const int wv = tid >> 6, ln = tid & 63;
    constexpr int RPW = ROWS / 4;
    const float4 wr = *(const float4*)(wrow256 + ln * 4);
    const float4 bb = *(const float4*)(bias + ln * 4);
    for (int i = wv * RPW; i < wv * RPW + RPW; ++i) {
        int r = row0 + i;
        int srow = r / 15;
        if (CLAMP && srow > 7199) srow = 7199;
        float a = (float)(r % 15);
        float4 u = *(const float4*)(U + srow * 256 + ln * 4);
        float sv[4];
        sv[0] = fmaxf(u.x + a * wr.x + bb.x, 0.f);
        sv[1] = fmaxf(u.y + a * wr.y + bb.y, 0.f);
        sv[2] = fmaxf(u.z + a * wr.z + bb.z, 0.f);
        sv[3] = fmaxf(u.w + a * wr.w + bb.w, 0.f);
        split3_write(sv, actH + i * ASTR + ln * 4, actM + i * ASTR + ln * 4, actL + i * ASTR + ln * 4);
    }
}

// ---------------------------------------------------------------------------
// stage1m: 480 rows (b,a1), 30 blocks x 16 rows. rews0 + U2cr/U2tm.
// ---------------------------------------------------------------------------
__global__ __launch_bounds__(256, 2) void stage1m_kernel(
    const float* __restrict__ U1cr, const float* __restrict__ U1tm,
    const short* __restrict__ planes,
    const float* __restrict__ crW0, const float* __restrict__ crB0,
    const float* __restrict__ crB1, const float* __restrict__ crW2, const float* __restrict__ crB2,
    const float* __restrict__ tmW0, const float* __restrict__ tmB0,
    const float* __restrict__ tmB1,
    const float* __restrict__ c2cr, const float* __restrict__ c2tm,
    float* __restrict__ rews0, float* __restrict__ U2cr, float* __restrict__ U2tm)
{
    __shared__ short actH[16 * ASTR];
    __shared__ short actM[16 * ASTR];
    __shared__ short actL[16 * ASTR];
    __shared__ float hred[64];
    const int tid = threadIdx.x;
    const int row0 = blockIdx.x * 16;
    const int ln15 = tid & 15, lng = (tid >> 4) & 3, wv = tid >> 6;

    stage3w<16, false>(U1cr, crW0 + 65536, crB0, row0, actH, actM, actL);
    __syncthreads();
    {
        f32x4 acc[4][1];
#pragma unroll
        for (int a = 0; a < 4; ++a) acc[a][0] = f32x4{0.f,0.f,0.f,0.f};
        mm3<1, 6>(planes + 0*PL, planes + 1*PL, planes + 2*PL, actH, actM, actL, acc);
        float hp = 0.f;
#pragma unroll
        for (int ct = 0; ct < 4; ++ct) {
            const int colb = wv * 64 + ct * 16 + lng * 4;
            const float4 b1 = *(const float4*)(crB1 + colb);
            f32x4 v = acc[ct][0];
            v[0] += b1.x; v[1] += b1.y; v[2] += b1.z; v[3] += b1.w;
#pragma unroll
            for (int j = 0; j < 4; ++j) v[j] = fmaxf(v[j], 0.f);
#pragma unroll
            for (int j = 0; j < 4; ++j) hp += v[j] * crW2[(colb + j) * 2 + 1];
        }
        hp += __shfl_xor(hp, 16);
        hp += __shfl_xor(hp, 32);
        if (lng == 0) hred[wv * 16 + ln15] = hp;
        __syncthreads();
        if (tid < 16) rews0[row0 + tid] = hred[tid] + hred[16 + tid] + hred[32 + tid] + hred[48 + tid] + crB2[1];
        __syncthreads();
    }

    stage3w<16, false>(U1tm, tmW0 + 65536, tmB0, row0, actH, actM, actL);
    __syncthreads();
    {
        f32x4 acc[4][1];
#pragma unroll
        for (int a = 0; a < 4; ++a) acc[a][0] = f32x4{0.f,0.f,0.f,0.f};
        mm3<1, 6>(planes + 3*PL, planes + 4*PL, planes + 5*PL, actH, actM, actL, acc);
        __syncthreads();
#pragma unroll
        for (int ct = 0; ct < 4; ++ct) {
            const int colb = wv * 64 + ct * 16 + lng * 4;
            const float4 bb = *(const float4*)(tmB1 + colb);
            f32x4 v = acc[ct][0];
            v[0] += bb.x; v[1] += bb.y; v[2] += bb.z; v[3] += bb.w;
#pragma unroll
            for (int j = 0; j < 4; ++j) v[j] = fmaxf(v[j], 0.f);
            float sv[4] = {v[0], v[1], v[2], v[3]};
            const int ao = ln15 * ASTR + colb;
            split3_write(sv, actH + ao, actM + ao, actL + ao);
        }
        __syncthreads();
    }
    {
        f32x4 acc[4][1];
#pragma unroll
        for (int a = 0; a < 4; ++a) acc[a][0] = f32x4{0.f,0.f,0.f,0.f};
        mm3<1, 6>(planes + 12*PL, planes + 13*PL, planes + 14*PL, actH, actM, actL, acc);
#pragma unroll
        for (int ct = 0; ct < 4; ++ct) {
            const int colb = wv * 64 + ct * 16 + lng * 4;
            const float4 cc = *(const float4*)(c2cr + colb);
            float4 o; o.x = acc[ct][0][0] + cc.x; o.y = acc[ct][0][1] + cc.y;
            o.z = acc[ct][0][2] + cc.z; o.w = acc[ct][0][3] + cc.w;
            *(float4*)(U2cr + (row0 + ln15) * 256 + colb) = o;
        }
    }
    {
        f32x4 acc[4][1];
#pragma unroll
        for (int a = 0; a < 4; ++a) acc[a][0] = f32x4{0.f,0.f,0.f,0.f};
        mm3<1, 6>(planes + 15*PL, planes + 16*PL, planes + 17*PL, actH, actM, actL, acc);
#pragma unroll
        for (int ct = 0; ct < 4; ++ct) {
            const int colb = wv * 64 + ct * 16 + lng * 4;
            const float4 cc = *(const float4*)(c2tm + colb);
            float4 o; o.x = acc[ct][0][0] + cc.x; o.y = acc[ct][0][1] + cc.y;
            o.z = acc[ct][0][2] + cc.z; o.w = acc[ct][0][3] + cc.w;
            *(float4*)(U2tm + (row0 + ln15) * 256 + colb) = o;
        }
    }
}

// ---------------------------------------------------------------------------
// stage2m: 7200 rows, 450 blocks x 16 rows. cont1/rews1 + Ucr/Utm (permuted).
// ---------------------------------------------------------------------------
__global__ __launch_bounds__(256, 2) void stage2m_kernel(
    const float* __restrict__ U2cr, const float* __restrict__ U2tm,
    const short* __restrict__ planes,
    const float* __restrict__ crW0, const float* __restrict__ crB0,
    const float* __restrict__ crB1, const float* __restrict__ crW2, const float* __restrict__ crB2,
    const float* __restrict__ tmW0, const float* __restrict__ tmB0,
    const float* __restrict__ tmB1,
    const float* __restrict__ c2cr, const float* __restrict__ c2tm,
    float* __restrict__ cont1, float* __restrict__ rews1,
    float* __restrict__ Ucr, float* __restrict__ Utm)
{
    __shared__ short actH[16 * ASTR];
    __shared__ short actM[16 * ASTR];
    __shared__ short actL[16 * ASTR];
    __shared__ float hred[2][64];
    const int tid = threadIdx.x;
    const int row0 = blockIdx.x * 16;
    const int ln15 = tid & 15, lng = (tid >> 4) & 3, wv = tid >> 6;

    stage3w<16, false>(U2cr, crW0 + 65536, crB0, row0, actH, actM, actL);
    __syncthreads();
    {
        f32x4 acc[4][1];
#pragma unroll
        for (int a = 0; a < 4; ++a) acc[a][0] = f32x4{0.f,0.f,0.f,0.f};
        mm3<1, 6>(planes + 0*PL, planes + 1*PL, planes + 2*PL, actH, actM, actL, acc);
        float hp0 = 0.f, hp1 = 0.f;
#pragma unroll
        for (int ct = 0; ct < 4; ++ct) {
            const int colb = wv * 64 + ct * 16 + lng * 4;
            const float4 b1 = *(const float4*)(crB1 + colb);
            f32x4 v = acc[ct][0];
            v[0] += b1.x; v[1] += b1.y; v[2] += b1.z; v[3] += b1.w;
#pragma unroll
            for (int j = 0; j < 4; ++j) v[j] = fmaxf(v[j], 0.f);
#pragma unroll
            for (int j = 0; j < 4; ++j) {
                hp0 += v[j] * crW2[(colb + j) * 2 + 0];
                hp1 += v[j] * crW2[(colb + j) * 2 + 1];
            }
        }
        hp0 += __shfl_xor(hp0, 16); hp0 += __shfl_xor(hp0, 32);
        hp1 += __shfl_xor(hp1, 16); hp1 += __shfl_xor(hp1, 32);
        if (lng == 0) {
            hred[0][wv * 16 + ln15] = hp0;
            hred[1][wv * 16 + ln15] = hp1;
        }
        __syncthreads();
        if (tid < 16)
            cont1[row0 + tid] = hred[0][tid] + hred[0][16 + tid] + hred[0][32 + tid] + hred[0][48 + tid] + crB2[0];
        else if (tid >= 64 && tid < 80)
            rews1[row0 + tid - 64] = hred[1][tid - 64] + hred[1][16 + tid - 64] + hred[1][32 + tid - 64] + hred[1][48 + tid - 64] + crB2[1];
        __syncthreads();
    }

    stage3w<16, false>(U2tm, tmW0 + 65536, tmB0, row0, actH, actM, actL);
    __syncthreads();
    {
        f32x4 acc[4][1];
#pragma unroll
        for (int a = 0; a < 4; ++a) acc[a][0] = f32x4{0.f,0.f,0.f,0.f};
        mm3<1, 6>(planes + 3*PL, planes + 4*PL, planes + 5*PL, actH, actM, actL, acc);
        __syncthreads();
#pragma unroll
        for (int ct = 0; ct < 4; ++ct) {
            const int colb = wv * 64 + ct * 16 + lng * 4;
            const float4 bb = *(const float4*)(tmB1 + colb);
            f32x4 v = acc[ct][0];
            v[0] += bb.x; v[1] += bb.y; v[2] += bb.z; v[3] += bb.w;
#pragma unroll
            for (int j = 0; j < 4; ++j) v[j] = fmaxf(v[j], 0.f);
            float sv[4] = {v[0], v[1], v[2], v[3]};
            const int ao = ln15 * ASTR + colb;
            split3_write(sv, actH + ao, actM + ao, actL + ao);
        }
        __syncthreads();
    }
    int pr;
    {
        int r = row0 + ln15;
        int b = r / 225, a1 = (r / 15) % 15, a2 = r % 15;
        pr = (b * 15 + a2) * 15 + a1;
    }
    {
        f32x4 acc[4][1];
#pragma unroll
        for (int a = 0; a < 4; ++a) acc[a][0] = f32x4{0.f,0.f,0.f,0.f};
        mm3<1, 6>(planes + 12*PL, planes + 13*PL, planes + 14*PL, actH, actM, actL, acc);
#pragma unroll
        for (int ct = 0; ct < 4; ++ct) {
            const int colb = wv * 64 + ct * 16 + lng * 4;
            const float4 cc = *(const float4*)(c2cr + colb);
            float4 o; o.x = acc[ct][0][0] + cc.x; o.y = acc[ct][0][1] + cc.y;
            o.z = acc[ct][0][2] + cc.z; o.w = acc[ct][0][3] + cc.w;
            *(float4*)(Ucr + pr * 256 + colb) = o;
        }
    }
    {
        f32x4 acc[4][1];
#pragma unroll
        for (int a = 0; a < 4; ++a) acc[a][0] = f32x4{0.f,0.f,0.f,0.f};
        mm3<1, 3>(planes + 15*PL, planes + 16*PL, planes + 17*PL, actH, actM, actL, acc);
#pragma unroll
        for (int ct = 0; ct < 4; ++ct) {
            const int colb = wv * 64 + ct * 16 + lng * 4;
            const float4 cc = *(const float4*)(c2tm + colb);
            float4 o; o.x = acc[ct][0][0] + cc.x; o.y = acc[ct][0][1] + cc.y;
            o.z = acc[ct][0][2] + cc.z; o.w = acc[ct][0][3] + cc.w;
            *(float4*)(Utm + pr * 256 + colb) = o;
        }
    }
}

// ---------------------------------------------------------------------------
// layer_g2: 2-way (H,M) 3-pass 16x16x32 layer over RT*16-row act tile.
// ---------------------------------------------------------------------------
template<int RT, bool RELU, bool HEAD, bool WRITEACT>
__device__ __forceinline__ void layer_g2(
    const short* __restrict__ plH, const short* __restrict__ plL,
    const float* __restrict__ bias,
    const float* __restrict__ headW, const float* __restrict__ headB,
    float* __restrict__ headOut, int row0,
    short* actH, short* actL, float* hred)
{
    const int tid = threadIdx.x;
    const int ln15 = tid & 15, lng = (tid >> 4) & 3, wv = tid >> 6;
    const int wo = (wv * 64 + ln15) * 32 + lng * 8;
    f32x4 acc[4][RT];
#pragma unroll
    for (int a = 0; a < 4; ++a)
#pragma unroll
        for (int b = 0; b < RT; ++b) acc[a][b] = f32x4{0.f, 0.f, 0.f, 0.f};

#pragma unroll
    for (int kk = 0; kk < 8; ++kk) {
        bf16x8 aH[4], aL[4], bH[RT], bL[RT];
#pragma unroll
        for (int ct = 0; ct < 4; ++ct) {
            aH[ct] = *(const bf16x8*)(plH + wo + kk * 8192 + ct * 512);
            aL[ct] = *(const bf16x8*)(plL + wo + kk * 8192 + ct * 512);
        }
#pragma unroll
        for (int rt = 0; rt < RT; ++rt) {
            int off = (rt * 16 + ln15) * ASTR + kk * 32 + lng * 8;
            bH[rt] = *(const bf16x8*)(actH + off);
            bL[rt] = *(const bf16x8*)(actL + off);
        }
        __builtin_amdgcn_s_setprio(1);
#pragma unroll
        for (int ct = 0; ct < 4; ++ct)
#pragma unroll
            for (int rt = 0; rt < RT; ++rt) {
                acc[ct][rt] = __builtin_amdgcn_mfma_f32_16x16x32_bf16(aH[ct], bH[rt], acc[ct][rt], 0, 0, 0);
                acc[ct][rt] = __builtin_amdgcn_mfma_f32_16x16x32_bf16(aH[ct], bL[rt], acc[ct][rt], 0, 0, 0);
                acc[ct][rt] = __builtin_amdgcn_mfma_f32_16x16x32_bf16(aL[ct], bH[rt], acc[ct][rt], 0, 0, 0);
            }
        __builtin_amdgcn_s_setprio(0);
    }
    __syncthreads();

    float hp[RT];
#pragma unroll
    for (int rt = 0; rt < RT; ++rt) hp[rt] = 0.f;
#pragma unroll
    for (int ct = 0; ct < 4; ++ct) {
        const int colb = wv * 64 + ct * 16 + lng * 4;
        const float4 bb = *(const float4*)(bias + colb);
#pragma unroll
        for (int rt = 0; rt < RT; ++rt) {
            f32x4 v = acc[ct][rt];
            v[0] += bb.x; v[1] += bb.y; v[2] += bb.z; v[3] += bb.w;
            if (RELU) {
#pragma unroll
                for (int j = 0; j < 4; ++j) v[j] = fmaxf(v[j], 0.f);
            }
            if (HEAD) {
                const float4 hw = *(const float4*)(headW + colb);
                hp[rt] += v[0] * hw.x + v[1] * hw.y + v[2] * hw.z + v[3] * hw.w;
            }
            if (WRITEACT) {
                float sv[4] = {v[0], v[1], v[2], v[3]};
                const int ao = (rt * 16 + ln15) * ASTR + colb;
                split2_write(sv, actH + ao, actL + ao);
            }
        }
    }
    if constexpr (HEAD) {
        constexpr int NR = RT * 16;
#pragma unroll
        for (int rt = 0; rt < RT; ++rt) {
            hp[rt] += __shfl_xor(hp[rt], 16);
            hp[rt] += __shfl_xor(hp[rt], 32);
        }
        if (lng == 0) {
#pragma unroll
            for (int rt = 0; rt < RT; ++rt) hred[wv * NR + rt * 16 + ln15] = hp[rt];
        }
        __syncthreads();
        if (tid < NR && row0 + tid < 108000) {
            float s = hred[tid] + hred[NR + tid] + hred[2 * NR + tid] + hred[3 * NR + tid] + headB[0];
            headOut[row0 + tid] = s;
        }
    }
    if constexpr (WRITEACT) __syncthreads();
}

// ---------------------------------------------------------------------------
// k3ab: fused stage-3, 2 blocks/CU, larger tiles to amortize weight fetch.
// k3b: 1688 x 64-row tiles (RT=4, last block guarded). k3a: 2250 x 48-row.
// Interleave 3:4 in groups of 7 (3938 blocks total).
// ---------------------------------------------------------------------------
__global__ __launch_bounds__(256, 2) void k3ab_kernel(
    const float* __restrict__ Ucr, const float* __restrict__ Utm,
    const short* __restrict__ planes,
    const float* __restrict__ crW0, const float* __restrict__ crB0,
    const float* __restrict__ crB1, const float* __restrict__ crW2,
    const float* __restrict__ crB2,
    const float* __restrict__ tmW0, const float* __restrict__ tmB0,
    const float* __restrict__ tmB1,
    const float* __restrict__ b45, const float* __restrict__ emB1,
    const float* __restrict__ w5, const float* __restrict__ b5,
    float* __restrict__ cont2, float* __restrict__ Vns3)
{
    __shared__ short lds[3 * 48 * ASTR];   // 76032 B >= 2*64*ASTR (67584 B)
    __shared__ float hred[256];
    const int tid = threadIdx.x;
    const int g = blockIdx.x / 7, rm = blockIdx.x % 7;
    bool isB; int idx;
    if (g < 562) {
        isB = rm < 3;
        idx = isB ? (g * 3 + rm) : (g * 4 + (rm - 3));
    } else {
        isB = rm < 2;
        idx = isB ? (1686 + rm) : (2248 + (rm - 2));
    }
    const int ln15 = tid & 15, lng = (tid >> 4) & 3, wv = tid >> 6;
    const short* P = planes;

    if (isB) {
        const int row0 = idx * 64;
        short* actH = lds;
        short* actL = lds + 64 * ASTR;
        const int ln = tid & 63;
        const float4 wr = *(const float4*)(tmW0 + 65536 + ln * 4);
        const float4 bb = *(const float4*)(tmB0 + ln * 4);
        for (int i = wv * 16; i < wv * 16 + 16; ++i) {
            int r = row0 + i;
            int srow = r / 15;
            if (srow > 7199) srow = 7199;
            float a = (float)(r % 15);
            float4 u = *(const float4*)(Utm + srow * 256 + ln * 4);
            float sv[4];
            sv[0] = fmaxf(u.x + a * wr.x + bb.x, 0.f);
            sv[1] = fmaxf(u.y + a * wr.y + bb.y, 0.f);
            sv[2] = fmaxf(u.z + a * wr.z + bb.z, 0.f);
            sv[3] = fmaxf(u.w + a * wr.w + bb.w, 0.f);
            split2_write(sv, actH + i * ASTR + ln * 4, actL + i * ASTR + ln * 4);
        }
        __syncthreads();
        layer_g2<4, true,  false, true >(P + 3 * PL,  P + 4 * PL,  tmB1, nullptr, nullptr, nullptr, row0, actH, actL, hred);
        layer_g2<4, true,  false, true >(P + 9 * PL,  P + 10 * PL, b45,  nullptr, nullptr, nullptr, row0, actH, actL, hred);
        layer_g2<4, true,  true,  false>(P + 6 * PL,  P + 7 * PL,  emB1, w5, b5, Vns3, row0, actH, actL, hred);
    } else {
        const int row0 = idx * 48;
        short* actH = lds;
        short* actM = lds + 48 * ASTR;
        short* actL = lds + 2 * 48 * ASTR;
        stage3w<48, false>(Ucr, crW0 + 65536, crB0, row0, actH, actM, actL);
        __syncthreads();
        f32x4 acc[4][3];
#pragma unroll
        for (int a = 0; a < 4; ++a)
#pragma unroll
            for (int b = 0; b < 3; ++b) acc[a][b] = f32x4{0.f,0.f,0.f,0.f};
        mm3<3, 6>(P + 0*PL, P + 1*PL, P + 2*PL, actH, actM, actL, acc);
        float hp[3] = {0.f, 0.f, 0.f};
#pragma unroll
        for (int ct = 0; ct < 4; ++ct) {
            const int colb = wv * 64 + ct * 16 + lng * 4;
            const float4 b1 = *(const float4*)(crB1 + colb);
#pragma unroll
            for (int rt = 0; rt < 3; ++rt) {
                f32x4 v = acc[ct][rt];
                v[0] += b1.x; v[1] += b1.y; v[2] += b1.z; v[3] += b1.w;
#pragma unroll
                for (int j = 0; j < 4; ++j) v[j] = fmaxf(v[j], 0.f);
#pragma unroll
                for (int j = 0; j < 4; ++j) hp[rt] += v[j] * crW2[(colb + j) * 2];
            }
        }
#pragma unroll
        for (int rt = 0; rt < 3; ++rt) {
            hp[rt] += __shfl_xor(hp[rt], 16);
            hp[rt] += __shfl_xor(hp[rt], 32);
        }
        if (lng == 0) {
#pragma unroll
            for (int rt = 0; rt < 3; ++rt) hred[wv * 48 + rt * 16 + ln15] = hp[rt];
        }
        __syncthreads();
        if (tid < 48)
            cont2[row0 + tid] = hred[tid] + hred[48 + tid] + hred[96 + tid] + hred[144 + tid] + crB2[0];
    }
}

extern "C" void kernel_launch(void* const* d_in, const int* in_sizes, int n_in,
                              void* d_out, int out_size, void* d_ws, size_t ws_size,
                              hipStream_t stream)
{
    (void)in_sizes; (void)n_in; (void)out_size; (void)ws_size;
    const float* x    = (const float*)d_in[0];
    const float* emW0 = (const float*)d_in[1];
    const float* emB0 = (const float*)d_in[2];
    const float* emW1 = (const float*)d_in[3];
    const float* emB1 = (const float*)d_in[4];
    const float* emW2 = (const float*)d_in[5];
    const float* emB2 = (const float*)d_in[6];
    const float* vW   = (const float*)d_in[7];
    const float* vb   = (const float*)d_in[8];
    const float* crW0 = (const float*)d_in[9];
    const float* crB0 = (const float*)d_in[10];
    const float* crW1 = (const float*)d_in[11];
    const float* crB1 = (const float*)d_in[12];
    const float* crW2 = (const float*)d_in[13];
    const float* crB2 = (const float*)d_in[14];
    const float* tmW0 = (const float*)d_in[15];
    const float* tmB0 = (const float*)d_in[16];
    const float* tmW1 = (const float*)d_in[17];
    const float* tmB1 = (const float*)d_in[18];
    const float* tmW2 = (const float*)d_in[19];
    const float* tmB2 = (const float*)d_in[20];
    float* out = (float*)d_out;

    float* w     = (float*)d_ws;
    float* rews0 = w;                     // 480
    float* cont1 = rews0 + 480;           // 7200
    float* rews1 = cont1 + 7200;          // 7200
    float* cont2 = rews1 + 7200;          // 108000
    float* Vns3  = cont2 + 108000;        // 108000
    float* U1cr  = Vns3 + 108000;         // 32*256
    float* U1tm  = U1cr + 32 * 256;       // 32*256
    short* planes = (short*)(U1tm + 32 * 256);  // 18 * PL shorts = 2.25 MB
    float* U2cr  = (float*)(planes + 18 * PL);  // 480*256
    float* U2tm  = U2cr + 480 * 256;            // 480*256
    float* Ucr   = U2tm + 480 * 256;            // 7200*256
    float* Utm   = Ucr + 7200 * 256;            // 7200*256
    float* w5    = Utm + 7200 * 256;            // 256
    float* b5    = w5 + 256;                    // 1 (pad to 4)
    float* c2cr  = b5 + 4;                      // 256
    float* c2tm  = c2cr + 256;                  // 256
    float* b45   = c2tm + 256;                  // 256

    front_kernel<<<66, 256, 0, stream>>>(x,
        emW0, emB0, emW1, emB1, emW2, emB2, vW, vb,
        crW0, crW1, tmW0, tmW1, tmW2, tmB2,
        planes, w5, b5, c2cr, c2tm, b45,
        out + NB * NA, U1cr, U1tm);
    stage1m_kernel<<<30, 256, 0, stream>>>(U1cr, U1tm, planes,
        crW0, crB0, crB1, crW2, crB2, tmW0, tmB0, tmB1,
        c2cr, c2tm, rews0, U2cr, U2tm);
    stage2m_kernel<<<450, 256, 0, stream>>>(U2cr, U2tm, planes,
        crW0, crB0, crB1, crW2, crB2, tmW0, tmB0, tmB1,
        c2cr, c2tm, cont1, rews1, Ucr, Utm);
    k3ab_kernel<<<3938, 256, 0, stream>>>(Ucr, Utm, planes,
        crW0, crB0, crB1, crW2, crB2,
        tmW0, tmB0, tmB1, b45, emB1, w5, b5, cont2, Vns3);
    finalize_kernel<<<NB, 256, 0, stream>>>(Vns3, cont2, rews0, rews1, cont1, out);
}